// Round 2
// baseline (3237.971 us; speedup 1.0000x reference)
//
#include <hip/hip_runtime.h>
#include <hip/hip_bf16.h>
#include <math.h>

typedef __hip_bfloat16 bf16;
typedef __bf16 bf16x8 __attribute__((ext_vector_type(8)));
typedef float f32x4 __attribute__((ext_vector_type(4)));
typedef unsigned short u16;
typedef u16 u16x8 __attribute__((ext_vector_type(8)));

#define NB 4096          // batch rows
#define DM 768           // model dim

__device__ __forceinline__ float cvt(float x){ return x; }
__device__ __forceinline__ float cvt(bf16 x){ return __bfloat162float(x); }
__device__ __forceinline__ void stv(float* p, float v){ *p = v; }
__device__ __forceinline__ void stv(bf16* p, float v){ *p = __float2bfloat16(v); }

__device__ __forceinline__ float gelu_f(float x){
    return 0.5f * x * (1.0f + erff(x * 0.70710678118654752440f));
}
__device__ __forceinline__ float sigmoid_f(float x){
    return 1.0f / (1.0f + __expf(-x));
}

__device__ __forceinline__ void async_copy16(const void* g, void* l){
    __builtin_amdgcn_global_load_lds((const __attribute__((address_space(1))) void*)g,
                                     (__attribute__((address_space(3))) void*)l, 16, 0, 0);
}

// ---------------------------------------------------------------------------
// Job descriptor shared by both GEMM kernels.
// Per job: C = act((A @ Bm^T + b0) * alpha * gv + b1)
// act: 0 none, 1 gelu, 2 sigmoid, 3 relu, 4 exp.
// rs != nullptr: block (gx,gy) writes its per-row tile sums to rs[gx*M + row].
// A: (M,ldA) bf16 cols [0,K). Bm: (N,ldB) bf16 (B^T layout) cols [0,K).
// trans=1: store C^T into (N,M).
// ---------------------------------------------------------------------------
#define MAXJ 8
struct Job {
    const bf16* A; const bf16* B; bf16* C;
    const float* b0; const float* gv; const float* b1;
    float* rs;
    int M, N, K, ldA, ldB, act, trans, blk0, nx;
    float alpha;
};
struct Jobs { Job j[MAXJ]; int nj; };

// ---------------------------------------------------------------------------
// Legacy 128x128 kernel (kept for shapes not divisible by 256: J2's N=384).
// ---------------------------------------------------------------------------
__global__ __launch_bounds__(256) void mgemm_k(Jobs jb)
{
    int z = 0;
    #pragma unroll
    for (int i = 1; i < MAXJ; ++i)
        if (i < jb.nj && (int)blockIdx.x >= jb.j[i].blk0) z = i;
    const Job& J = jb.j[z];
    const bf16* __restrict__ A  = J.A;
    const bf16* __restrict__ Bm = J.B;
    bf16* __restrict__ C        = J.C;
    const int bx = (int)blockIdx.x - J.blk0;
    const int gx = bx % J.nx;
    const int gy = bx / J.nx;
    const int M = J.M, N = J.N, K = J.K, ldA = J.ldA, ldB = J.ldB;

    __shared__ __align__(16) bf16 smem[17408];
    const int tid  = threadIdx.x;
    const int wave = tid >> 6;
    const int lane = tid & 63;
    const int row0 = gy * 128;
    const int col0 = gx * 128;
    const int wrow = (wave & 1) * 64;
    const int wcol = (wave >> 1) * 64;
    const int fl   = lane & 15;
    const int q    = lane >> 4;

    const int sr8 = lane >> 3;
    const int sc8 = (((lane & 7) ^ sr8)) * 8;
    const bf16* pA = A  + (size_t)(row0 + wave * 32 + sr8) * ldA + sc8;
    const bf16* pB = Bm + (size_t)(col0 + wave * 32 + sr8) * ldB + sc8;
    bf16* ldsA = &smem[(wave * 32) * 64];
    bf16* ldsB = &smem[8192 + (wave * 32) * 64];

    f32x4 acc[4][4] = {};
    for (int k0 = 0; k0 < K; k0 += 64){
        #pragma unroll
        for (int i = 0; i < 4; ++i){
            async_copy16(pA + (size_t)(i * 8) * ldA, ldsA + i * 512);
            async_copy16(pB + (size_t)(i * 8) * ldB, ldsB + i * 512);
        }
        pA += 64; pB += 64;
        __syncthreads();
        #pragma unroll
        for (int ks = 0; ks < 2; ++ks){
            bf16x8 af[4], bfv[4];
            #pragma unroll
            for (int i = 0; i < 4; ++i){
                const int ra = wrow + i * 16 + fl;
                const int rb = wcol + i * 16 + fl;
                const int ca = ((ks * 4 + q) ^ (ra & 7)) * 8;
                const int cb = ((ks * 4 + q) ^ (rb & 7)) * 8;
                af[i]  = *(const bf16x8*)&smem[ra * 64 + ca];
                bfv[i] = *(const bf16x8*)&smem[8192 + rb * 64 + cb];
            }
            #pragma unroll
            for (int mi = 0; mi < 4; ++mi)
                #pragma unroll
                for (int ni = 0; ni < 4; ++ni)
                    acc[mi][ni] = __builtin_amdgcn_mfma_f32_16x16x32_bf16(af[mi], bfv[ni], acc[mi][ni], 0, 0, 0);
        }
        __syncthreads();
    }

    constexpr int ELD = 136;
    #pragma unroll
    for (int ni = 0; ni < 4; ++ni){
        const int col = col0 + wcol + ni * 16 + fl;
        const float b0 = J.b0 ? J.b0[col] : 0.f;
        const float gm = (J.gv ? J.gv[col] : 1.f) * J.alpha;
        const float b1 = J.b1 ? J.b1[col] : 0.f;
        const int lcol = wcol + ni * 16 + fl;
        #pragma unroll
        for (int mi = 0; mi < 4; ++mi){
            const int lrow = wrow + mi * 16 + q * 4;
            #pragma unroll
            for (int r = 0; r < 4; ++r){
                float v = (acc[mi][ni][r] + b0) * gm + b1;
                if      (J.act == 1) v = gelu_f(v);
                else if (J.act == 2) v = sigmoid_f(v);
                else if (J.act == 3) v = fmaxf(v, 0.f);
                else if (J.act == 4) v = __expf(v);
                if (J.trans) smem[(size_t)lcol * ELD + lrow + r] = __float2bfloat16(v);
                else         smem[(size_t)(lrow + r) * ELD + lcol] = __float2bfloat16(v);
            }
        }
    }
    __syncthreads();
    const int erow = tid >> 4;
    const int ecol = (tid & 15) * 8;
    #pragma unroll
    for (int p = 0; p < 8; ++p){
        const int row = p * 16 + erow;
        const u16x8 uv = *(const u16x8*)&smem[row * ELD + ecol];
        if (J.trans) *(u16x8*)&C[(size_t)(col0 + row) * M + row0 + ecol] = uv;
        else         *(u16x8*)&C[(size_t)(row0 + row) * N + col0 + ecol] = uv;
        if (J.rs){
            float s = 0.f;
            #pragma unroll
            for (int j = 0; j < 8; ++j) s += __uint_as_float((unsigned)uv[j] << 16);
            s += __shfl_down(s, 8, 16);
            s += __shfl_down(s, 4, 16);
            s += __shfl_down(s, 2, 16);
            s += __shfl_down(s, 1, 16);
            if ((tid & 15) == 0) J.rs[(size_t)gx * M + row0 + row] = s;
        }
    }
}

// ---------------------------------------------------------------------------
// 256x256 8-phase kernel (T2 swizzle + T3/T4 counted vmcnt + T5 setprio).
// Requires M%256==0, N%256==0, K%128==0. 512 threads = 8 waves (2M x 4N),
// per-wave output 128x64, BK=64, 2 K-tiles per iteration, 128 KiB LDS.
//
// REGISTER BUDGET (R1 lesson): at 512-thread blocks, __launch_bounds__'s 2nd
// arg acts as min-BLOCKS/CU (CUDA semantics) -- (512,2) capped VGPRs at 128
// and spilled the 128-reg accumulator to scratch (measured: VGPR_Count=128,
// WRITE_SIZE 1.3GB/dispatch, MfmaUtil 2%). Pin 2 waves/SIMD explicitly via
// amdgpu_waves_per_eu(2,2) -> VGPR cap 256, which fits the ~230-reg set.
// (8 waves/block + 128KiB LDS force 1 block/CU = 2 waves/SIMD regardless.)
//
// Staging schedule (steady state, tiles E=2i buf0 / O=2i+1 buf1):
//   ph1 O.A1  ph2 O.B1  ph3 (E+2).A0  ph4 (E+2).B0
//   ph5 (E+2).A1  ph6 (E+2).B1  ph7 (O+2).A0  ph8 (O+2).B0
// Each stage only overwrites an LDS region whose last ds_read was >=1 barrier
// earlier. s_waitcnt vmcnt(4) at ph4/ph8 leaves exactly the 2 newest
// half-tiles in flight and guarantees the next K-tile has fully landed.
// Correctness of this schedule was harness-verified in R1 (absmax 0.0).
// ---------------------------------------------------------------------------
__global__ __attribute__((amdgpu_flat_work_group_size(512, 512), amdgpu_waves_per_eu(2, 2)))
void mgemm256_k(Jobs jb)
{
    int z = 0;
    #pragma unroll
    for (int i = 1; i < MAXJ; ++i)
        if (i < jb.nj && (int)blockIdx.x >= jb.j[i].blk0) z = i;
    const Job& J = jb.j[z];
    const bf16* __restrict__ A  = J.A;
    const bf16* __restrict__ Bm = J.B;
    bf16* __restrict__ C        = J.C;
    const int bx = (int)blockIdx.x - J.blk0;
    const int gx = bx % J.nx;
    const int gy = bx / J.nx;
    const int M = J.M, N = J.N, ldA = J.ldA, ldB = J.ldB;
    const int NH = J.K >> 7;                  // iterations, 2 K-tiles each

    __shared__ __align__(16) bf16 smem[65536];   // 128 KiB: A[2][256][64], B[2][256][64]
    const int tid  = threadIdx.x;
    const int w    = tid >> 6;
    const int lane = tid & 63;
    const int wm   = w >> 2;                  // 0..1
    const int wn   = w & 3;                   // 0..3
    const int fl   = lane & 15;
    const int q    = lane >> 4;
    const int row0 = gy * 256;
    const int col0 = gx * 256;

    // staging: per global_load_lds a wave covers 8 rows x 64 cols (1 KiB).
    // phys chunk (lane&7) at row r holds logical chunk (lane&7)^(r&7).
    const int sr = lane >> 3;
    const int sc = ((lane & 7) ^ sr) * 8;
    const bf16* aS = A  + (size_t)(row0 + w * 16 + sr) * ldA + sc;
    const bf16* bS = Bm + (size_t)(col0 + w * 16 + sr) * ldB + sc;
    bf16* aL = &smem[w * 1024];
    bf16* bL = &smem[32768 + w * 1024];

    auto SA = [&](int t, int h, int bb){
        const bf16* g = aS + (size_t)(h * 128) * ldA + t * 64;
        bf16* l = aL + bb * 16384 + h * 8192;
        async_copy16(g, l);
        async_copy16(g + (size_t)8 * ldA, l + 512);
    };
    auto SB = [&](int t, int h, int bb){
        const bf16* g = bS + (size_t)(h * 128) * ldB + t * 64;
        bf16* l = bL + bb * 16384 + h * 8192;
        async_copy16(g, l);
        async_copy16(g + (size_t)8 * ldB, l + 512);
    };

    // fragment read offsets (row&7 == fl&7 for every frag row)
    const int aoff0 = fl * 64 + ((q       ^ (fl & 7)) * 8);   // k-chunk q
    const int aoff1 = fl * 64 + (((4 + q) ^ (fl & 7)) * 8);   // k-chunk 4+q

    // Named fragment arrays, ONLY compile-time indices (macros, no pointer
    // params) -- keeps SROA able to promote everything to registers.
    bf16x8 fa[8];          // A half: 4 m-frags x 2 ks
    bf16x8 fb0[4], fb1[4]; // B halves: 2 n-frags x 2 ks each
    f32x4 acc[8][4] = {};

    #define RDA(bb, mh) do {                                                   \
        const bf16* ab_ = &smem[(bb) * 16384 + wm * 8192 + (mh) * 4096];       \
        _Pragma("unroll")                                                      \
        for (int j_ = 0; j_ < 4; ++j_){                                        \
            fa[j_ * 2 + 0] = *(const bf16x8*)&ab_[j_ * 1024 + aoff0];          \
            fa[j_ * 2 + 1] = *(const bf16x8*)&ab_[j_ * 1024 + aoff1];          \
        }                                                                      \
    } while (0)
    #define RDB(FB, bb, nh) do {                                               \
        const bf16* bb_ = &smem[32768 + (bb) * 16384 + wn * 4096 + (nh) * 2048];\
        _Pragma("unroll")                                                      \
        for (int n_ = 0; n_ < 2; ++n_){                                        \
            FB[n_ * 2 + 0] = *(const bf16x8*)&bb_[n_ * 1024 + aoff0];          \
            FB[n_ * 2 + 1] = *(const bf16x8*)&bb_[n_ * 1024 + aoff1];          \
        }                                                                      \
    } while (0)
    #define QM(mh, nh, FB) do {                                                \
        __builtin_amdgcn_s_setprio(1);                                         \
        _Pragma("unroll")                                                      \
        for (int j_ = 0; j_ < 4; ++j_){                                        \
            _Pragma("unroll")                                                  \
            for (int n_ = 0; n_ < 2; ++n_){                                    \
                acc[(mh)*4 + j_][(nh)*2 + n_] = __builtin_amdgcn_mfma_f32_16x16x32_bf16( \
                    fa[j_*2 + 0], FB[n_*2 + 0], acc[(mh)*4 + j_][(nh)*2 + n_], 0, 0, 0); \
                acc[(mh)*4 + j_][(nh)*2 + n_] = __builtin_amdgcn_mfma_f32_16x16x32_bf16( \
                    fa[j_*2 + 1], FB[n_*2 + 1], acc[(mh)*4 + j_][(nh)*2 + n_], 0, 0, 0); \
            }                                                                  \
        }                                                                      \
        __builtin_amdgcn_s_setprio(0);                                         \
    } while (0)
    #define BAR()  __builtin_amdgcn_s_barrier()
    #define LGKM() asm volatile("s_waitcnt lgkmcnt(0)" ::: "memory")

    // prologue: tile0 fully + tile1 first halves; vmcnt(4) -> tile0 landed
    SA(0, 0, 0); SB(0, 0, 0); SA(0, 1, 0); SB(0, 1, 0); SA(1, 0, 1); SB(1, 0, 1);
    asm volatile("s_waitcnt vmcnt(4)" ::: "memory");
    BAR();

    for (int i = 0; i < NH; ++i){
        const int E = 2 * i, O = 2 * i + 1;
        const bool pf = (i + 1 < NH);
        // ph1: Q(0,0) of E
        RDA(0, 0); RDB(fb0, 0, 0); SA(O, 1, 1);
        BAR(); LGKM(); QM(0, 0, fb0); BAR();
        // ph2: Q(0,1) of E
        RDB(fb1, 0, 1); SB(O, 1, 1);
        BAR(); LGKM(); QM(0, 1, fb1); BAR();
        // ph3: Q(1,0) of E
        RDA(0, 1); if (pf) SA(E + 2, 0, 0);
        BAR(); LGKM(); QM(1, 0, fb0); BAR();
        // ph4: Q(1,1) of E; counted wait -> tile O fully landed
        if (pf){ SB(E + 2, 0, 0); asm volatile("s_waitcnt vmcnt(4)" ::: "memory"); }
        else   { asm volatile("s_waitcnt vmcnt(0)" ::: "memory"); }
        BAR(); LGKM(); QM(1, 1, fb1); BAR();
        // ph5: Q(0,0) of O
        RDA(1, 0); RDB(fb0, 1, 0); if (pf) SA(E + 2, 1, 0);
        BAR(); LGKM(); QM(0, 0, fb0); BAR();
        // ph6: Q(0,1) of O
        RDB(fb1, 1, 1); if (pf) SB(E + 2, 1, 0);
        BAR(); LGKM(); QM(0, 1, fb1); BAR();
        // ph7: Q(1,0) of O
        RDA(1, 1); if (pf) SA(O + 2, 0, 1);
        BAR(); LGKM(); QM(1, 0, fb0); BAR();
        // ph8: Q(1,1) of O; counted wait -> tile E+2 fully landed
        if (pf){ SB(O + 2, 0, 1); asm volatile("s_waitcnt vmcnt(4)" ::: "memory"); }
        else   { asm volatile("s_waitcnt vmcnt(0)" ::: "memory"); }
        BAR(); LGKM(); QM(1, 1, fb1); BAR();
    }
    #undef BAR
    #undef LGKM
    #undef RDA
    #undef RDB
    #undef QM

    // epilogue: two 128-row (or 128-col for trans) passes through LDS scratch
    float cb0[4], cgm[4], cb1[4];
    #pragma unroll
    for (int ni = 0; ni < 4; ++ni){
        const int col = col0 + wn * 64 + ni * 16 + fl;
        cb0[ni] = J.b0 ? J.b0[col] : 0.f;
        cgm[ni] = (J.gv ? J.gv[col] : 1.f) * J.alpha;
        cb1[ni] = J.b1 ? J.b1[col] : 0.f;
    }
    constexpr int ELD = 264;
    const int erow = tid >> 5;            // 0..15
    const int ecol = (tid & 31) * 8;      // 16 B chunk
    for (int p = 0; p < 2; ++p){
        __syncthreads();
        const bool mine = J.trans ? ((wn >> 1) == p) : (wm == p);
        if (mine){
            #pragma unroll
            for (int ni = 0; ni < 4; ++ni)
                #pragma unroll
                for (int mi = 0; mi < 8; ++mi)
                    #pragma unroll
                    for (int r = 0; r < 4; ++r){
                        float v = (acc[mi][ni][r] + cb0[ni]) * cgm[ni] + cb1[ni];
                        if      (J.act == 1) v = gelu_f(v);
                        else if (J.act == 2) v = sigmoid_f(v);
                        else if (J.act == 3) v = fmaxf(v, 0.f);
                        else if (J.act == 4) v = __expf(v);
                        if (J.trans)
                            smem[(size_t)((wn & 1) * 64 + ni * 16 + fl) * ELD + wm * 128 + mi * 16 + q * 4 + r] = __float2bfloat16(v);
                        else
                            smem[(size_t)(mi * 16 + q * 4 + r) * ELD + wn * 64 + ni * 16 + fl] = __float2bfloat16(v);
                    }
        }
        __syncthreads();
        #pragma unroll
        for (int s = 0; s < 8; ++s){
            const int row = s * 16 + erow;
            const u16x8 uv = *(const u16x8*)&smem[row * ELD + ecol];
            if (J.trans) *(u16x8*)&C[(size_t)(col0 + p * 128 + row) * M + row0 + ecol] = uv;
            else         *(u16x8*)&C[(size_t)(row0 + p * 128 + row) * N + col0 + ecol] = uv;
            if (J.rs){
                float sv = 0.f;
                #pragma unroll
                for (int jj = 0; jj < 8; ++jj) sv += __uint_as_float((unsigned)uv[jj] << 16);
                sv += __shfl_down(sv, 16, 32);
                sv += __shfl_down(sv, 8, 32);
                sv += __shfl_down(sv, 4, 32);
                sv += __shfl_down(sv, 2, 32);
                sv += __shfl_down(sv, 1, 32);
                if ((tid & 31) == 0) J.rs[(size_t)gx * M + row0 + p * 128 + row] = sv;
            }
        }
    }
}

// Reduce 16 per-chunk partials per row into the softmax denominator.
// part layout: [2 dirs][16 chunks][NB rows]; l: [2][NB].
__global__ __launch_bounds__(256) void denom_k(const float* __restrict__ part, float* __restrict__ l)
{
    const int t = blockIdx.x * 256 + threadIdx.x;     // 0 .. 2*NB-1
    if (t >= 2 * NB) return;
    const int dir = t >> 12, row = t & (NB - 1);
    const float* p = part + (size_t)dir * 16 * NB + row;
    float s = 0.f;
    #pragma unroll
    for (int c = 0; c < 16; ++c) s += p[(size_t)c * NB];
    l[t] = s;
}

// Batched fp32 -> bf16 conversion
#define NCVT 14
struct CvtDesc { const float* s[NCVT]; bf16* d[NCVT]; int n[NCVT]; };
__global__ __launch_bounds__(256) void cvt_k(CvtDesc cd)
{
    const int e = blockIdx.y;
    const int base = (blockIdx.x * 256 + threadIdx.x) * 4;
    if (base >= cd.n[e]) return;
    const float4 v = *(const float4*)(cd.s[e] + base);
    union { bf16 h[4]; unsigned long long u; } o;
    o.h[0] = __float2bfloat16(v.x);
    o.h[1] = __float2bfloat16(v.y);
    o.h[2] = __float2bfloat16(v.z);
    o.h[3] = __float2bfloat16(v.w);
    *(unsigned long long*)(cd.d[e] + base) = o.u;
}

__global__ __launch_bounds__(256) void extract_k(
    const float* __restrict__ w1, const float* __restrict__ saw,
    bf16* __restrict__ w1c, float* __restrict__ sac)
{
    const int idx = blockIdx.x * 256 + threadIdx.x;
    if (idx < 384 * 768){
        const int oc = idx / 768, ic = idx % 768;
        w1c[idx] = __float2bfloat16(w1[(size_t)oc * 6912 + (size_t)ic * 9 + 4]);
    }
    if (idx < 384) sac[idx] = saw[(size_t)idx * 49 + 24];
}

// Fused FDA tail: ca1 -> ca2 -> x2 -> sa -> x3 -> dec -> x4, in place
__global__ __launch_bounds__(128) void fda_fused_k(
    bf16* __restrict__ x, const float* __restrict__ wc1, const float* __restrict__ wc2,
    const float* __restrict__ sac, const float* __restrict__ sab,
    const float* __restrict__ decw, const float* __restrict__ decb,
    const float* __restrict__ sigma)
{
    __shared__ float xs[384];
    __shared__ float ca1s[24];
    __shared__ float red[128];
    const int b = blockIdx.x;
    const int tid = threadIdx.x;
    bf16* xr = x + (size_t)b * 384;
    #pragma unroll
    for (int i = 0; i < 3; ++i) xs[tid + i * 128] = cvt(xr[tid + i * 128]);
    __syncthreads();
    if (tid < 96){
        const int o = tid >> 2, sub = tid & 3;
        const float* w = wc1 + (size_t)o * 384 + sub * 96;
        float p = 0.f;
        #pragma unroll 8
        for (int k = 0; k < 96; ++k) p = fmaf(xs[sub * 96 + k], w[k], p);
        p += __shfl_down(p, 1, 64);
        p += __shfl_down(p, 2, 64);
        if (sub == 0) ca1s[o] = gelu_f(p);
    }
    __syncthreads();
    float x2[3];
    float p = 0.f;
    #pragma unroll
    for (int i = 0; i < 3; ++i){
        const int c = tid + i * 128;
        float s = 0.f;
        const float* w = wc2 + (size_t)c * 24;
        #pragma unroll
        for (int k = 0; k < 24; ++k) s = fmaf(ca1s[k], w[k], s);
        const float v = xs[c] * sigmoid_f(s);
        x2[i] = v;
        p += v * sac[c];
    }
    red[tid] = p; __syncthreads();
    for (int s = 64; s > 0; s >>= 1){ if (tid < s) red[tid] += red[tid + s]; __syncthreads(); }
    const float sa = sigmoid_f(red[0] + sab[0]);
    __syncthreads();
    float qq = 0.f;
    #pragma unroll
    for (int i = 0; i < 3; ++i){
        const int c = tid + i * 128;
        x2[i] *= sa;
        qq += x2[i] * decw[c];
    }
    red[tid] = qq; __syncthreads();
    for (int s = 64; s > 0; s >>= 1){ if (tid < s) red[tid] += red[tid + s]; __syncthreads(); }
    const float xg = gelu_f(red[0] + decb[0]);
    #pragma unroll
    for (int i = 0; i < 3; ++i){
        const int c = tid + i * 128;
        const float sg = sigma[c];
        stv(&xr[c], x2[i] + sg * (x2[i] - xg));
    }
}

// o1 = (a+b)/l1[row] ; o2 = (c+d)/l2[row]  (split-K reduce + softmax denom)
__global__ __launch_bounds__(256) void reduce2_k(
    const bf16* __restrict__ a, const bf16* __restrict__ b, bf16* __restrict__ o1,
    const float* __restrict__ l1,
    const bf16* __restrict__ c, const bf16* __restrict__ d, bf16* __restrict__ o2,
    const float* __restrict__ l2)
{
    const size_t i = ((size_t)blockIdx.x * 256 + threadIdx.x) * 8;
    if (i >= (size_t)NB * DM) return;
    const int row = (int)(i / DM);
    const float inv1 = 1.0f / l1[row];
    const float inv2 = 1.0f / l2[row];
    u16x8 ua = *(const u16x8*)((const u16*)a + i);
    u16x8 ub = *(const u16x8*)((const u16*)b + i);
    u16x8 uc = *(const u16x8*)((const u16*)c + i);
    u16x8 ud = *(const u16x8*)((const u16*)d + i);
    u16x8 r1, r2;
    #pragma unroll
    for (int j = 0; j < 8; ++j){
        const float s1 = (__uint_as_float((unsigned)ua[j] << 16) + __uint_as_float((unsigned)ub[j] << 16)) * inv1;
        const float s2 = (__uint_as_float((unsigned)uc[j] << 16) + __uint_as_float((unsigned)ud[j] << 16)) * inv2;
        r1[j] = __bfloat16_as_ushort(__float2bfloat16(s1));
        r2[j] = __bfloat16_as_ushort(__float2bfloat16(s2));
    }
    *(u16x8*)((u16*)o1 + i) = r1;
    *(u16x8*)((u16*)o2 + i) = r2;
}

// Fused gate-combine + classifier + softmax(3). One block per batch row.
__global__ __launch_bounds__(256) void combine_cls_k(
    const bf16* __restrict__ g1, const bf16* __restrict__ a1, const float* __restrict__ s1,
    const bf16* __restrict__ g2, const bf16* __restrict__ a2, const float* __restrict__ s2,
    const float* __restrict__ w, const float* __restrict__ bias, float* __restrict__ out)
{
    __shared__ float r0[256], r1[256], r2[256];
    const int b = blockIdx.x;
    const int tid = threadIdx.x;
    const size_t off = (size_t)b * DM;
    float p0 = 0.f, p1 = 0.f, p2 = 0.f;
    #pragma unroll
    for (int i = 0; i < 3; ++i){
        const int c = tid + i * 256;
        const float v = sigmoid_f(cvt(g1[off + c])) * cvt(a1[off + c]) * s1[c]
                      + sigmoid_f(cvt(g2[off + c])) * cvt(a2[off + c]) * s2[c];
        p0 = fmaf(v, w[c],         p0);
        p1 = fmaf(v, w[DM + c],    p1);
        p2 = fmaf(v, w[2*DM + c],  p2);
    }
    r0[tid] = p0; r1[tid] = p1; r2[tid] = p2; __syncthreads();
    for (int s = 128; s > 0; s >>= 1){
        if (tid < s){ r0[tid] += r0[tid + s]; r1[tid] += r1[tid + s]; r2[tid] += r2[tid + s]; }
        __syncthreads();
    }
    if (tid == 0){
        const float l0 = r0[0] + bias[0];
        const float l1 = r1[0] + bias[1];
        const float l2 = r2[0] + bias[2];
        const float mx = fmaxf(l0, fmaxf(l1, l2));
        const float e0 = __expf(l0 - mx), e1 = __expf(l1 - mx), e2 = __expf(l2 - mx);
        const float inv = 1.f / (e0 + e1 + e2);
        out[(size_t)b * 3 + 0] = e0 * inv;
        out[(size_t)b * 3 + 1] = e1 * inv;
        out[(size_t)b * 3 + 2] = e2 * inv;
    }
}

extern "C" void kernel_launch(void* const* d_in, const int* in_sizes, int n_in,
                              void* d_out, int out_size, void* d_ws, size_t ws_size,
                              hipStream_t stream)
{
    const float* text   = (const float*)d_in[0];
    const float* image  = (const float*)d_in[1];
    const float* tl_w   = (const float*)d_in[2];
    const float* tl_b   = (const float*)d_in[3];
    const float* il_w   = (const float*)d_in[4];
    const float* il_b   = (const float*)d_in[5];
    const float* sda_wv = (const float*)d_in[10];
    const float* sda_bv = (const float*)d_in[11];
    const float* sda_wo = (const float*)d_in[12];
    const float* sda_bo = (const float*)d_in[13];
    const float* fda_w1 = (const float*)d_in[14];
    const float* fda_b1 = (const float*)d_in[15];
    const float* bn1_g  = (const float*)d_in[16];
    const float* bn1_b  = (const float*)d_in[17];
    const float* ca_w1  = (const float*)d_in[18];
    const float* ca_w2  = (const float*)d_in[19];
    const float* sa_w   = (const float*)d_in[20];
    const float* sa_b   = (const float*)d_in[21];
    const float* dec_w  = (const float*)d_in[22];
    const float* dec_b  = (const float*)d_in[23];
    const float* sigma  = (const float*)d_in[24];
    const float* fda_wf = (const float*)d_in[25];
    const float* fda_bf = (const float*)d_in[26];
    const float* bn2_g  = (const float*)d_in[27];
    const float* bn2_b  = (const float*)d_in[28];
    const float* dmi_wq = (const float*)d_in[29];
    const float* dmi_bq = (const float*)d_in[30];
    const float* dmi_wk = (const float*)d_in[31];
    const float* dmi_bk = (const float*)d_in[32];
    const float* dmi_wv = (const float*)d_in[33];
    const float* dmi_bv = (const float*)d_in[34];
    const float* tg_w1  = (const float*)d_in[35];
    const float* tg_b1  = (const float*)d_in[36];
    const float* tg_w2  = (const float*)d_in[37];
    const float* tg_b2  = (const float*)d_in[38];
    const float* ig_w1  = (const float*)d_in[39];
    const float* ig_b1  = (const float*)d_in[40];
    const float* ig_w2  = (const float*)d_in[41];
    const float* ig_b2  = (const float*)d_in[42];
    const float* t_scale= (const float*)d_in[43];
    const float* i_scale= (const float*)d_in[44];
    const float* cls_w  = (const float*)d_in[45];
    const float* cls_b  = (const float*)d_in[46];
    float* out = (float*)d_out;

    // ---- workspace ----
    char* base = (char*)d_ws;
    auto alloc = [&](size_t bytes){ void* p = (void*)base; base += (bytes + 255) & ~(size_t)255; return p; };
    const size_t SLOT = (size_t)NB * DM;
    const size_t W768 = (size_t)768 * 768;
    bf16* tl_wb   = (bf16*)alloc(W768 * 2);
    bf16* il_wb   = (bf16*)alloc(W768 * 2);
    bf16* sda_wvb = (bf16*)alloc((size_t)512 * 768 * 2);
    bf16* sda_wob = (bf16*)alloc((size_t)768 * 512 * 2);
    bf16* fda_wfb = (bf16*)alloc((size_t)768 * 384 * 2);
    bf16* dmi_wqb = (bf16*)alloc(W768 * 2);
    bf16* dmi_wkb = (bf16*)alloc(W768 * 2);
    bf16* dmi_wvb = (bf16*)alloc(W768 * 2);
    bf16* tg_w1b  = (bf16*)alloc(W768 * 2);
    bf16* tg_w2b  = (bf16*)alloc(W768 * 2);
    bf16* ig_w1b  = (bf16*)alloc(W768 * 2);
    bf16* ig_w2b  = (bf16*)alloc(W768 * 2);
    bf16* w1c     = (bf16*)alloc((size_t)384 * 768 * 2);
    float* sac    = (float*)alloc(1536 * 4);
    float* lbuf   = (float*)alloc(2 * NB * 4);               // final denominators [2][NB]
    float* part   = (float*)alloc((size_t)2 * 16 * NB * 4);  // per-chunk partials [2][16][NB]
    bf16* SL[8];
    for (int i = 0; i < 8; ++i) SL[i] = (bf16*)alloc(SLOT * 2);
    bf16* SC1 = (bf16*)alloc((size_t)NB * NB * 2);
    bf16* SC2 = (bf16*)alloc((size_t)NB * NB * 2);

    const float bnscale = 1.0f / sqrtf(1.0f + 1e-5f);
    const float iscale  = 1.0f / sqrtf(768.0f);
    const dim3 blk(256);

    struct JB {
        Jobs jb; int blocks; int tile;
        void add(const bf16* A, const bf16* B, bf16* C, int M, int N, int K, int ldA, int ldB,
                 const float* b0, float al, const float* gv, const float* b1, int act, int trans,
                 float* rs = nullptr){
            Job& j = jb.j[jb.nj++];
            j.A=A; j.B=B; j.C=C; j.b0=b0; j.gv=gv; j.b1=b1; j.rs=rs;
            j.M=M; j.N=N; j.K=K; j.ldA=ldA; j.ldB=ldB; j.act=act; j.trans=trans;
            j.alpha=al; j.blk0=blocks; j.nx=N/tile;
            blocks += (N/tile)*(M/tile);
        }
    };
    auto launch128 = [&](JB& b){ mgemm_k   <<<dim3(b.blocks), dim3(256), 0, stream>>>(b.jb); };
    auto launch256 = [&](JB& b){ mgemm256_k<<<dim3(b.blocks), dim3(512), 0, stream>>>(b.jb); };

    // fp32 -> bf16 staging
    CvtDesc cd;
    const float* srcs[NCVT] = {text, image, tl_w, il_w, sda_wv, sda_wo, fda_wf,
                               dmi_wq, dmi_wk, dmi_wv, tg_w1, tg_w2, ig_w1, ig_w2};
    bf16* dsts[NCVT] = {SL[0], SL[1], tl_wb, il_wb, sda_wvb, sda_wob, fda_wfb,
                        dmi_wqb, dmi_wkb, dmi_wvb, tg_w1b, tg_w2b, ig_w1b, ig_w2b};
    int   lens[NCVT] = {(int)SLOT, (int)SLOT, (int)W768, (int)W768, 512*768, 768*512, 768*384,
                        (int)W768, (int)W768, (int)W768, (int)W768, (int)W768, (int)W768, (int)W768};
    for (int i = 0; i < NCVT; ++i){ cd.s[i] = srcs[i]; cd.d[i] = dsts[i]; cd.n[i] = lens[i]; }
    cvt_k<<<dim3((int)(SLOT / 1024), NCVT), blk, 0, stream>>>(cd);
    extract_k<<<dim3((384 * 768 + 255) / 256), blk, 0, stream>>>(fda_w1, sa_w, w1c, sac);

    // J1: t0 = gelu(text@tl^T) -> SL2 ; im0 = gelu(image@il^T) -> SL3   [256-tile]
    { JB b{}; b.tile=256;
      b.add(SL[0], tl_wb, SL[2], NB, DM, DM, DM, DM, tl_b, 1.f, nullptr, nullptr, 1, 0);
      b.add(SL[1], il_wb, SL[3], NB, DM, DM, DM, DM, il_b, 1.f, nullptr, nullptr, 1, 0); launch256(b); }
    // J2: wv = t0@wv^T -> SL0 (N=512) ; x1 = conv1(im0) -> SL1 (N=384)  [128-tile: N=384]
    { JB b{}; b.tile=128;
      b.add(SL[2], sda_wvb, SL[0], NB, 512, DM, DM, DM, sda_bv, 1.f, nullptr, nullptr, 0, 0);
      b.add(SL[3], w1c,     SL[1], NB, 384, DM, DM, DM, fda_b1, bnscale, bn1_g, bn1_b, 1, 0); launch128(b); }
    // fused FDA tail (in place on SL1)
    fda_fused_k<<<dim3(NB), dim3(128), 0, stream>>>(SL[1], ca_w1, ca_w2, sac, sa_b, dec_w, dec_b, sigma);
    // J34: t1 = wv@wo^T -> SL4 (K=512) ; im1 = gelu((x4@wf^T+bf)*bn2) -> SL5 (K=384)  [256-tile]
    { JB b{}; b.tile=256;
      b.add(SL[0], sda_wob, SL[4], NB, DM, 512, 512, 512, sda_bo, 1.f, nullptr, nullptr, 0, 0);
      b.add(SL[1], fda_wfb, SL[5], NB, DM, 384, 384, 384, fda_bf, bnscale, bn2_g, bn2_b, 1, 0); launch256(b); }

    // J5: QKV both directions (6 jobs)  [256-tile]
    { JB b{}; b.tile=256;
      b.add(SL[4], dmi_wqb, SL[0], NB, DM, DM, DM, DM, dmi_bq, 1.f, nullptr, nullptr, 0, 0);
      b.add(SL[5], dmi_wkb, SL[1], NB, DM, DM, DM, DM, dmi_bk, 1.f, nullptr, nullptr, 0, 0);
      b.add(SL[5], dmi_wvb, SL[2], NB, DM, DM, DM, DM, dmi_bv, 1.f, nullptr, nullptr, 0, 1);
      b.add(SL[5], dmi_wqb, SL[3], NB, DM, DM, DM, DM, dmi_bq, 1.f, nullptr, nullptr, 0, 0);
      b.add(SL[4], dmi_wkb, SL[6], NB, DM, DM, DM, DM, dmi_bk, 1.f, nullptr, nullptr, 0, 0);
      b.add(SL[4], dmi_wvb, SL[7], NB, DM, DM, DM, DM, dmi_bv, 1.f, nullptr, nullptr, 0, 1);
      launch256(b); }
    // J6: scores with fused exp + per-block partial row sums (16 chunks)  [256-tile]
    { JB b{}; b.tile=256;
      b.add(SL[0], SL[1], SC1, NB, NB, DM, DM, DM, nullptr, iscale, nullptr, nullptr, 4, 0, part);
      b.add(SL[3], SL[6], SC2, NB, NB, DM, DM, DM, nullptr, iscale, nullptr, nullptr, 4, 0, part + 16 * NB); launch256(b); }
    // reduce partials -> lbuf
    denom_k<<<dim3((2 * NB + 255) / 256), blk, 0, stream>>>(part, lbuf);
    // J7: PV split-K=2 x 2 dirs (4 jobs) on unnormalized exp-scores  [256-tile]
    { JB b{}; b.tile=256;
      b.add(SC1,        SL[2],        SL[0], NB, DM, 2048, NB, NB, nullptr, 1.f, nullptr, nullptr, 0, 0);
      b.add(SC1 + 2048, SL[2] + 2048, SL[1], NB, DM, 2048, NB, NB, nullptr, 1.f, nullptr, nullptr, 0, 0);
      b.add(SC2,        SL[7],        SL[3], NB, DM, 2048, NB, NB, nullptr, 1.f, nullptr, nullptr, 0, 0);
      b.add(SC2 + 2048, SL[7] + 2048, SL[6], NB, DM, 2048, NB, NB, nullptr, 1.f, nullptr, nullptr, 0, 0);
      launch256(b); }
    // a1 = (SL0+SL1)/l1 -> SL4 ; a2 = (SL3+SL6)/l2 -> SL5
    reduce2_k<<<dim3((int)(SLOT / 2048)), blk, 0, stream>>>(SL[0], SL[1], SL[4], lbuf,
                                                           SL[3], SL[6], SL[5], lbuf + NB);
    // J8/J9: gates  [256-tile]
    { JB b{}; b.tile=256;
      b.add(SL[4], tg_w1b, SL[0], NB, DM, DM, DM, DM, tg_b1, 1.f, nullptr, nullptr, 3, 0);
      b.add(SL[5], ig_w1b, SL[1], NB, DM, DM, DM, DM, ig_b1, 1.f, nullptr, nullptr, 3, 0); launch256(b); }
    { JB b{}; b.tile=256;
      b.add(SL[0], tg_w2b, SL[3], NB, DM, DM, DM, DM, tg_b2, 1.f, nullptr, nullptr, 2, 0);
      b.add(SL[1], ig_w2b, SL[6], NB, DM, DM, DM, DM, ig_b2, 1.f, nullptr, nullptr, 2, 0); launch256(b); }
    // fused combine + classifier + softmax
    combine_cls_k<<<dim3(NB), blk, 0, stream>>>(SL[3], SL[4], t_scale, SL[6], SL[5], i_scale,
                                                cls_w, cls_b, out);
}

// Round 3
// 3234.516 us; speedup vs baseline: 1.0011x; 1.0011x over previous
//
#include <hip/hip_runtime.h>
#include <hip/hip_bf16.h>
#include <math.h>

typedef __hip_bfloat16 bf16;
typedef __bf16 bf16x8 __attribute__((ext_vector_type(8)));
typedef float f32x4 __attribute__((ext_vector_type(4)));
typedef unsigned short u16;
typedef u16 u16x8 __attribute__((ext_vector_type(8)));

#define NB 4096          // batch rows
#define DM 768           // model dim

__device__ __forceinline__ float cvt(float x){ return x; }
__device__ __forceinline__ float cvt(bf16 x){ return __bfloat162float(x); }
__device__ __forceinline__ void stv(float* p, float v){ *p = v; }
__device__ __forceinline__ void stv(bf16* p, float v){ *p = __float2bfloat16(v); }

__device__ __forceinline__ float gelu_f(float x){
    return 0.5f * x * (1.0f + erff(x * 0.70710678118654752440f));
}
__device__ __forceinline__ float sigmoid_f(float x){
    return 1.0f / (1.0f + __expf(-x));
}

__device__ __forceinline__ void async_copy16(const void* g, void* l){
    __builtin_amdgcn_global_load_lds((const __attribute__((address_space(1))) void*)g,
                                     (__attribute__((address_space(3))) void*)l, 16, 0, 0);
}

// ---------------------------------------------------------------------------
// Job descriptor shared by both GEMM kernels.
// Per job: C = act((A @ Bm^T + b0) * alpha * gv + b1)
// act: 0 none, 1 gelu, 2 sigmoid, 3 relu, 4 exp.
// rs != nullptr: block (gx,gy) writes its per-row tile sums to rs[gx*M + row].
// A: (M,ldA) bf16 cols [0,K). Bm: (N,ldB) bf16 (B^T layout) cols [0,K).
// trans=1: store C^T into (N,M).
// ---------------------------------------------------------------------------
#define MAXJ 8
struct Job {
    const bf16* A; const bf16* B; bf16* C;
    const float* b0; const float* gv; const float* b1;
    float* rs;
    int M, N, K, ldA, ldB, act, trans, blk0, nx;
    float alpha;
};
struct Jobs { Job j[MAXJ]; int nj; };

// ---------------------------------------------------------------------------
// Legacy 128x128 kernel (kept for shapes not divisible by 256: J2's N=384).
// ---------------------------------------------------------------------------
__global__ __launch_bounds__(256) void mgemm_k(Jobs jb)
{
    int z = 0;
    #pragma unroll
    for (int i = 1; i < MAXJ; ++i)
        if (i < jb.nj && (int)blockIdx.x >= jb.j[i].blk0) z = i;
    const Job& J = jb.j[z];
    const bf16* __restrict__ A  = J.A;
    const bf16* __restrict__ Bm = J.B;
    bf16* __restrict__ C        = J.C;
    const int bx = (int)blockIdx.x - J.blk0;
    const int gx = bx % J.nx;
    const int gy = bx / J.nx;
    const int M = J.M, N = J.N, K = J.K, ldA = J.ldA, ldB = J.ldB;

    __shared__ __align__(16) bf16 smem[17408];
    const int tid  = threadIdx.x;
    const int wave = tid >> 6;
    const int lane = tid & 63;
    const int row0 = gy * 128;
    const int col0 = gx * 128;
    const int wrow = (wave & 1) * 64;
    const int wcol = (wave >> 1) * 64;
    const int fl   = lane & 15;
    const int q    = lane >> 4;

    const int sr8 = lane >> 3;
    const int sc8 = (((lane & 7) ^ sr8)) * 8;
    const bf16* pA = A  + (size_t)(row0 + wave * 32 + sr8) * ldA + sc8;
    const bf16* pB = Bm + (size_t)(col0 + wave * 32 + sr8) * ldB + sc8;
    bf16* ldsA = &smem[(wave * 32) * 64];
    bf16* ldsB = &smem[8192 + (wave * 32) * 64];

    f32x4 acc[4][4] = {};
    for (int k0 = 0; k0 < K; k0 += 64){
        #pragma unroll
        for (int i = 0; i < 4; ++i){
            async_copy16(pA + (size_t)(i * 8) * ldA, ldsA + i * 512);
            async_copy16(pB + (size_t)(i * 8) * ldB, ldsB + i * 512);
        }
        pA += 64; pB += 64;
        __syncthreads();
        #pragma unroll
        for (int ks = 0; ks < 2; ++ks){
            bf16x8 af[4], bfv[4];
            #pragma unroll
            for (int i = 0; i < 4; ++i){
                const int ra = wrow + i * 16 + fl;
                const int rb = wcol + i * 16 + fl;
                const int ca = ((ks * 4 + q) ^ (ra & 7)) * 8;
                const int cb = ((ks * 4 + q) ^ (rb & 7)) * 8;
                af[i]  = *(const bf16x8*)&smem[ra * 64 + ca];
                bfv[i] = *(const bf16x8*)&smem[8192 + rb * 64 + cb];
            }
            #pragma unroll
            for (int mi = 0; mi < 4; ++mi)
                #pragma unroll
                for (int ni = 0; ni < 4; ++ni)
                    acc[mi][ni] = __builtin_amdgcn_mfma_f32_16x16x32_bf16(af[mi], bfv[ni], acc[mi][ni], 0, 0, 0);
        }
        __syncthreads();
    }

    constexpr int ELD = 136;
    #pragma unroll
    for (int ni = 0; ni < 4; ++ni){
        const int col = col0 + wcol + ni * 16 + fl;
        const float b0 = J.b0 ? J.b0[col] : 0.f;
        const float gm = (J.gv ? J.gv[col] : 1.f) * J.alpha;
        const float b1 = J.b1 ? J.b1[col] : 0.f;
        const int lcol = wcol + ni * 16 + fl;
        #pragma unroll
        for (int mi = 0; mi < 4; ++mi){
            const int lrow = wrow + mi * 16 + q * 4;
            #pragma unroll
            for (int r = 0; r < 4; ++r){
                float v = (acc[mi][ni][r] + b0) * gm + b1;
                if      (J.act == 1) v = gelu_f(v);
                else if (J.act == 2) v = sigmoid_f(v);
                else if (J.act == 3) v = fmaxf(v, 0.f);
                else if (J.act == 4) v = __expf(v);
                if (J.trans) smem[(size_t)lcol * ELD + lrow + r] = __float2bfloat16(v);
                else         smem[(size_t)(lrow + r) * ELD + lcol] = __float2bfloat16(v);
            }
        }
    }
    __syncthreads();
    const int erow = tid >> 4;
    const int ecol = (tid & 15) * 8;
    #pragma unroll
    for (int p = 0; p < 8; ++p){
        const int row = p * 16 + erow;
        const u16x8 uv = *(const u16x8*)&smem[row * ELD + ecol];
        if (J.trans) *(u16x8*)&C[(size_t)(col0 + row) * M + row0 + ecol] = uv;
        else         *(u16x8*)&C[(size_t)(row0 + row) * N + col0 + ecol] = uv;
        if (J.rs){
            float s = 0.f;
            #pragma unroll
            for (int j = 0; j < 8; ++j) s += __uint_as_float((unsigned)uv[j] << 16);
            s += __shfl_down(s, 8, 16);
            s += __shfl_down(s, 4, 16);
            s += __shfl_down(s, 2, 16);
            s += __shfl_down(s, 1, 16);
            if ((tid & 15) == 0) J.rs[(size_t)gx * M + row0 + row] = s;
        }
    }
}

// ---------------------------------------------------------------------------
// 256x256 8-phase kernel (T2 swizzle + T3/T4 counted vmcnt + T5 setprio).
// Requires M%256==0, N%256==0, K%128==0. 512 threads = 8 waves (2M x 4N),
// per-wave output 128x64, BK=64, 2 K-tiles per iteration, 128 KiB LDS.
//
// REGISTER BUDGET (R1/R2 lessons): gfx950 per-SIMD unified (VGPR+AGPR) file
// = 512 wave-regs. Cap per wave = 512 / (waves-per-SIMD required by the
// flat-work-group-size constraint).
//   R1 __launch_bounds__(512,2): 2nd arg acted as 2 blocks/CU -> 4 waves/SIMD
//     -> cap 128 -> 128-reg acc spilled everything (VGPR_Count=128, 1.3GB
//     scratch writes, MfmaUtil 2%).
//   R2 amdgpu_* attributes: silently ignored -> HIP default flat WG (1,1024)
//     -> 16-wave WG must be co-resident -> 4 waves/SIMD -> same cap 128,
//     byte-identical counters.
// Fix: plain __launch_bounds__(512) -- flat WG (1,512) -> an 8-wave WG needs
// only 2 waves/SIMD -> cap 256, which fits the ~230-reg working set
// (acc 128 + frags 64 + addressing). This is HipKittens' exact config.
//
// Staging schedule (steady state, tiles E=2i buf0 / O=2i+1 buf1):
//   ph1 O.A1  ph2 O.B1  ph3 (E+2).A0  ph4 (E+2).B0
//   ph5 (E+2).A1  ph6 (E+2).B1  ph7 (O+2).A0  ph8 (O+2).B0
// Each stage only overwrites an LDS region whose last ds_read was >=1 barrier
// earlier. s_waitcnt vmcnt(4) at ph4/ph8 leaves exactly the 2 newest
// half-tiles in flight and guarantees the next K-tile has fully landed.
// Correctness of this schedule was harness-verified in R1/R2 (absmax 0.0).
// ---------------------------------------------------------------------------
__global__ __launch_bounds__(512) void mgemm256_k(Jobs jb)
{
    int z = 0;
    #pragma unroll
    for (int i = 1; i < MAXJ; ++i)
        if (i < jb.nj && (int)blockIdx.x >= jb.j[i].blk0) z = i;
    const Job& J = jb.j[z];
    const bf16* __restrict__ A  = J.A;
    const bf16* __restrict__ Bm = J.B;
    bf16* __restrict__ C        = J.C;
    const int bx = (int)blockIdx.x - J.blk0;
    const int gx = bx % J.nx;
    const int gy = bx / J.nx;
    const int M = J.M, N = J.N, ldA = J.ldA, ldB = J.ldB;
    const int NH = J.K >> 7;                  // iterations, 2 K-tiles each

    __shared__ __align__(16) bf16 smem[65536];   // 128 KiB: A[2][256][64], B[2][256][64]
    const int tid  = threadIdx.x;
    const int w    = tid >> 6;
    const int lane = tid & 63;
    const int wm   = w >> 2;                  // 0..1
    const int wn   = w & 3;                   // 0..3
    const int fl   = lane & 15;
    const int q    = lane >> 4;
    const int row0 = gy * 256;
    const int col0 = gx * 256;

    // staging: per global_load_lds a wave covers 8 rows x 64 cols (1 KiB).
    // phys chunk (lane&7) at row r holds logical chunk (lane&7)^(r&7).
    const int sr = lane >> 3;
    const int sc = ((lane & 7) ^ sr) * 8;
    const bf16* aS = A  + (size_t)(row0 + w * 16 + sr) * ldA + sc;
    const bf16* bS = Bm + (size_t)(col0 + w * 16 + sr) * ldB + sc;
    bf16* aL = &smem[w * 1024];
    bf16* bL = &smem[32768 + w * 1024];

    auto SA = [&](int t, int h, int bb){
        const bf16* g = aS + (size_t)(h * 128) * ldA + t * 64;
        bf16* l = aL + bb * 16384 + h * 8192;
        async_copy16(g, l);
        async_copy16(g + (size_t)8 * ldA, l + 512);
    };
    auto SB = [&](int t, int h, int bb){
        const bf16* g = bS + (size_t)(h * 128) * ldB + t * 64;
        bf16* l = bL + bb * 16384 + h * 8192;
        async_copy16(g, l);
        async_copy16(g + (size_t)8 * ldB, l + 512);
    };

    // fragment read offsets (row&7 == fl&7 for every frag row)
    const int aoff0 = fl * 64 + ((q       ^ (fl & 7)) * 8);   // k-chunk q
    const int aoff1 = fl * 64 + (((4 + q) ^ (fl & 7)) * 8);   // k-chunk 4+q

    // Named fragment arrays, ONLY compile-time indices (macros, no pointer
    // params) -- keeps SROA able to promote everything to registers.
    bf16x8 fa[8];          // A half: 4 m-frags x 2 ks
    bf16x8 fb0[4], fb1[4]; // B halves: 2 n-frags x 2 ks each
    f32x4 acc[8][4] = {};

    #define RDA(bb, mh) do {                                                   \
        const bf16* ab_ = &smem[(bb) * 16384 + wm * 8192 + (mh) * 4096];       \
        _Pragma("unroll")                                                      \
        for (int j_ = 0; j_ < 4; ++j_){                                        \
            fa[j_ * 2 + 0] = *(const bf16x8*)&ab_[j_ * 1024 + aoff0];          \
            fa[j_ * 2 + 1] = *(const bf16x8*)&ab_[j_ * 1024 + aoff1];          \
        }                                                                      \
    } while (0)
    #define RDB(FB, bb, nh) do {                                               \
        const bf16* bb_ = &smem[32768 + (bb) * 16384 + wn * 4096 + (nh) * 2048];\
        _Pragma("unroll")                                                      \
        for (int n_ = 0; n_ < 2; ++n_){                                        \
            FB[n_ * 2 + 0] = *(const bf16x8*)&bb_[n_ * 1024 + aoff0];          \
            FB[n_ * 2 + 1] = *(const bf16x8*)&bb_[n_ * 1024 + aoff1];          \
        }                                                                      \
    } while (0)
    #define QM(mh, nh, FB) do {                                                \
        __builtin_amdgcn_s_setprio(1);                                         \
        _Pragma("unroll")                                                      \
        for (int j_ = 0; j_ < 4; ++j_){                                        \
            _Pragma("unroll")                                                  \
            for (int n_ = 0; n_ < 2; ++n_){                                    \
                acc[(mh)*4 + j_][(nh)*2 + n_] = __builtin_amdgcn_mfma_f32_16x16x32_bf16( \
                    fa[j_*2 + 0], FB[n_*2 + 0], acc[(mh)*4 + j_][(nh)*2 + n_], 0, 0, 0); \
                acc[(mh)*4 + j_][(nh)*2 + n_] = __builtin_amdgcn_mfma_f32_16x16x32_bf16( \
                    fa[j_*2 + 1], FB[n_*2 + 1], acc[(mh)*4 + j_][(nh)*2 + n_], 0, 0, 0); \
            }                                                                  \
        }                                                                      \
        __builtin_amdgcn_s_setprio(0);                                         \
    } while (0)
    #define BAR()  __builtin_amdgcn_s_barrier()
    #define LGKM() asm volatile("s_waitcnt lgkmcnt(0)" ::: "memory")

    // prologue: tile0 fully + tile1 first halves; vmcnt(4) -> tile0 landed
    SA(0, 0, 0); SB(0, 0, 0); SA(0, 1, 0); SB(0, 1, 0); SA(1, 0, 1); SB(1, 0, 1);
    asm volatile("s_waitcnt vmcnt(4)" ::: "memory");
    BAR();

    for (int i = 0; i < NH; ++i){
        const int E = 2 * i, O = 2 * i + 1;
        const bool pf = (i + 1 < NH);
        // ph1: Q(0,0) of E
        RDA(0, 0); RDB(fb0, 0, 0); SA(O, 1, 1);
        BAR(); LGKM(); QM(0, 0, fb0); BAR();
        // ph2: Q(0,1) of E
        RDB(fb1, 0, 1); SB(O, 1, 1);
        BAR(); LGKM(); QM(0, 1, fb1); BAR();
        // ph3: Q(1,0) of E
        RDA(0, 1); if (pf) SA(E + 2, 0, 0);
        BAR(); LGKM(); QM(1, 0, fb0); BAR();
        // ph4: Q(1,1) of E; counted wait -> tile O fully landed
        if (pf){ SB(E + 2, 0, 0); asm volatile("s_waitcnt vmcnt(4)" ::: "memory"); }
        else   { asm volatile("s_waitcnt vmcnt(0)" ::: "memory"); }
        BAR(); LGKM(); QM(1, 1, fb1); BAR();
        // ph5: Q(0,0) of O
        RDA(1, 0); RDB(fb0, 1, 0); if (pf) SA(E + 2, 1, 0);
        BAR(); LGKM(); QM(0, 0, fb0); BAR();
        // ph6: Q(0,1) of O
        RDB(fb1, 1, 1); if (pf) SB(E + 2, 1, 0);
        BAR(); LGKM(); QM(0, 1, fb1); BAR();
        // ph7: Q(1,0) of O
        RDA(1, 1); if (pf) SA(O + 2, 0, 1);
        BAR(); LGKM(); QM(1, 0, fb0); BAR();
        // ph8: Q(1,1) of O; counted wait -> tile E+2 fully landed
        if (pf){ SB(O + 2, 0, 1); asm volatile("s_waitcnt vmcnt(4)" ::: "memory"); }
        else   { asm volatile("s_waitcnt vmcnt(0)" ::: "memory"); }
        BAR(); LGKM(); QM(1, 1, fb1); BAR();
    }
    #undef BAR
    #undef LGKM
    #undef RDA
    #undef RDB
    #undef QM

    // epilogue: two 128-row (or 128-col for trans) passes through LDS scratch
    float cb0[4], cgm[4], cb1[4];
    #pragma unroll
    for (int ni = 0; ni < 4; ++ni){
        const int col = col0 + wn * 64 + ni * 16 + fl;
        cb0[ni] = J.b0 ? J.b0[col] : 0.f;
        cgm[ni] = (J.gv ? J.gv[col] : 1.f) * J.alpha;
        cb1[ni] = J.b1 ? J.b1[col] : 0.f;
    }
    constexpr int ELD = 264;
    const int erow = tid >> 5;            // 0..15
    const int ecol = (tid & 31) * 8;      // 16 B chunk
    for (int p = 0; p < 2; ++p){
        __syncthreads();
        const bool mine = J.trans ? ((wn >> 1) == p) : (wm == p);
        if (mine){
            #pragma unroll
            for (int ni = 0; ni < 4; ++ni)
                #pragma unroll
                for (int mi = 0; mi < 8; ++mi)
                    #pragma unroll
                    for (int r = 0; r < 4; ++r){
                        float v = (acc[mi][ni][r] + cb0[ni]) * cgm[ni] + cb1[ni];
                        if      (J.act == 1) v = gelu_f(v);
                        else if (J.act == 2) v = sigmoid_f(v);
                        else if (J.act == 3) v = fmaxf(v, 0.f);
                        else if (J.act == 4) v = __expf(v);
                        if (J.trans)
                            smem[(size_t)((wn & 1) * 64 + ni * 16 + fl) * ELD + wm * 128 + mi * 16 + q * 4 + r] = __float2bfloat16(v);
                        else
                            smem[(size_t)(mi * 16 + q * 4 + r) * ELD + wn * 64 + ni * 16 + fl] = __float2bfloat16(v);
                    }
        }
        __syncthreads();
        #pragma unroll
        for (int s = 0; s < 8; ++s){
            const int row = s * 16 + erow;
            const u16x8 uv = *(const u16x8*)&smem[row * ELD + ecol];
            if (J.trans) *(u16x8*)&C[(size_t)(col0 + p * 128 + row) * M + row0 + ecol] = uv;
            else         *(u16x8*)&C[(size_t)(row0 + p * 128 + row) * N + col0 + ecol] = uv;
            if (J.rs){
                float sv = 0.f;
                #pragma unroll
                for (int jj = 0; jj < 8; ++jj) sv += __uint_as_float((unsigned)uv[jj] << 16);
                sv += __shfl_down(sv, 16, 32);
                sv += __shfl_down(sv, 8, 32);
                sv += __shfl_down(sv, 4, 32);
                sv += __shfl_down(sv, 2, 32);
                sv += __shfl_down(sv, 1, 32);
                if ((tid & 31) == 0) J.rs[(size_t)gx * M + row0 + p * 128 + row] = sv;
            }
        }
    }
}

// Reduce 16 per-chunk partials per row into the softmax denominator.
// part layout: [2 dirs][16 chunks][NB rows]; l: [2][NB].
__global__ __launch_bounds__(256) void denom_k(const float* __restrict__ part, float* __restrict__ l)
{
    const int t = blockIdx.x * 256 + threadIdx.x;     // 0 .. 2*NB-1
    if (t >= 2 * NB) return;
    const int dir = t >> 12, row = t & (NB - 1);
    const float* p = part + (size_t)dir * 16 * NB + row;
    float s = 0.f;
    #pragma unroll
    for (int c = 0; c < 16; ++c) s += p[(size_t)c * NB];
    l[t] = s;
}

// Batched fp32 -> bf16 conversion
#define NCVT 14
struct CvtDesc { const float* s[NCVT]; bf16* d[NCVT]; int n[NCVT]; };
__global__ __launch_bounds__(256) void cvt_k(CvtDesc cd)
{
    const int e = blockIdx.y;
    const int base = (blockIdx.x * 256 + threadIdx.x) * 4;
    if (base >= cd.n[e]) return;
    const float4 v = *(const float4*)(cd.s[e] + base);
    union { bf16 h[4]; unsigned long long u; } o;
    o.h[0] = __float2bfloat16(v.x);
    o.h[1] = __float2bfloat16(v.y);
    o.h[2] = __float2bfloat16(v.z);
    o.h[3] = __float2bfloat16(v.w);
    *(unsigned long long*)(cd.d[e] + base) = o.u;
}

__global__ __launch_bounds__(256) void extract_k(
    const float* __restrict__ w1, const float* __restrict__ saw,
    bf16* __restrict__ w1c, float* __restrict__ sac)
{
    const int idx = blockIdx.x * 256 + threadIdx.x;
    if (idx < 384 * 768){
        const int oc = idx / 768, ic = idx % 768;
        w1c[idx] = __float2bfloat16(w1[(size_t)oc * 6912 + (size_t)ic * 9 + 4]);
    }
    if (idx < 384) sac[idx] = saw[(size_t)idx * 49 + 24];
}

// Fused FDA tail: ca1 -> ca2 -> x2 -> sa -> x3 -> dec -> x4, in place
__global__ __launch_bounds__(128) void fda_fused_k(
    bf16* __restrict__ x, const float* __restrict__ wc1, const float* __restrict__ wc2,
    const float* __restrict__ sac, const float* __restrict__ sab,
    const float* __restrict__ decw, const float* __restrict__ decb,
    const float* __restrict__ sigma)
{
    __shared__ float xs[384];
    __shared__ float ca1s[24];
    __shared__ float red[128];
    const int b = blockIdx.x;
    const int tid = threadIdx.x;
    bf16* xr = x + (size_t)b * 384;
    #pragma unroll
    for (int i = 0; i < 3; ++i) xs[tid + i * 128] = cvt(xr[tid + i * 128]);
    __syncthreads();
    if (tid < 96){
        const int o = tid >> 2, sub = tid & 3;
        const float* w = wc1 + (size_t)o * 384 + sub * 96;
        float p = 0.f;
        #pragma unroll 8
        for (int k = 0; k < 96; ++k) p = fmaf(xs[sub * 96 + k], w[k], p);
        p += __shfl_down(p, 1, 64);
        p += __shfl_down(p, 2, 64);
        if (sub == 0) ca1s[o] = gelu_f(p);
    }
    __syncthreads();
    float x2[3];
    float p = 0.f;
    #pragma unroll
    for (int i = 0; i < 3; ++i){
        const int c = tid + i * 128;
        float s = 0.f;
        const float* w = wc2 + (size_t)c * 24;
        #pragma unroll
        for (int k = 0; k < 24; ++k) s = fmaf(ca1s[k], w[k], s);
        const float v = xs[c] * sigmoid_f(s);
        x2[i] = v;
        p += v * sac[c];
    }
    red[tid] = p; __syncthreads();
    for (int s = 64; s > 0; s >>= 1){ if (tid < s) red[tid] += red[tid + s]; __syncthreads(); }
    const float sa = sigmoid_f(red[0] + sab[0]);
    __syncthreads();
    float qq = 0.f;
    #pragma unroll
    for (int i = 0; i < 3; ++i){
        const int c = tid + i * 128;
        x2[i] *= sa;
        qq += x2[i] * decw[c];
    }
    red[tid] = qq; __syncthreads();
    for (int s = 64; s > 0; s >>= 1){ if (tid < s) red[tid] += red[tid + s]; __syncthreads(); }
    const float xg = gelu_f(red[0] + decb[0]);
    #pragma unroll
    for (int i = 0; i < 3; ++i){
        const int c = tid + i * 128;
        const float sg = sigma[c];
        stv(&xr[c], x2[i] + sg * (x2[i] - xg));
    }
}

// o1 = (a+b)/l1[row] ; o2 = (c+d)/l2[row]  (split-K reduce + softmax denom)
__global__ __launch_bounds__(256) void reduce2_k(
    const bf16* __restrict__ a, const bf16* __restrict__ b, bf16* __restrict__ o1,
    const float* __restrict__ l1,
    const bf16* __restrict__ c, const bf16* __restrict__ d, bf16* __restrict__ o2,
    const float* __restrict__ l2)
{
    const size_t i = ((size_t)blockIdx.x * 256 + threadIdx.x) * 8;
    if (i >= (size_t)NB * DM) return;
    const int row = (int)(i / DM);
    const float inv1 = 1.0f / l1[row];
    const float inv2 = 1.0f / l2[row];
    u16x8 ua = *(const u16x8*)((const u16*)a + i);
    u16x8 ub = *(const u16x8*)((const u16*)b + i);
    u16x8 uc = *(const u16x8*)((const u16*)c + i);
    u16x8 ud = *(const u16x8*)((const u16*)d + i);
    u16x8 r1, r2;
    #pragma unroll
    for (int j = 0; j < 8; ++j){
        const float s1 = (__uint_as_float((unsigned)ua[j] << 16) + __uint_as_float((unsigned)ub[j] << 16)) * inv1;
        const float s2 = (__uint_as_float((unsigned)uc[j] << 16) + __uint_as_float((unsigned)ud[j] << 16)) * inv2;
        r1[j] = __bfloat16_as_ushort(__float2bfloat16(s1));
        r2[j] = __bfloat16_as_ushort(__float2bfloat16(s2));
    }
    *(u16x8*)((u16*)o1 + i) = r1;
    *(u16x8*)((u16*)o2 + i) = r2;
}

// Fused gate-combine + classifier + softmax(3). One block per batch row.
__global__ __launch_bounds__(256) void combine_cls_k(
    const bf16* __restrict__ g1, const bf16* __restrict__ a1, const float* __restrict__ s1,
    const bf16* __restrict__ g2, const bf16* __restrict__ a2, const float* __restrict__ s2,
    const float* __restrict__ w, const float* __restrict__ bias, float* __restrict__ out)
{
    __shared__ float r0[256], r1[256], r2[256];
    const int b = blockIdx.x;
    const int tid = threadIdx.x;
    const size_t off = (size_t)b * DM;
    float p0 = 0.f, p1 = 0.f, p2 = 0.f;
    #pragma unroll
    for (int i = 0; i < 3; ++i){
        const int c = tid + i * 256;
        const float v = sigmoid_f(cvt(g1[off + c])) * cvt(a1[off + c]) * s1[c]
                      + sigmoid_f(cvt(g2[off + c])) * cvt(a2[off + c]) * s2[c];
        p0 = fmaf(v, w[c],         p0);
        p1 = fmaf(v, w[DM + c],    p1);
        p2 = fmaf(v, w[2*DM + c],  p2);
    }
    r0[tid] = p0; r1[tid] = p1; r2[tid] = p2; __syncthreads();
    for (int s = 128; s > 0; s >>= 1){
        if (tid < s){ r0[tid] += r0[tid + s]; r1[tid] += r1[tid + s]; r2[tid] += r2[tid + s]; }
        __syncthreads();
    }
    if (tid == 0){
        const float l0 = r0[0] + bias[0];
        const float l1 = r1[0] + bias[1];
        const float l2 = r2[0] + bias[2];
        const float mx = fmaxf(l0, fmaxf(l1, l2));
        const float e0 = __expf(l0 - mx), e1 = __expf(l1 - mx), e2 = __expf(l2 - mx);
        const float inv = 1.f / (e0 + e1 + e2);
        out[(size_t)b * 3 + 0] = e0 * inv;
        out[(size_t)b * 3 + 1] = e1 * inv;
        out[(size_t)b * 3 + 2] = e2 * inv;
    }
}

extern "C" void kernel_launch(void* const* d_in, const int* in_sizes, int n_in,
                              void* d_out, int out_size, void* d_ws, size_t ws_size,
                              hipStream_t stream)
{
    const float* text   = (const float*)d_in[0];
    const float* image  = (const float*)d_in[1];
    const float* tl_w   = (const float*)d_in[2];
    const float* tl_b   = (const float*)d_in[3];
    const float* il_w   = (const float*)d_in[4];
    const float* il_b   = (const float*)d_in[5];
    const float* sda_wv = (const float*)d_in[10];
    const float* sda_bv = (const float*)d_in[11];
    const float* sda_wo = (const float*)d_in[12];
    const float* sda_bo = (const float*)d_in[13];
    const float* fda_w1 = (const float*)d_in[14];
    const float* fda_b1 = (const float*)d_in[15];
    const float* bn1_g  = (const float*)d_in[16];
    const float* bn1_b  = (const float*)d_in[17];
    const float* ca_w1  = (const float*)d_in[18];
    const float* ca_w2  = (const float*)d_in[19];
    const float* sa_w   = (const float*)d_in[20];
    const float* sa_b   = (const float*)d_in[21];
    const float* dec_w  = (const float*)d_in[22];
    const float* dec_b  = (const float*)d_in[23];
    const float* sigma  = (const float*)d_in[24];
    const float* fda_wf = (const float*)d_in[25];
    const float* fda_bf = (const float*)d_in[26];
    const float* bn2_g  = (const float*)d_in[27];
    const float* bn2_b  = (const float*)d_in[28];
    const float* dmi_wq = (const float*)d_in[29];
    const float* dmi_bq = (const float*)d_in[30];
    const float* dmi_wk = (const float*)d_in[31];
    const float* dmi_bk = (const float*)d_in[32];
    const float* dmi_wv = (const float*)d_in[33];
    const float* dmi_bv = (const float*)d_in[34];
    const float* tg_w1  = (const float*)d_in[35];
    const float* tg_b1  = (const float*)d_in[36];
    const float* tg_w2  = (const float*)d_in[37];
    const float* tg_b2  = (const float*)d_in[38];
    const float* ig_w1  = (const float*)d_in[39];
    const float* ig_b1  = (const float*)d_in[40];
    const float* ig_w2  = (const float*)d_in[41];
    const float* ig_b2  = (const float*)d_in[42];
    const float* t_scale= (const float*)d_in[43];
    const float* i_scale= (const float*)d_in[44];
    const float* cls_w  = (const float*)d_in[45];
    const float* cls_b  = (const float*)d_in[46];
    float* out = (float*)d_out;

    // ---- workspace ----
    char* base = (char*)d_ws;
    auto alloc = [&](size_t bytes){ void* p = (void*)base; base += (bytes + 255) & ~(size_t)255; return p; };
    const size_t SLOT = (size_t)NB * DM;
    const size_t W768 = (size_t)768 * 768;
    bf16* tl_wb   = (bf16*)alloc(W768 * 2);
    bf16* il_wb   = (bf16*)alloc(W768 * 2);
    bf16* sda_wvb = (bf16*)alloc((size_t)512 * 768 * 2);
    bf16* sda_wob = (bf16*)alloc((size_t)768 * 512 * 2);
    bf16* fda_wfb = (bf16*)alloc((size_t)768 * 384 * 2);
    bf16* dmi_wqb = (bf16*)alloc(W768 * 2);
    bf16* dmi_wkb = (bf16*)alloc(W768 * 2);
    bf16* dmi_wvb = (bf16*)alloc(W768 * 2);
    bf16* tg_w1b  = (bf16*)alloc(W768 * 2);
    bf16* tg_w2b  = (bf16*)alloc(W768 * 2);
    bf16* ig_w1b  = (bf16*)alloc(W768 * 2);
    bf16* ig_w2b  = (bf16*)alloc(W768 * 2);
    bf16* w1c     = (bf16*)alloc((size_t)384 * 768 * 2);
    float* sac    = (float*)alloc(1536 * 4);
    float* lbuf   = (float*)alloc(2 * NB * 4);               // final denominators [2][NB]
    float* part   = (float*)alloc((size_t)2 * 16 * NB * 4);  // per-chunk partials [2][16][NB]
    bf16* SL[8];
    for (int i = 0; i < 8; ++i) SL[i] = (bf16*)alloc(SLOT * 2);
    bf16* SC1 = (bf16*)alloc((size_t)NB * NB * 2);
    bf16* SC2 = (bf16*)alloc((size_t)NB * NB * 2);

    const float bnscale = 1.0f / sqrtf(1.0f + 1e-5f);
    const float iscale  = 1.0f / sqrtf(768.0f);
    const dim3 blk(256);

    struct JB {
        Jobs jb; int blocks; int tile;
        void add(const bf16* A, const bf16* B, bf16* C, int M, int N, int K, int ldA, int ldB,
                 const float* b0, float al, const float* gv, const float* b1, int act, int trans,
                 float* rs = nullptr){
            Job& j = jb.j[jb.nj++];
            j.A=A; j.B=B; j.C=C; j.b0=b0; j.gv=gv; j.b1=b1; j.rs=rs;
            j.M=M; j.N=N; j.K=K; j.ldA=ldA; j.ldB=ldB; j.act=act; j.trans=trans;
            j.alpha=al; j.blk0=blocks; j.nx=N/tile;
            blocks += (N/tile)*(M/tile);
        }
    };
    auto launch128 = [&](JB& b){ mgemm_k   <<<dim3(b.blocks), dim3(256), 0, stream>>>(b.jb); };
    auto launch256 = [&](JB& b){ mgemm256_k<<<dim3(b.blocks), dim3(512), 0, stream>>>(b.jb); };

    // fp32 -> bf16 staging
    CvtDesc cd;
    const float* srcs[NCVT] = {text, image, tl_w, il_w, sda_wv, sda_wo, fda_wf,
                               dmi_wq, dmi_wk, dmi_wv, tg_w1, tg_w2, ig_w1, ig_w2};
    bf16* dsts[NCVT] = {SL[0], SL[1], tl_wb, il_wb, sda_wvb, sda_wob, fda_wfb,
                        dmi_wqb, dmi_wkb, dmi_wvb, tg_w1b, tg_w2b, ig_w1b, ig_w2b};
    int   lens[NCVT] = {(int)SLOT, (int)SLOT, (int)W768, (int)W768, 512*768, 768*512, 768*384,
                        (int)W768, (int)W768, (int)W768, (int)W768, (int)W768, (int)W768, (int)W768};
    for (int i = 0; i < NCVT; ++i){ cd.s[i] = srcs[i]; cd.d[i] = dsts[i]; cd.n[i] = lens[i]; }
    cvt_k<<<dim3((int)(SLOT / 1024), NCVT), blk, 0, stream>>>(cd);
    extract_k<<<dim3((384 * 768 + 255) / 256), blk, 0, stream>>>(fda_w1, sa_w, w1c, sac);

    // J1: t0 = gelu(text@tl^T) -> SL2 ; im0 = gelu(image@il^T) -> SL3   [256-tile]
    { JB b{}; b.tile=256;
      b.add(SL[0], tl_wb, SL[2], NB, DM, DM, DM, DM, tl_b, 1.f, nullptr, nullptr, 1, 0);
      b.add(SL[1], il_wb, SL[3], NB, DM, DM, DM, DM, il_b, 1.f, nullptr, nullptr, 1, 0); launch256(b); }
    // J2: wv = t0@wv^T -> SL0 (N=512) ; x1 = conv1(im0) -> SL1 (N=384)  [128-tile: N=384]
    { JB b{}; b.tile=128;
      b.add(SL[2], sda_wvb, SL[0], NB, 512, DM, DM, DM, sda_bv, 1.f, nullptr, nullptr, 0, 0);
      b.add(SL[3], w1c,     SL[1], NB, 384, DM, DM, DM, fda_b1, bnscale, bn1_g, bn1_b, 1, 0); launch128(b); }
    // fused FDA tail (in place on SL1)
    fda_fused_k<<<dim3(NB), dim3(128), 0, stream>>>(SL[1], ca_w1, ca_w2, sac, sa_b, dec_w, dec_b, sigma);
    // J34: t1 = wv@wo^T -> SL4 (K=512) ; im1 = gelu((x4@wf^T+bf)*bn2) -> SL5 (K=384)  [256-tile]
    { JB b{}; b.tile=256;
      b.add(SL[0], sda_wob, SL[4], NB, DM, 512, 512, 512, sda_bo, 1.f, nullptr, nullptr, 0, 0);
      b.add(SL[1], fda_wfb, SL[5], NB, DM, 384, 384, 384, fda_bf, bnscale, bn2_g, bn2_b, 1, 0); launch256(b); }

    // J5: QKV both directions (6 jobs)  [256-tile]
    { JB b{}; b.tile=256;
      b.add(SL[4], dmi_wqb, SL[0], NB, DM, DM, DM, DM, dmi_bq, 1.f, nullptr, nullptr, 0, 0);
      b.add(SL[5], dmi_wkb, SL[1], NB, DM, DM, DM, DM, dmi_bk, 1.f, nullptr, nullptr, 0, 0);
      b.add(SL[5], dmi_wvb, SL[2], NB, DM, DM, DM, DM, dmi_bv, 1.f, nullptr, nullptr, 0, 1);
      b.add(SL[5], dmi_wqb, SL[3], NB, DM, DM, DM, DM, dmi_bq, 1.f, nullptr, nullptr, 0, 0);
      b.add(SL[4], dmi_wkb, SL[6], NB, DM, DM, DM, DM, dmi_bk, 1.f, nullptr, nullptr, 0, 0);
      b.add(SL[4], dmi_wvb, SL[7], NB, DM, DM, DM, DM, dmi_bv, 1.f, nullptr, nullptr, 0, 1);
      launch256(b); }
    // J6: scores with fused exp + per-block partial row sums (16 chunks)  [256-tile]
    { JB b{}; b.tile=256;
      b.add(SL[0], SL[1], SC1, NB, NB, DM, DM, DM, nullptr, iscale, nullptr, nullptr, 4, 0, part);
      b.add(SL[3], SL[6], SC2, NB, NB, DM, DM, DM, nullptr, iscale, nullptr, nullptr, 4, 0, part + 16 * NB); launch256(b); }
    // reduce partials -> lbuf
    denom_k<<<dim3((2 * NB + 255) / 256), blk, 0, stream>>>(part, lbuf);
    // J7: PV split-K=2 x 2 dirs (4 jobs) on unnormalized exp-scores  [256-tile]
    { JB b{}; b.tile=256;
      b.add(SC1,        SL[2],        SL[0], NB, DM, 2048, NB, NB, nullptr, 1.f, nullptr, nullptr, 0, 0);
      b.add(SC1 + 2048, SL[2] + 2048, SL[1], NB, DM, 2048, NB, NB, nullptr, 1.f, nullptr, nullptr, 0, 0);
      b.add(SC2,        SL[7],        SL[3], NB, DM, 2048, NB, NB, nullptr, 1.f, nullptr, nullptr, 0, 0);
      b.add(SC2 + 2048, SL[7] + 2048, SL[6], NB, DM, 2048, NB, NB, nullptr, 1.f, nullptr, nullptr, 0, 0);
      launch256(b); }
    // a1 = (SL0+SL1)/l1 -> SL4 ; a2 = (SL3+SL6)/l2 -> SL5
    reduce2_k<<<dim3((int)(SLOT / 2048)), blk, 0, stream>>>(SL[0], SL[1], SL[4], lbuf,
                                                           SL[3], SL[6], SL[5], lbuf + NB);
    // J8/J9: gates  [256-tile]
    { JB b{}; b.tile=256;
      b.add(SL[4], tg_w1b, SL[0], NB, DM, DM, DM, DM, tg_b1, 1.f, nullptr, nullptr, 3, 0);
      b.add(SL[5], ig_w1b, SL[1], NB, DM, DM, DM, DM, ig_b1, 1.f, nullptr, nullptr, 3, 0); launch256(b); }
    { JB b{}; b.tile=256;
      b.add(SL[0], tg_w2b, SL[3], NB, DM, DM, DM, DM, tg_b2, 1.f, nullptr, nullptr, 2, 0);
      b.add(SL[1], ig_w2b, SL[6], NB, DM, DM, DM, DM, ig_b2, 1.f, nullptr, nullptr, 2, 0); launch256(b); }
    // fused combine + classifier + softmax
    combine_cls_k<<<dim3(NB), blk, 0, stream>>>(SL[3], SL[4], t_scale, SL[6], SL[5], i_scale,
                                                cls_w, cls_b, out);
}

// Round 4
// 2644.746 us; speedup vs baseline: 1.2243x; 1.2230x over previous
//
#include <hip/hip_runtime.h>
#include <hip/hip_bf16.h>
#include <math.h>

typedef __hip_bfloat16 bf16;
typedef __bf16 bf16x8 __attribute__((ext_vector_type(8)));
typedef float f32x4 __attribute__((ext_vector_type(4)));
typedef unsigned short u16;
typedef u16 u16x8 __attribute__((ext_vector_type(8)));

#define NB 4096          // batch rows
#define DM 768           // model dim

__device__ __forceinline__ float cvt(float x){ return x; }
__device__ __forceinline__ float cvt(bf16 x){ return __bfloat162float(x); }
__device__ __forceinline__ void stv(float* p, float v){ *p = v; }
__device__ __forceinline__ void stv(bf16* p, float v){ *p = __float2bfloat16(v); }

__device__ __forceinline__ float gelu_f(float x){
    return 0.5f * x * (1.0f + erff(x * 0.70710678118654752440f));
}
__device__ __forceinline__ float sigmoid_f(float x){
    return 1.0f / (1.0f + __expf(-x));
}

__device__ __forceinline__ void async_copy16(const void* g, void* l){
    __builtin_amdgcn_global_load_lds((const __attribute__((address_space(1))) void*)g,
                                     (__attribute__((address_space(3))) void*)l, 16, 0, 0);
}

// ---------------------------------------------------------------------------
// Job descriptor shared by both GEMM kernels.
// Per job: C = act((A @ Bm^T + b0) * alpha * gv + b1)
// act: 0 none, 1 gelu, 2 sigmoid, 3 relu, 4 exp.
// rs != nullptr: block (gx,gy) writes its per-row tile sums to rs[gx*M + row].
// A: (M,ldA) bf16 cols [0,K). Bm: (N,ldB) bf16 (B^T layout) cols [0,K).
// trans=1: store C^T into (N,M).
// ---------------------------------------------------------------------------
#define MAXJ 8
struct Job {
    const bf16* A; const bf16* B; bf16* C;
    const float* b0; const float* gv; const float* b1;
    float* rs;
    int M, N, K, ldA, ldB, act, trans, blk0, nx;
    float alpha;
};
struct Jobs { Job j[MAXJ]; int nj; };

// ---------------------------------------------------------------------------
// Legacy 128x128 kernel (kept for shapes not divisible by 256: J2's N=384).
// ---------------------------------------------------------------------------
__global__ __launch_bounds__(256) void mgemm_k(Jobs jb)
{
    int z = 0;
    #pragma unroll
    for (int i = 1; i < MAXJ; ++i)
        if (i < jb.nj && (int)blockIdx.x >= jb.j[i].blk0) z = i;
    const Job& J = jb.j[z];
    const bf16* __restrict__ A  = J.A;
    const bf16* __restrict__ Bm = J.B;
    bf16* __restrict__ C        = J.C;
    const int bx = (int)blockIdx.x - J.blk0;
    const int gx = bx % J.nx;
    const int gy = bx / J.nx;
    const int M = J.M, N = J.N, K = J.K, ldA = J.ldA, ldB = J.ldB;

    __shared__ __align__(16) bf16 smem[17408];
    const int tid  = threadIdx.x;
    const int wave = tid >> 6;
    const int lane = tid & 63;
    const int row0 = gy * 128;
    const int col0 = gx * 128;
    const int wrow = (wave & 1) * 64;
    const int wcol = (wave >> 1) * 64;
    const int fl   = lane & 15;
    const int q    = lane >> 4;

    const int sr8 = lane >> 3;
    const int sc8 = (((lane & 7) ^ sr8)) * 8;
    const bf16* pA = A  + (size_t)(row0 + wave * 32 + sr8) * ldA + sc8;
    const bf16* pB = Bm + (size_t)(col0 + wave * 32 + sr8) * ldB + sc8;
    bf16* ldsA = &smem[(wave * 32) * 64];
    bf16* ldsB = &smem[8192 + (wave * 32) * 64];

    f32x4 acc[4][4] = {};
    for (int k0 = 0; k0 < K; k0 += 64){
        #pragma unroll
        for (int i = 0; i < 4; ++i){
            async_copy16(pA + (size_t)(i * 8) * ldA, ldsA + i * 512);
            async_copy16(pB + (size_t)(i * 8) * ldB, ldsB + i * 512);
        }
        pA += 64; pB += 64;
        __syncthreads();
        #pragma unroll
        for (int ks = 0; ks < 2; ++ks){
            bf16x8 af[4], bfv[4];
            #pragma unroll
            for (int i = 0; i < 4; ++i){
                const int ra = wrow + i * 16 + fl;
                const int rb = wcol + i * 16 + fl;
                const int ca = ((ks * 4 + q) ^ (ra & 7)) * 8;
                const int cb = ((ks * 4 + q) ^ (rb & 7)) * 8;
                af[i]  = *(const bf16x8*)&smem[ra * 64 + ca];
                bfv[i] = *(const bf16x8*)&smem[8192 + rb * 64 + cb];
            }
            #pragma unroll
            for (int mi = 0; mi < 4; ++mi)
                #pragma unroll
                for (int ni = 0; ni < 4; ++ni)
                    acc[mi][ni] = __builtin_amdgcn_mfma_f32_16x16x32_bf16(af[mi], bfv[ni], acc[mi][ni], 0, 0, 0);
        }
        __syncthreads();
    }

    constexpr int ELD = 136;
    #pragma unroll
    for (int ni = 0; ni < 4; ++ni){
        const int col = col0 + wcol + ni * 16 + fl;
        const float b0 = J.b0 ? J.b0[col] : 0.f;
        const float gm = (J.gv ? J.gv[col] : 1.f) * J.alpha;
        const float b1 = J.b1 ? J.b1[col] : 0.f;
        const int lcol = wcol + ni * 16 + fl;
        #pragma unroll
        for (int mi = 0; mi < 4; ++mi){
            const int lrow = wrow + mi * 16 + q * 4;
            #pragma unroll
            for (int r = 0; r < 4; ++r){
                float v = (acc[mi][ni][r] + b0) * gm + b1;
                if      (J.act == 1) v = gelu_f(v);
                else if (J.act == 2) v = sigmoid_f(v);
                else if (J.act == 3) v = fmaxf(v, 0.f);
                else if (J.act == 4) v = __expf(v);
                if (J.trans) smem[(size_t)lcol * ELD + lrow + r] = __float2bfloat16(v);
                else         smem[(size_t)(lrow + r) * ELD + lcol] = __float2bfloat16(v);
            }
        }
    }
    __syncthreads();
    const int erow = tid >> 4;
    const int ecol = (tid & 15) * 8;
    #pragma unroll
    for (int p = 0; p < 8; ++p){
        const int row = p * 16 + erow;
        const u16x8 uv = *(const u16x8*)&smem[row * ELD + ecol];
        if (J.trans) *(u16x8*)&C[(size_t)(col0 + row) * M + row0 + ecol] = uv;
        else         *(u16x8*)&C[(size_t)(row0 + row) * N + col0 + ecol] = uv;
        if (J.rs){
            float s = 0.f;
            #pragma unroll
            for (int j = 0; j < 8; ++j) s += __uint_as_float((unsigned)uv[j] << 16);
            s += __shfl_down(s, 8, 16);
            s += __shfl_down(s, 4, 16);
            s += __shfl_down(s, 2, 16);
            s += __shfl_down(s, 1, 16);
            if ((tid & 15) == 0) J.rs[(size_t)gx * M + row0 + row] = s;
        }
    }
}

// ---------------------------------------------------------------------------
// 256x256 8-phase kernel, 256 threads = 4 waves (2M x 2N), per-wave 128x128.
// BK=64, 2 K-tiles per iteration, 128 KiB LDS. Requires M,N%256==0, K%128==0,
// K>=256.
//
// WHY 256 THREADS (R1-R3 lesson): this toolchain pins 512-thread kernels to a
// 128-reg unified budget (all three register directives ignored; VGPR_Count
// 128, catastrophic acc spill, MfmaUtil 2%). 256-thread kernels are the only
// class with proven larger budgets here. acc 8x8xf32x4 = 256 regs + frags 96
// + addressing ~20 => ~370, under the ~450 no-spill line. LDS 128 KiB =>
// 1 WG/CU (4 waves, 1/SIMD): all latency hiding comes from the counted-vmcnt
// pipeline, none from TLP.
//
// INTERLEAVED STAGING HALVES (R3 race fix): waves read wave-LOCAL halves
// (rows wm*128 + mh*64 + [0,64)), i.e. half mh = rows {mh*64+[0,64)} u
// {128+mh*64+[0,64)}. Staging "half h" now targets exactly that interleaved
// set, so every same-window stage/read pair is disjoint:
//   ph3 stages A.h0 {0-63,128-191} while ph3 reads A.mh1 {64-127,192-255}.
// (The R1 version staged global halves h*128+[0,128) and raced at ph3/ph7;
// it only passed because the spilled binary serialized memory.)
//
// Staging schedule (steady state, tiles E=2i buf0 / O=2i+1 buf1):
//   ph1 O.A1  ph2 O.B1  ph3 (E+2).A0  ph4 (E+2).B0
//   ph5 (E+2).A1  ph6 (E+2).B1  ph7 (O+2).A0  ph8 (O+2).B0
// Each SA/SB = 4 global_load_lds. vmcnt(8) at ph4/ph8 leaves exactly the 2
// newest stages (8 loads) in flight and guarantees the awaited K-tile fully
// landed (derivation: 2 stages issued since that tile's last stage).
// ---------------------------------------------------------------------------
__global__ __launch_bounds__(256, 1) void mgemm256_k(Jobs jb)
{
    int z = 0;
    #pragma unroll
    for (int i = 1; i < MAXJ; ++i)
        if (i < jb.nj && (int)blockIdx.x >= jb.j[i].blk0) z = i;
    const Job& J = jb.j[z];
    const bf16* __restrict__ A  = J.A;
    const bf16* __restrict__ Bm = J.B;
    bf16* __restrict__ C        = J.C;
    const int bx = (int)blockIdx.x - J.blk0;
    const int gx = bx % J.nx;
    const int gy = bx / J.nx;
    const int M = J.M, N = J.N, ldA = J.ldA, ldB = J.ldB;
    const int NH = J.K >> 7;                  // iterations, 2 K-tiles each

    __shared__ __align__(16) bf16 smem[65536];   // 128 KiB: A[2][256][64], B[2][256][64]
    const int tid  = threadIdx.x;
    const int w    = tid >> 6;                // 0..3
    const int lane = tid & 63;
    const int wm   = w >> 1;                  // 0..1
    const int wn   = w & 1;                   // 0..1
    const int fl   = lane & 15;
    const int q    = lane >> 4;
    const int row0 = gy * 256;
    const int col0 = gx * 256;

    // staging: per global_load_lds a wave covers 8 rows x 64 cols (1 KiB).
    // phys chunk (lane&7) at row r holds logical chunk (lane&7)^(r&7).
    // wave w covers rows arow + h*64 + i*8 (+sr), i=0..3 -- the interleaved
    // half-h set {h*64+[0,64)} u {128+h*64+[0,64)} across the 4 waves.
    const int sr   = lane >> 3;
    const int sc   = ((lane & 7) ^ sr) * 8;
    const int arow = (w >> 1) * 128 + (w & 1) * 32;
    const bf16* aSw = A  + (size_t)(row0 + arow + sr) * ldA + sc;
    const bf16* bSw = Bm + (size_t)(col0 + arow + sr) * ldB + sc;
    bf16* aLw = &smem[arow * 64];
    bf16* bLw = &smem[32768 + arow * 64];

    auto SA = [&](int t, int h, int bb){
        const bf16* g = aSw + (size_t)(h * 64) * ldA + t * 64;
        bf16* l = aLw + bb * 16384 + h * 4096;
        #pragma unroll
        for (int i = 0; i < 4; ++i)
            async_copy16(g + (size_t)(i * 8) * ldA, l + i * 512);
    };
    auto SB = [&](int t, int h, int bb){
        const bf16* g = bSw + (size_t)(h * 64) * ldB + t * 64;
        bf16* l = bLw + bb * 16384 + h * 4096;
        #pragma unroll
        for (int i = 0; i < 4; ++i)
            async_copy16(g + (size_t)(i * 8) * ldB, l + i * 512);
    };

    // fragment read offsets (row&7 == fl&7 for every frag row)
    const int aoff0 = fl * 64 + ((q       ^ (fl & 7)) * 8);   // k-chunk q
    const int aoff1 = fl * 64 + (((4 + q) ^ (fl & 7)) * 8);   // k-chunk 4+q

    // Named fragment arrays, ONLY compile-time indices (macros) -- keeps SROA
    // able to promote everything to registers.
    bf16x8 fa[8];          // A half: 4 m-frags x 2 ks
    bf16x8 fb0[8], fb1[8]; // B halves: 4 n-frags x 2 ks each
    f32x4 acc[8][8] = {};

    #define RDA(bb, mh) do {                                                   \
        const bf16* ab_ = &smem[(bb) * 16384 + wm * 8192 + (mh) * 4096];       \
        _Pragma("unroll")                                                      \
        for (int j_ = 0; j_ < 4; ++j_){                                        \
            fa[j_ * 2 + 0] = *(const bf16x8*)&ab_[j_ * 1024 + aoff0];          \
            fa[j_ * 2 + 1] = *(const bf16x8*)&ab_[j_ * 1024 + aoff1];          \
        }                                                                      \
    } while (0)
    #define RDB(FB, bb, nh) do {                                               \
        const bf16* bb_ = &smem[32768 + (bb) * 16384 + wn * 8192 + (nh) * 4096];\
        _Pragma("unroll")                                                      \
        for (int n_ = 0; n_ < 4; ++n_){                                        \
            FB[n_ * 2 + 0] = *(const bf16x8*)&bb_[n_ * 1024 + aoff0];          \
            FB[n_ * 2 + 1] = *(const bf16x8*)&bb_[n_ * 1024 + aoff1];          \
        }                                                                      \
    } while (0)
    #define QM(mh, nh, FB) do {                                                \
        __builtin_amdgcn_s_setprio(1);                                         \
        _Pragma("unroll")                                                      \
        for (int j_ = 0; j_ < 4; ++j_){                                        \
            _Pragma("unroll")                                                  \
            for (int n_ = 0; n_ < 4; ++n_){                                    \
                acc[(mh)*4 + j_][(nh)*4 + n_] = __builtin_amdgcn_mfma_f32_16x16x32_bf16( \
                    fa[j_*2 + 0], FB[n_*2 + 0], acc[(mh)*4 + j_][(nh)*4 + n_], 0, 0, 0); \
                acc[(mh)*4 + j_][(nh)*4 + n_] = __builtin_amdgcn_mfma_f32_16x16x32_bf16( \
                    fa[j_*2 + 1], FB[n_*2 + 1], acc[(mh)*4 + j_][(nh)*4 + n_], 0, 0, 0); \
            }                                                                  \
        }                                                                      \
        __builtin_amdgcn_s_setprio(0);                                         \
    } while (0)
    #define BAR()  __builtin_amdgcn_s_barrier()
    #define LGKM() asm volatile("s_waitcnt lgkmcnt(0)" ::: "memory")

    // prologue: tile0 fully + tile1 first halves (24 loads); vmcnt(8) -> tile0 landed
    SA(0, 0, 0); SB(0, 0, 0); SA(0, 1, 0); SB(0, 1, 0); SA(1, 0, 1); SB(1, 0, 1);
    asm volatile("s_waitcnt vmcnt(8)" ::: "memory");
    BAR();

    for (int i = 0; i < NH; ++i){
        const int E = 2 * i, O = 2 * i + 1;
        const bool pf = (i + 1 < NH);
        // ph1: Q(0,0) of E
        RDA(0, 0); RDB(fb0, 0, 0); SA(O, 1, 1);
        BAR(); LGKM(); QM(0, 0, fb0); BAR();
        // ph2: Q(0,1) of E
        RDB(fb1, 0, 1); SB(O, 1, 1);
        BAR(); LGKM(); QM(0, 1, fb1); BAR();
        // ph3: Q(1,0) of E (reads A.mh1 -- disjoint from SA's h0 rows)
        RDA(0, 1); if (pf) SA(E + 2, 0, 0);
        BAR(); LGKM(); QM(1, 0, fb0); BAR();
        // ph4: Q(1,1) of E; counted wait -> tile O fully landed
        if (pf){ SB(E + 2, 0, 0); asm volatile("s_waitcnt vmcnt(8)" ::: "memory"); }
        else   { asm volatile("s_waitcnt vmcnt(0)" ::: "memory"); }
        BAR(); LGKM(); QM(1, 1, fb1); BAR();
        // ph5: Q(0,0) of O
        RDA(1, 0); RDB(fb0, 1, 0); if (pf) SA(E + 2, 1, 0);
        BAR(); LGKM(); QM(0, 0, fb0); BAR();
        // ph6: Q(0,1) of O
        RDB(fb1, 1, 1); if (pf) SB(E + 2, 1, 0);
        BAR(); LGKM(); QM(0, 1, fb1); BAR();
        // ph7: Q(1,0) of O
        RDA(1, 1); if (pf) SA(O + 2, 0, 1);
        BAR(); LGKM(); QM(1, 0, fb0); BAR();
        // ph8: Q(1,1) of O; counted wait -> tile E+2 fully landed
        if (pf){ SB(O + 2, 0, 1); asm volatile("s_waitcnt vmcnt(8)" ::: "memory"); }
        else   { asm volatile("s_waitcnt vmcnt(0)" ::: "memory"); }
        BAR(); LGKM(); QM(1, 1, fb1); BAR();
    }
    #undef BAR
    #undef LGKM
    #undef RDA
    #undef RDB
    #undef QM

    // epilogue: two 128-row (or 128-N-row for trans) passes through LDS scratch
    float cb0[8], cgm[8], cb1[8];
    #pragma unroll
    for (int ni = 0; ni < 8; ++ni){
        const int col = col0 + wn * 128 + ni * 16 + fl;
        cb0[ni] = J.b0 ? J.b0[col] : 0.f;
        cgm[ni] = (J.gv ? J.gv[col] : 1.f) * J.alpha;
        cb1[ni] = J.b1 ? J.b1[col] : 0.f;
    }
    constexpr int ELD = 264;
    const int erow = tid >> 5;            // 0..7
    const int ecol = (tid & 31) * 8;      // 16 B chunk, covers 256 cols
    for (int p = 0; p < 2; ++p){
        __syncthreads();
        const bool mine = J.trans ? (wn == p) : (wm == p);
        if (mine){
            #pragma unroll
            for (int ni = 0; ni < 8; ++ni)
                #pragma unroll
                for (int mi = 0; mi < 8; ++mi)
                    #pragma unroll
                    for (int r = 0; r < 4; ++r){
                        float v = (acc[mi][ni][r] + cb0[ni]) * cgm[ni] + cb1[ni];
                        if      (J.act == 1) v = gelu_f(v);
                        else if (J.act == 2) v = sigmoid_f(v);
                        else if (J.act == 3) v = fmaxf(v, 0.f);
                        else if (J.act == 4) v = __expf(v);
                        if (J.trans)
                            smem[(size_t)(ni * 16 + fl) * ELD + wm * 128 + mi * 16 + q * 4 + r] = __float2bfloat16(v);
                        else
                            smem[(size_t)(mi * 16 + q * 4 + r) * ELD + wn * 128 + ni * 16 + fl] = __float2bfloat16(v);
                    }
        }
        __syncthreads();
        #pragma unroll
        for (int s = 0; s < 16; ++s){
            const int row = s * 8 + erow;
            const u16x8 uv = *(const u16x8*)&smem[row * ELD + ecol];
            if (J.trans) *(u16x8*)&C[(size_t)(col0 + p * 128 + row) * M + row0 + ecol] = uv;
            else         *(u16x8*)&C[(size_t)(row0 + p * 128 + row) * N + col0 + ecol] = uv;
            if (J.rs){
                float sv = 0.f;
                #pragma unroll
                for (int jj = 0; jj < 8; ++jj) sv += __uint_as_float((unsigned)uv[jj] << 16);
                sv += __shfl_down(sv, 16, 32);
                sv += __shfl_down(sv, 8, 32);
                sv += __shfl_down(sv, 4, 32);
                sv += __shfl_down(sv, 2, 32);
                sv += __shfl_down(sv, 1, 32);
                if ((tid & 31) == 0) J.rs[(size_t)gx * M + row0 + p * 128 + row] = sv;
            }
        }
    }
}

// Reduce 16 per-chunk partials per row into the softmax denominator.
// part layout: [2 dirs][16 chunks][NB rows]; l: [2][NB].
__global__ __launch_bounds__(256) void denom_k(const float* __restrict__ part, float* __restrict__ l)
{
    const int t = blockIdx.x * 256 + threadIdx.x;     // 0 .. 2*NB-1
    if (t >= 2 * NB) return;
    const int dir = t >> 12, row = t & (NB - 1);
    const float* p = part + (size_t)dir * 16 * NB + row;
    float s = 0.f;
    #pragma unroll
    for (int c = 0; c < 16; ++c) s += p[(size_t)c * NB];
    l[t] = s;
}

// Batched fp32 -> bf16 conversion
#define NCVT 14
struct CvtDesc { const float* s[NCVT]; bf16* d[NCVT]; int n[NCVT]; };
__global__ __launch_bounds__(256) void cvt_k(CvtDesc cd)
{
    const int e = blockIdx.y;
    const int base = (blockIdx.x * 256 + threadIdx.x) * 4;
    if (base >= cd.n[e]) return;
    const float4 v = *(const float4*)(cd.s[e] + base);
    union { bf16 h[4]; unsigned long long u; } o;
    o.h[0] = __float2bfloat16(v.x);
    o.h[1] = __float2bfloat16(v.y);
    o.h[2] = __float2bfloat16(v.z);
    o.h[3] = __float2bfloat16(v.w);
    *(unsigned long long*)(cd.d[e] + base) = o.u;
}

__global__ __launch_bounds__(256) void extract_k(
    const float* __restrict__ w1, const float* __restrict__ saw,
    bf16* __restrict__ w1c, float* __restrict__ sac)
{
    const int idx = blockIdx.x * 256 + threadIdx.x;
    if (idx < 384 * 768){
        const int oc = idx / 768, ic = idx % 768;
        w1c[idx] = __float2bfloat16(w1[(size_t)oc * 6912 + (size_t)ic * 9 + 4]);
    }
    if (idx < 384) sac[idx] = saw[(size_t)idx * 49 + 24];
}

// Fused FDA tail: ca1 -> ca2 -> x2 -> sa -> x3 -> dec -> x4, in place
__global__ __launch_bounds__(128) void fda_fused_k(
    bf16* __restrict__ x, const float* __restrict__ wc1, const float* __restrict__ wc2,
    const float* __restrict__ sac, const float* __restrict__ sab,
    const float* __restrict__ decw, const float* __restrict__ decb,
    const float* __restrict__ sigma)
{
    __shared__ float xs[384];
    __shared__ float ca1s[24];
    __shared__ float red[128];
    const int b = blockIdx.x;
    const int tid = threadIdx.x;
    bf16* xr = x + (size_t)b * 384;
    #pragma unroll
    for (int i = 0; i < 3; ++i) xs[tid + i * 128] = cvt(xr[tid + i * 128]);
    __syncthreads();
    if (tid < 96){
        const int o = tid >> 2, sub = tid & 3;
        const float* w = wc1 + (size_t)o * 384 + sub * 96;
        float p = 0.f;
        #pragma unroll 8
        for (int k = 0; k < 96; ++k) p = fmaf(xs[sub * 96 + k], w[k], p);
        p += __shfl_down(p, 1, 64);
        p += __shfl_down(p, 2, 64);
        if (sub == 0) ca1s[o] = gelu_f(p);
    }
    __syncthreads();
    float x2[3];
    float p = 0.f;
    #pragma unroll
    for (int i = 0; i < 3; ++i){
        const int c = tid + i * 128;
        float s = 0.f;
        const float* w = wc2 + (size_t)c * 24;
        #pragma unroll
        for (int k = 0; k < 24; ++k) s = fmaf(ca1s[k], w[k], s);
        const float v = xs[c] * sigmoid_f(s);
        x2[i] = v;
        p += v * sac[c];
    }
    red[tid] = p; __syncthreads();
    for (int s = 64; s > 0; s >>= 1){ if (tid < s) red[tid] += red[tid + s]; __syncthreads(); }
    const float sa = sigmoid_f(red[0] + sab[0]);
    __syncthreads();
    float qq = 0.f;
    #pragma unroll
    for (int i = 0; i < 3; ++i){
        const int c = tid + i * 128;
        x2[i] *= sa;
        qq += x2[i] * decw[c];
    }
    red[tid] = qq; __syncthreads();
    for (int s = 64; s > 0; s >>= 1){ if (tid < s) red[tid] += red[tid + s]; __syncthreads(); }
    const float xg = gelu_f(red[0] + decb[0]);
    #pragma unroll
    for (int i = 0; i < 3; ++i){
        const int c = tid + i * 128;
        const float sg = sigma[c];
        stv(&xr[c], x2[i] + sg * (x2[i] - xg));
    }
}

// o1 = (a+b)/l1[row] ; o2 = (c+d)/l2[row]  (split-K reduce + softmax denom)
__global__ __launch_bounds__(256) void reduce2_k(
    const bf16* __restrict__ a, const bf16* __restrict__ b, bf16* __restrict__ o1,
    const float* __restrict__ l1,
    const bf16* __restrict__ c, const bf16* __restrict__ d, bf16* __restrict__ o2,
    const float* __restrict__ l2)
{
    const size_t i = ((size_t)blockIdx.x * 256 + threadIdx.x) * 8;
    if (i >= (size_t)NB * DM) return;
    const int row = (int)(i / DM);
    const float inv1 = 1.0f / l1[row];
    const float inv2 = 1.0f / l2[row];
    u16x8 ua = *(const u16x8*)((const u16*)a + i);
    u16x8 ub = *(const u16x8*)((const u16*)b + i);
    u16x8 uc = *(const u16x8*)((const u16*)c + i);
    u16x8 ud = *(const u16x8*)((const u16*)d + i);
    u16x8 r1, r2;
    #pragma unroll
    for (int j = 0; j < 8; ++j){
        const float s1 = (__uint_as_float((unsigned)ua[j] << 16) + __uint_as_float((unsigned)ub[j] << 16)) * inv1;
        const float s2 = (__uint_as_float((unsigned)uc[j] << 16) + __uint_as_float((unsigned)ud[j] << 16)) * inv2;
        r1[j] = __bfloat16_as_ushort(__float2bfloat16(s1));
        r2[j] = __bfloat16_as_ushort(__float2bfloat16(s2));
    }
    *(u16x8*)((u16*)o1 + i) = r1;
    *(u16x8*)((u16*)o2 + i) = r2;
}

// Fused gate-combine + classifier + softmax(3). One block per batch row.
__global__ __launch_bounds__(256) void combine_cls_k(
    const bf16* __restrict__ g1, const bf16* __restrict__ a1, const float* __restrict__ s1,
    const bf16* __restrict__ g2, const bf16* __restrict__ a2, const float* __restrict__ s2,
    const float* __restrict__ w, const float* __restrict__ bias, float* __restrict__ out)
{
    __shared__ float r0[256], r1[256], r2[256];
    const int b = blockIdx.x;
    const int tid = threadIdx.x;
    const size_t off = (size_t)b * DM;
    float p0 = 0.f, p1 = 0.f, p2 = 0.f;
    #pragma unroll
    for (int i = 0; i < 3; ++i){
        const int c = tid + i * 256;
        const float v = sigmoid_f(cvt(g1[off + c])) * cvt(a1[off + c]) * s1[c]
                      + sigmoid_f(cvt(g2[off + c])) * cvt(a2[off + c]) * s2[c];
        p0 = fmaf(v, w[c],         p0);
        p1 = fmaf(v, w[DM + c],    p1);
        p2 = fmaf(v, w[2*DM + c],  p2);
    }
    r0[tid] = p0; r1[tid] = p1; r2[tid] = p2; __syncthreads();
    for (int s = 128; s > 0; s >>= 1){
        if (tid < s){ r0[tid] += r0[tid + s]; r1[tid] += r1[tid + s]; r2[tid] += r2[tid + s]; }
        __syncthreads();
    }
    if (tid == 0){
        const float l0 = r0[0] + bias[0];
        const float l1 = r1[0] + bias[1];
        const float l2 = r2[0] + bias[2];
        const float mx = fmaxf(l0, fmaxf(l1, l2));
        const float e0 = __expf(l0 - mx), e1 = __expf(l1 - mx), e2 = __expf(l2 - mx);
        const float inv = 1.f / (e0 + e1 + e2);
        out[(size_t)b * 3 + 0] = e0 * inv;
        out[(size_t)b * 3 + 1] = e1 * inv;
        out[(size_t)b * 3 + 2] = e2 * inv;
    }
}

extern "C" void kernel_launch(void* const* d_in, const int* in_sizes, int n_in,
                              void* d_out, int out_size, void* d_ws, size_t ws_size,
                              hipStream_t stream)
{
    const float* text   = (const float*)d_in[0];
    const float* image  = (const float*)d_in[1];
    const float* tl_w   = (const float*)d_in[2];
    const float* tl_b   = (const float*)d_in[3];
    const float* il_w   = (const float*)d_in[4];
    const float* il_b   = (const float*)d_in[5];
    const float* sda_wv = (const float*)d_in[10];
    const float* sda_bv = (const float*)d_in[11];
    const float* sda_wo = (const float*)d_in[12];
    const float* sda_bo = (const float*)d_in[13];
    const float* fda_w1 = (const float*)d_in[14];
    const float* fda_b1 = (const float*)d_in[15];
    const float* bn1_g  = (const float*)d_in[16];
    const float* bn1_b  = (const float*)d_in[17];
    const float* ca_w1  = (const float*)d_in[18];
    const float* ca_w2  = (const float*)d_in[19];
    const float* sa_w   = (const float*)d_in[20];
    const float* sa_b   = (const float*)d_in[21];
    const float* dec_w  = (const float*)d_in[22];
    const float* dec_b  = (const float*)d_in[23];
    const float* sigma  = (const float*)d_in[24];
    const float* fda_wf = (const float*)d_in[25];
    const float* fda_bf = (const float*)d_in[26];
    const float* bn2_g  = (const float*)d_in[27];
    const float* bn2_b  = (const float*)d_in[28];
    const float* dmi_wq = (const float*)d_in[29];
    const float* dmi_bq = (const float*)d_in[30];
    const float* dmi_wk = (const float*)d_in[31];
    const float* dmi_bk = (const float*)d_in[32];
    const float* dmi_wv = (const float*)d_in[33];
    const float* dmi_bv = (const float*)d_in[34];
    const float* tg_w1  = (const float*)d_in[35];
    const float* tg_b1  = (const float*)d_in[36];
    const float* tg_w2  = (const float*)d_in[37];
    const float* tg_b2  = (const float*)d_in[38];
    const float* ig_w1  = (const float*)d_in[39];
    const float* ig_b1  = (const float*)d_in[40];
    const float* ig_w2  = (const float*)d_in[41];
    const float* ig_b2  = (const float*)d_in[42];
    const float* t_scale= (const float*)d_in[43];
    const float* i_scale= (const float*)d_in[44];
    const float* cls_w  = (const float*)d_in[45];
    const float* cls_b  = (const float*)d_in[46];
    float* out = (float*)d_out;

    // ---- workspace ----
    char* base = (char*)d_ws;
    auto alloc = [&](size_t bytes){ void* p = (void*)base; base += (bytes + 255) & ~(size_t)255; return p; };
    const size_t SLOT = (size_t)NB * DM;
    const size_t W768 = (size_t)768 * 768;
    bf16* tl_wb   = (bf16*)alloc(W768 * 2);
    bf16* il_wb   = (bf16*)alloc(W768 * 2);
    bf16* sda_wvb = (bf16*)alloc((size_t)512 * 768 * 2);
    bf16* sda_wob = (bf16*)alloc((size_t)768 * 512 * 2);
    bf16* fda_wfb = (bf16*)alloc((size_t)768 * 384 * 2);
    bf16* dmi_wqb = (bf16*)alloc(W768 * 2);
    bf16* dmi_wkb = (bf16*)alloc(W768 * 2);
    bf16* dmi_wvb = (bf16*)alloc(W768 * 2);
    bf16* tg_w1b  = (bf16*)alloc(W768 * 2);
    bf16* tg_w2b  = (bf16*)alloc(W768 * 2);
    bf16* ig_w1b  = (bf16*)alloc(W768 * 2);
    bf16* ig_w2b  = (bf16*)alloc(W768 * 2);
    bf16* w1c     = (bf16*)alloc((size_t)384 * 768 * 2);
    float* sac    = (float*)alloc(1536 * 4);
    float* lbuf   = (float*)alloc(2 * NB * 4);               // final denominators [2][NB]
    float* part   = (float*)alloc((size_t)2 * 16 * NB * 4);  // per-chunk partials [2][16][NB]
    bf16* SL[8];
    for (int i = 0; i < 8; ++i) SL[i] = (bf16*)alloc(SLOT * 2);
    bf16* SC1 = (bf16*)alloc((size_t)NB * NB * 2);
    bf16* SC2 = (bf16*)alloc((size_t)NB * NB * 2);

    const float bnscale = 1.0f / sqrtf(1.0f + 1e-5f);
    const float iscale  = 1.0f / sqrtf(768.0f);
    const dim3 blk(256);

    struct JB {
        Jobs jb; int blocks; int tile;
        void add(const bf16* A, const bf16* B, bf16* C, int M, int N, int K, int ldA, int ldB,
                 const float* b0, float al, const float* gv, const float* b1, int act, int trans,
                 float* rs = nullptr){
            Job& j = jb.j[jb.nj++];
            j.A=A; j.B=B; j.C=C; j.b0=b0; j.gv=gv; j.b1=b1; j.rs=rs;
            j.M=M; j.N=N; j.K=K; j.ldA=ldA; j.ldB=ldB; j.act=act; j.trans=trans;
            j.alpha=al; j.blk0=blocks; j.nx=N/tile;
            blocks += (N/tile)*(M/tile);
        }
    };
    auto launch128 = [&](JB& b){ mgemm_k   <<<dim3(b.blocks), dim3(256), 0, stream>>>(b.jb); };
    auto launch256 = [&](JB& b){ mgemm256_k<<<dim3(b.blocks), dim3(256), 0, stream>>>(b.jb); };

    // fp32 -> bf16 staging
    CvtDesc cd;
    const float* srcs[NCVT] = {text, image, tl_w, il_w, sda_wv, sda_wo, fda_wf,
                               dmi_wq, dmi_wk, dmi_wv, tg_w1, tg_w2, ig_w1, ig_w2};
    bf16* dsts[NCVT] = {SL[0], SL[1], tl_wb, il_wb, sda_wvb, sda_wob, fda_wfb,
                        dmi_wqb, dmi_wkb, dmi_wvb, tg_w1b, tg_w2b, ig_w1b, ig_w2b};
    int   lens[NCVT] = {(int)SLOT, (int)SLOT, (int)W768, (int)W768, 512*768, 768*512, 768*384,
                        (int)W768, (int)W768, (int)W768, (int)W768, (int)W768, (int)W768, (int)W768};
    for (int i = 0; i < NCVT; ++i){ cd.s[i] = srcs[i]; cd.d[i] = dsts[i]; cd.n[i] = lens[i]; }
    cvt_k<<<dim3((int)(SLOT / 1024), NCVT), blk, 0, stream>>>(cd);
    extract_k<<<dim3((384 * 768 + 255) / 256), blk, 0, stream>>>(fda_w1, sa_w, w1c, sac);

    // J1: t0 = gelu(text@tl^T) -> SL2 ; im0 = gelu(image@il^T) -> SL3   [256-tile]
    { JB b{}; b.tile=256;
      b.add(SL[0], tl_wb, SL[2], NB, DM, DM, DM, DM, tl_b, 1.f, nullptr, nullptr, 1, 0);
      b.add(SL[1], il_wb, SL[3], NB, DM, DM, DM, DM, il_b, 1.f, nullptr, nullptr, 1, 0); launch256(b); }
    // J2: wv = t0@wv^T -> SL0 (N=512) ; x1 = conv1(im0) -> SL1 (N=384)  [128-tile: N=384]
    { JB b{}; b.tile=128;
      b.add(SL[2], sda_wvb, SL[0], NB, 512, DM, DM, DM, sda_bv, 1.f, nullptr, nullptr, 0, 0);
      b.add(SL[3], w1c,     SL[1], NB, 384, DM, DM, DM, fda_b1, bnscale, bn1_g, bn1_b, 1, 0); launch128(b); }
    // fused FDA tail (in place on SL1)
    fda_fused_k<<<dim3(NB), dim3(128), 0, stream>>>(SL[1], ca_w1, ca_w2, sac, sa_b, dec_w, dec_b, sigma);
    // J34: t1 = wv@wo^T -> SL4 (K=512) ; im1 = gelu((x4@wf^T+bf)*bn2) -> SL5 (K=384)  [256-tile]
    { JB b{}; b.tile=256;
      b.add(SL[0], sda_wob, SL[4], NB, DM, 512, 512, 512, sda_bo, 1.f, nullptr, nullptr, 0, 0);
      b.add(SL[1], fda_wfb, SL[5], NB, DM, 384, 384, 384, fda_bf, bnscale, bn2_g, bn2_b, 1, 0); launch256(b); }

    // J5: QKV both directions (6 jobs)  [256-tile]
    { JB b{}; b.tile=256;
      b.add(SL[4], dmi_wqb, SL[0], NB, DM, DM, DM, DM, dmi_bq, 1.f, nullptr, nullptr, 0, 0);
      b.add(SL[5], dmi_wkb, SL[1], NB, DM, DM, DM, DM, dmi_bk, 1.f, nullptr, nullptr, 0, 0);
      b.add(SL[5], dmi_wvb, SL[2], NB, DM, DM, DM, DM, dmi_bv, 1.f, nullptr, nullptr, 0, 1);
      b.add(SL[5], dmi_wqb, SL[3], NB, DM, DM, DM, DM, dmi_bq, 1.f, nullptr, nullptr, 0, 0);
      b.add(SL[4], dmi_wkb, SL[6], NB, DM, DM, DM, DM, dmi_bk, 1.f, nullptr, nullptr, 0, 0);
      b.add(SL[4], dmi_wvb, SL[7], NB, DM, DM, DM, DM, dmi_bv, 1.f, nullptr, nullptr, 0, 1);
      launch256(b); }
    // J6: scores with fused exp + per-block partial row sums (16 chunks)  [256-tile]
    { JB b{}; b.tile=256;
      b.add(SL[0], SL[1], SC1, NB, NB, DM, DM, DM, nullptr, iscale, nullptr, nullptr, 4, 0, part);
      b.add(SL[3], SL[6], SC2, NB, NB, DM, DM, DM, nullptr, iscale, nullptr, nullptr, 4, 0, part + 16 * NB); launch256(b); }
    // reduce partials -> lbuf
    denom_k<<<dim3((2 * NB + 255) / 256), blk, 0, stream>>>(part, lbuf);
    // J7: PV split-K=2 x 2 dirs (4 jobs) on unnormalized exp-scores  [256-tile]
    { JB b{}; b.tile=256;
      b.add(SC1,        SL[2],        SL[0], NB, DM, 2048, NB, NB, nullptr, 1.f, nullptr, nullptr, 0, 0);
      b.add(SC1 + 2048, SL[2] + 2048, SL[1], NB, DM, 2048, NB, NB, nullptr, 1.f, nullptr, nullptr, 0, 0);
      b.add(SC2,        SL[7],        SL[3], NB, DM, 2048, NB, NB, nullptr, 1.f, nullptr, nullptr, 0, 0);
      b.add(SC2 + 2048, SL[7] + 2048, SL[6], NB, DM, 2048, NB, NB, nullptr, 1.f, nullptr, nullptr, 0, 0);
      launch256(b); }
    // a1 = (SL0+SL1)/l1 -> SL4 ; a2 = (SL3+SL6)/l2 -> SL5
    reduce2_k<<<dim3((int)(SLOT / 2048)), blk, 0, stream>>>(SL[0], SL[1], SL[4], lbuf,
                                                           SL[3], SL[6], SL[5], lbuf + NB);
    // J8/J9: gates  [256-tile]
    { JB b{}; b.tile=256;
      b.add(SL[4], tg_w1b, SL[0], NB, DM, DM, DM, DM, tg_b1, 1.f, nullptr, nullptr, 3, 0);
      b.add(SL[5], ig_w1b, SL[1], NB, DM, DM, DM, DM, ig_b1, 1.f, nullptr, nullptr, 3, 0); launch256(b); }
    { JB b{}; b.tile=256;
      b.add(SL[0], tg_w2b, SL[3], NB, DM, DM, DM, DM, tg_b2, 1.f, nullptr, nullptr, 2, 0);
      b.add(SL[1], ig_w2b, SL[6], NB, DM, DM, DM, DM, ig_b2, 1.f, nullptr, nullptr, 2, 0); launch256(b); }
    // fused combine + classifier + softmax
    combine_cls_k<<<dim3(NB), blk, 0, stream>>>(SL[3], SL[4], t_scale, SL[6], SL[5], i_scale,
                                                cls_w, cls_b, out);
}

// Round 5
// 548.948 us; speedup vs baseline: 5.8985x; 4.8178x over previous
//
#include <hip/hip_runtime.h>
#include <hip/hip_bf16.h>
#include <math.h>

typedef __hip_bfloat16 bf16;
typedef __bf16 bf16x8 __attribute__((ext_vector_type(8)));
typedef float f32x4 __attribute__((ext_vector_type(4)));
typedef unsigned short u16;
typedef u16 u16x8 __attribute__((ext_vector_type(8)));

#define NB 4096          // batch rows
#define DM 768           // model dim

__device__ __forceinline__ float cvt(float x){ return x; }
__device__ __forceinline__ float cvt(bf16 x){ return __bfloat162float(x); }
__device__ __forceinline__ void stv(float* p, float v){ *p = v; }
__device__ __forceinline__ void stv(bf16* p, float v){ *p = __float2bfloat16(v); }

__device__ __forceinline__ float gelu_f(float x){
    return 0.5f * x * (1.0f + erff(x * 0.70710678118654752440f));
}
__device__ __forceinline__ float sigmoid_f(float x){
    return 1.0f / (1.0f + __expf(-x));
}

__device__ __forceinline__ void async_copy16(const void* g, void* l){
    __builtin_amdgcn_global_load_lds((const __attribute__((address_space(1))) void*)g,
                                     (__attribute__((address_space(3))) void*)l, 16, 0, 0);
}

// ---------------------------------------------------------------------------
// Flat multi-job MFMA GEMM (R7 K-loop/epilogue structure -- proven optimum).
// REVERTED to the harness-verified 565.7us configuration after R1-R4:
//   R1-R4 post-mortem: the 256x256 8-phase kernel is unreachable with this
//   toolchain's register budgeting. 512-thr kernels are pinned to a 128-reg
//   unified cap (launch_bounds 2nd arg acts as blocks/CU; amdgpu_* attrs
//   silently ignored); 256-thr kernels cap at 256 arch VGPRs with NO AGPR
//   overflow for the accumulator (R4: VGPR_Count=256 AND ~4KB/thread scratch
//   spill, WRITE 572MB/dispatch, MfmaUtil 2.7%). Every 8-phase variant lost
//   5x to the proven 128-tile kernel. Do not re-attempt without disasm.
// NEW in R5: XCD-aware per-job block swizzle (T1). Consecutive blocks share a
// 196KB A-panel; default dispatch round-robins them across the 8 XCD L2s so
// the panel is re-fetched 8x (J6 FETCH 61.8MB vs ~25MB ideal). Chunked swizzle
// gives each XCD a contiguous tile range. Bijective: all grids here have
// nb%8==0 (M/128=32 for every job); guarded anyway.
//
// Per job: C = act((A @ Bm^T + b0) * alpha * gv + b1)
// act: 0 none, 1 gelu, 2 sigmoid, 3 relu, 4 exp (__expf; softmax numerator --
// scores are tiny so no max subtraction needed, softmax is shift-invariant).
// rs != nullptr: block (gx,gy) writes its 128 per-row tile sums to
// rs[gx*M + row] (each slot written exactly once -- no atomics, no memset).
// A: (M,ldA) bf16 cols [0,K). Bm: (N,ldB) bf16 (B^T layout) cols [0,K).
// M%128==0, N%128==0, K%64==0. trans=1: store C^T into (N,M).
// BK=64 (32 MFMA per barrier), XOR-chunk LDS swizzle, LDS-staged coalesced
// epilogue stores (256 B lines).
// ---------------------------------------------------------------------------
#define MAXJ 8
struct Job {
    const bf16* A; const bf16* B; bf16* C;
    const float* b0; const float* gv; const float* b1;
    float* rs;
    int M, N, K, ldA, ldB, act, trans, blk0, nx, nb;
    float alpha;
};
struct Jobs { Job j[MAXJ]; int nj; };

__global__ __launch_bounds__(256) void mgemm_k(Jobs jb)
{
    int z = 0;
    #pragma unroll
    for (int i = 1; i < MAXJ; ++i)
        if (i < jb.nj && (int)blockIdx.x >= jb.j[i].blk0) z = i;
    const Job& J = jb.j[z];
    const bf16* __restrict__ A  = J.A;
    const bf16* __restrict__ Bm = J.B;
    bf16* __restrict__ C        = J.C;
    const int bx0 = (int)blockIdx.x - J.blk0;
    // XCD-aware chunked swizzle (bijective when nb%8==0): blocks resident on
    // one XCD (bx0 mod 8 fixed) map to a contiguous range of tile ids, so the
    // shared A-panel stays in that XCD's L2.
    int bx = bx0;
    if ((J.nb & 7) == 0){ const int cpx = J.nb >> 3; bx = (bx0 & 7) * cpx + (bx0 >> 3); }
    const int gx = bx % J.nx;
    const int gy = bx / J.nx;
    const int M = J.M, N = J.N, K = J.K, ldA = J.ldA, ldB = J.ldB;

    // staging: A = smem[0 .. 8191] (128x64), B = smem[8192 .. 16383]
    // epilogue: 128x136 bf16 tile = 17408 elems
    __shared__ __align__(16) bf16 smem[17408];
    const int tid  = threadIdx.x;
    const int wave = tid >> 6;
    const int lane = tid & 63;
    const int row0 = gy * 128;
    const int col0 = gx * 128;
    const int wrow = (wave & 1) * 64;
    const int wcol = (wave >> 1) * 64;
    const int fl   = lane & 15;
    const int q    = lane >> 4;

    // staging: per instr a wave stages 8 rows x 64 cols (1 KiB).
    // phys chunk (lane&7) at row r holds logical chunk (lane&7)^(r&7).
    const int sr8 = lane >> 3;
    const int sc8 = (((lane & 7) ^ sr8)) * 8;
    const bf16* pA = A  + (size_t)(row0 + wave * 32 + sr8) * ldA + sc8;
    const bf16* pB = Bm + (size_t)(col0 + wave * 32 + sr8) * ldB + sc8;
    bf16* ldsA = &smem[(wave * 32) * 64];
    bf16* ldsB = &smem[8192 + (wave * 32) * 64];

    f32x4 acc[4][4] = {};
    for (int k0 = 0; k0 < K; k0 += 64){
        #pragma unroll
        for (int i = 0; i < 4; ++i){
            async_copy16(pA + (size_t)(i * 8) * ldA, ldsA + i * 512);
            async_copy16(pB + (size_t)(i * 8) * ldB, ldsB + i * 512);
        }
        pA += 64; pB += 64;
        __syncthreads();
        #pragma unroll
        for (int ks = 0; ks < 2; ++ks){
            bf16x8 af[4], bfv[4];
            #pragma unroll
            for (int i = 0; i < 4; ++i){
                const int ra = wrow + i * 16 + fl;
                const int rb = wcol + i * 16 + fl;
                const int ca = ((ks * 4 + q) ^ (ra & 7)) * 8;
                const int cb = ((ks * 4 + q) ^ (rb & 7)) * 8;
                af[i]  = *(const bf16x8*)&smem[ra * 64 + ca];
                bfv[i] = *(const bf16x8*)&smem[8192 + rb * 64 + cb];
            }
            #pragma unroll
            for (int mi = 0; mi < 4; ++mi)
                #pragma unroll
                for (int ni = 0; ni < 4; ++ni)
                    acc[mi][ni] = __builtin_amdgcn_mfma_f32_16x16x32_bf16(af[mi], bfv[ni], acc[mi][ni], 0, 0, 0);
        }
        __syncthreads();
    }

    // epilogue: C/D layout col = lane&15, row = q*4 + reg (verified R4-R10)
    // stage to LDS (padded ld=136), then block-wide 256 B coalesced stores.
    constexpr int ELD = 136;
    #pragma unroll
    for (int ni = 0; ni < 4; ++ni){
        const int col = col0 + wcol + ni * 16 + fl;
        const float b0 = J.b0 ? J.b0[col] : 0.f;
        const float gm = (J.gv ? J.gv[col] : 1.f) * J.alpha;
        const float b1 = J.b1 ? J.b1[col] : 0.f;
        const int lcol = wcol + ni * 16 + fl;
        #pragma unroll
        for (int mi = 0; mi < 4; ++mi){
            const int lrow = wrow + mi * 16 + q * 4;
            #pragma unroll
            for (int r = 0; r < 4; ++r){
                float v = (acc[mi][ni][r] + b0) * gm + b1;
                if      (J.act == 1) v = gelu_f(v);
                else if (J.act == 2) v = sigmoid_f(v);
                else if (J.act == 3) v = fmaxf(v, 0.f);
                else if (J.act == 4) v = __expf(v);
                if (J.trans) smem[(size_t)lcol * ELD + lrow + r] = __float2bfloat16(v);
                else         smem[(size_t)(lrow + r) * ELD + lcol] = __float2bfloat16(v);
            }
        }
    }
    __syncthreads();
    const int erow = tid >> 4;         // 0..15
    const int ecol = (tid & 15) * 8;   // element offset, 16 B
    #pragma unroll
    for (int p = 0; p < 8; ++p){
        const int row = p * 16 + erow;
        const u16x8 uv = *(const u16x8*)&smem[row * ELD + ecol];
        if (J.trans) *(u16x8*)&C[(size_t)(col0 + row) * M + row0 + ecol] = uv;
        else         *(u16x8*)&C[(size_t)(row0 + row) * N + col0 + ecol] = uv;
        if (J.rs){
            float s = 0.f;
            #pragma unroll
            for (int j = 0; j < 8; ++j) s += __uint_as_float((unsigned)uv[j] << 16);
            s += __shfl_down(s, 8, 16);
            s += __shfl_down(s, 4, 16);
            s += __shfl_down(s, 2, 16);
            s += __shfl_down(s, 1, 16);
            if ((tid & 15) == 0) J.rs[(size_t)gx * M + row0 + row] = s;   // exactly-once, no atomic
        }
    }
}

// Reduce 32 per-chunk partials per row into the softmax denominator.
// part layout: [2 dirs][32 chunks][NB rows]; l: [2][NB].
__global__ __launch_bounds__(256) void denom_k(const float* __restrict__ part, float* __restrict__ l)
{
    const int t = blockIdx.x * 256 + threadIdx.x;     // 0 .. 2*NB-1
    if (t >= 2 * NB) return;
    const int dir = t >> 12, row = t & (NB - 1);
    const float* p = part + (size_t)dir * 32 * NB + row;
    float s = 0.f;
    #pragma unroll
    for (int c = 0; c < 32; ++c) s += p[(size_t)c * NB];
    l[t] = s;
}

// Batched fp32 -> bf16 conversion
#define NCVT 14
struct CvtDesc { const float* s[NCVT]; bf16* d[NCVT]; int n[NCVT]; };
__global__ __launch_bounds__(256) void cvt_k(CvtDesc cd)
{
    const int e = blockIdx.y;
    const int base = (blockIdx.x * 256 + threadIdx.x) * 4;
    if (base >= cd.n[e]) return;
    const float4 v = *(const float4*)(cd.s[e] + base);
    union { bf16 h[4]; unsigned long long u; } o;
    o.h[0] = __float2bfloat16(v.x);
    o.h[1] = __float2bfloat16(v.y);
    o.h[2] = __float2bfloat16(v.z);
    o.h[3] = __float2bfloat16(v.w);
    *(unsigned long long*)(cd.d[e] + base) = o.u;
}

__global__ __launch_bounds__(256) void extract_k(
    const float* __restrict__ w1, const float* __restrict__ saw,
    bf16* __restrict__ w1c, float* __restrict__ sac)
{
    const int idx = blockIdx.x * 256 + threadIdx.x;
    if (idx < 384 * 768){
        const int oc = idx / 768, ic = idx % 768;
        w1c[idx] = __float2bfloat16(w1[(size_t)oc * 6912 + (size_t)ic * 9 + 4]);
    }
    if (idx < 384) sac[idx] = saw[(size_t)idx * 49 + 24];
}

// Fused FDA tail: ca1 -> ca2 -> x2 -> sa -> x3 -> dec -> x4, in place
__global__ __launch_bounds__(128) void fda_fused_k(
    bf16* __restrict__ x, const float* __restrict__ wc1, const float* __restrict__ wc2,
    const float* __restrict__ sac, const float* __restrict__ sab,
    const float* __restrict__ decw, const float* __restrict__ decb,
    const float* __restrict__ sigma)
{
    __shared__ float xs[384];
    __shared__ float ca1s[24];
    __shared__ float red[128];
    const int b = blockIdx.x;
    const int tid = threadIdx.x;
    bf16* xr = x + (size_t)b * 384;
    #pragma unroll
    for (int i = 0; i < 3; ++i) xs[tid + i * 128] = cvt(xr[tid + i * 128]);
    __syncthreads();
    if (tid < 96){
        const int o = tid >> 2, sub = tid & 3;
        const float* w = wc1 + (size_t)o * 384 + sub * 96;
        float p = 0.f;
        #pragma unroll 8
        for (int k = 0; k < 96; ++k) p = fmaf(xs[sub * 96 + k], w[k], p);
        p += __shfl_down(p, 1, 64);
        p += __shfl_down(p, 2, 64);
        if (sub == 0) ca1s[o] = gelu_f(p);
    }
    __syncthreads();
    float x2[3];
    float p = 0.f;
    #pragma unroll
    for (int i = 0; i < 3; ++i){
        const int c = tid + i * 128;
        float s = 0.f;
        const float* w = wc2 + (size_t)c * 24;
        #pragma unroll
        for (int k = 0; k < 24; ++k) s = fmaf(ca1s[k], w[k], s);
        const float v = xs[c] * sigmoid_f(s);
        x2[i] = v;
        p += v * sac[c];
    }
    red[tid] = p; __syncthreads();
    for (int s = 64; s > 0; s >>= 1){ if (tid < s) red[tid] += red[tid + s]; __syncthreads(); }
    const float sa = sigmoid_f(red[0] + sab[0]);
    __syncthreads();
    float qq = 0.f;
    #pragma unroll
    for (int i = 0; i < 3; ++i){
        const int c = tid + i * 128;
        x2[i] *= sa;
        qq += x2[i] * decw[c];
    }
    red[tid] = qq; __syncthreads();
    for (int s = 64; s > 0; s >>= 1){ if (tid < s) red[tid] += red[tid + s]; __syncthreads(); }
    const float xg = gelu_f(red[0] + decb[0]);
    #pragma unroll
    for (int i = 0; i < 3; ++i){
        const int c = tid + i * 128;
        const float sg = sigma[c];
        stv(&xr[c], x2[i] + sg * (x2[i] - xg));
    }
}

// o1 = (a+b)/l1[row] ; o2 = (c+d)/l2[row]  (split-K reduce + softmax denom)
__global__ __launch_bounds__(256) void reduce2_k(
    const bf16* __restrict__ a, const bf16* __restrict__ b, bf16* __restrict__ o1,
    const float* __restrict__ l1,
    const bf16* __restrict__ c, const bf16* __restrict__ d, bf16* __restrict__ o2,
    const float* __restrict__ l2)
{
    const size_t i = ((size_t)blockIdx.x * 256 + threadIdx.x) * 8;
    if (i >= (size_t)NB * DM) return;
    const int row = (int)(i / DM);     // 8-elem chunk never crosses a row (768 % 8 == 0)
    const float inv1 = 1.0f / l1[row];
    const float inv2 = 1.0f / l2[row];
    u16x8 ua = *(const u16x8*)((const u16*)a + i);
    u16x8 ub = *(const u16x8*)((const u16*)b + i);
    u16x8 uc = *(const u16x8*)((const u16*)c + i);
    u16x8 ud = *(const u16x8*)((const u16*)d + i);
    u16x8 r1, r2;
    #pragma unroll
    for (int j = 0; j < 8; ++j){
        const float s1 = (__uint_as_float((unsigned)ua[j] << 16) + __uint_as_float((unsigned)ub[j] << 16)) * inv1;
        const float s2 = (__uint_as_float((unsigned)uc[j] << 16) + __uint_as_float((unsigned)ud[j] << 16)) * inv2;
        r1[j] = __bfloat16_as_ushort(__float2bfloat16(s1));
        r2[j] = __bfloat16_as_ushort(__float2bfloat16(s2));
    }
    *(u16x8*)((u16*)o1 + i) = r1;
    *(u16x8*)((u16*)o2 + i) = r2;
}

// Fused gate-combine + classifier + softmax(3). One block per batch row.
__global__ __launch_bounds__(256) void combine_cls_k(
    const bf16* __restrict__ g1, const bf16* __restrict__ a1, const float* __restrict__ s1,
    const bf16* __restrict__ g2, const bf16* __restrict__ a2, const float* __restrict__ s2,
    const float* __restrict__ w, const float* __restrict__ bias, float* __restrict__ out)
{
    __shared__ float r0[256], r1[256], r2[256];
    const int b = blockIdx.x;
    const int tid = threadIdx.x;
    const size_t off = (size_t)b * DM;
    float p0 = 0.f, p1 = 0.f, p2 = 0.f;
    #pragma unroll
    for (int i = 0; i < 3; ++i){
        const int c = tid + i * 256;
        const float v = sigmoid_f(cvt(g1[off + c])) * cvt(a1[off + c]) * s1[c]
                      + sigmoid_f(cvt(g2[off + c])) * cvt(a2[off + c]) * s2[c];
        p0 = fmaf(v, w[c],         p0);
        p1 = fmaf(v, w[DM + c],    p1);
        p2 = fmaf(v, w[2*DM + c],  p2);
    }
    r0[tid] = p0; r1[tid] = p1; r2[tid] = p2; __syncthreads();
    for (int s = 128; s > 0; s >>= 1){
        if (tid < s){ r0[tid] += r0[tid + s]; r1[tid] += r1[tid + s]; r2[tid] += r2[tid + s]; }
        __syncthreads();
    }
    if (tid == 0){
        const float l0 = r0[0] + bias[0];
        const float l1 = r1[0] + bias[1];
        const float l2 = r2[0] + bias[2];
        const float mx = fmaxf(l0, fmaxf(l1, l2));
        const float e0 = __expf(l0 - mx), e1 = __expf(l1 - mx), e2 = __expf(l2 - mx);
        const float inv = 1.f / (e0 + e1 + e2);
        out[(size_t)b * 3 + 0] = e0 * inv;
        out[(size_t)b * 3 + 1] = e1 * inv;
        out[(size_t)b * 3 + 2] = e2 * inv;
    }
}

extern "C" void kernel_launch(void* const* d_in, const int* in_sizes, int n_in,
                              void* d_out, int out_size, void* d_ws, size_t ws_size,
                              hipStream_t stream)
{
    const float* text   = (const float*)d_in[0];
    const float* image  = (const float*)d_in[1];
    const float* tl_w   = (const float*)d_in[2];
    const float* tl_b   = (const float*)d_in[3];
    const float* il_w   = (const float*)d_in[4];
    const float* il_b   = (const float*)d_in[5];
    const float* sda_wv = (const float*)d_in[10];
    const float* sda_bv = (const float*)d_in[11];
    const float* sda_wo = (const float*)d_in[12];
    const float* sda_bo = (const float*)d_in[13];
    const float* fda_w1 = (const float*)d_in[14];
    const float* fda_b1 = (const float*)d_in[15];
    const float* bn1_g  = (const float*)d_in[16];
    const float* bn1_b  = (const float*)d_in[17];
    const float* ca_w1  = (const float*)d_in[18];
    const float* ca_w2  = (const float*)d_in[19];
    const float* sa_w   = (const float*)d_in[20];
    const float* sa_b   = (const float*)d_in[21];
    const float* dec_w  = (const float*)d_in[22];
    const float* dec_b  = (const float*)d_in[23];
    const float* sigma  = (const float*)d_in[24];
    const float* fda_wf = (const float*)d_in[25];
    const float* fda_bf = (const float*)d_in[26];
    const float* bn2_g  = (const float*)d_in[27];
    const float* bn2_b  = (const float*)d_in[28];
    const float* dmi_wq = (const float*)d_in[29];
    const float* dmi_bq = (const float*)d_in[30];
    const float* dmi_wk = (const float*)d_in[31];
    const float* dmi_bk = (const float*)d_in[32];
    const float* dmi_wv = (const float*)d_in[33];
    const float* dmi_bv = (const float*)d_in[34];
    const float* tg_w1  = (const float*)d_in[35];
    const float* tg_b1  = (const float*)d_in[36];
    const float* tg_w2  = (const float*)d_in[37];
    const float* tg_b2  = (const float*)d_in[38];
    const float* ig_w1  = (const float*)d_in[39];
    const float* ig_b1  = (const float*)d_in[40];
    const float* ig_w2  = (const float*)d_in[41];
    const float* ig_b2  = (const float*)d_in[42];
    const float* t_scale= (const float*)d_in[43];
    const float* i_scale= (const float*)d_in[44];
    const float* cls_w  = (const float*)d_in[45];
    const float* cls_b  = (const float*)d_in[46];
    float* out = (float*)d_out;

    // ---- workspace (~129 MB) ----
    char* base = (char*)d_ws;
    auto alloc = [&](size_t bytes){ void* p = (void*)base; base += (bytes + 255) & ~(size_t)255; return p; };
    const size_t SLOT = (size_t)NB * DM;
    const size_t W768 = (size_t)768 * 768;
    bf16* tl_wb   = (bf16*)alloc(W768 * 2);
    bf16* il_wb   = (bf16*)alloc(W768 * 2);
    bf16* sda_wvb = (bf16*)alloc((size_t)512 * 768 * 2);
    bf16* sda_wob = (bf16*)alloc((size_t)768 * 512 * 2);
    bf16* fda_wfb = (bf16*)alloc((size_t)768 * 384 * 2);
    bf16* dmi_wqb = (bf16*)alloc(W768 * 2);
    bf16* dmi_wkb = (bf16*)alloc(W768 * 2);
    bf16* dmi_wvb = (bf16*)alloc(W768 * 2);
    bf16* tg_w1b  = (bf16*)alloc(W768 * 2);
    bf16* tg_w2b  = (bf16*)alloc(W768 * 2);
    bf16* ig_w1b  = (bf16*)alloc(W768 * 2);
    bf16* ig_w2b  = (bf16*)alloc(W768 * 2);
    bf16* w1c     = (bf16*)alloc((size_t)384 * 768 * 2);
    float* sac    = (float*)alloc(1536 * 4);
    float* lbuf   = (float*)alloc(2 * NB * 4);               // final denominators [2][NB]
    float* part   = (float*)alloc((size_t)2 * 32 * NB * 4);  // per-chunk partials [2][32][NB], 1 MB
    bf16* SL[8];
    for (int i = 0; i < 8; ++i) SL[i] = (bf16*)alloc(SLOT * 2);
    bf16* SC1 = (bf16*)alloc((size_t)NB * NB * 2);
    bf16* SC2 = (bf16*)alloc((size_t)NB * NB * 2);

    const float bnscale = 1.0f / sqrtf(1.0f + 1e-5f);
    const float iscale  = 1.0f / sqrtf(768.0f);
    const dim3 blk(256);

    struct JB {
        Jobs jb; int blocks;
        void add(const bf16* A, const bf16* B, bf16* C, int M, int N, int K, int ldA, int ldB,
                 const float* b0, float al, const float* gv, const float* b1, int act, int trans,
                 float* rs = nullptr){
            Job& j = jb.j[jb.nj++];
            j.A=A; j.B=B; j.C=C; j.b0=b0; j.gv=gv; j.b1=b1; j.rs=rs;
            j.M=M; j.N=N; j.K=K; j.ldA=ldA; j.ldB=ldB; j.act=act; j.trans=trans;
            j.alpha=al; j.blk0=blocks; j.nx=N/128; j.nb=(N/128)*(M/128);
            blocks += (N/128)*(M/128);
        }
    };
    auto launch = [&](JB& b){ mgemm_k<<<dim3(b.blocks), blk, 0, stream>>>(b.jb); };

    // fp32 -> bf16 staging
    CvtDesc cd;
    const float* srcs[NCVT] = {text, image, tl_w, il_w, sda_wv, sda_wo, fda_wf,
                               dmi_wq, dmi_wk, dmi_wv, tg_w1, tg_w2, ig_w1, ig_w2};
    bf16* dsts[NCVT] = {SL[0], SL[1], tl_wb, il_wb, sda_wvb, sda_wob, fda_wfb,
                        dmi_wqb, dmi_wkb, dmi_wvb, tg_w1b, tg_w2b, ig_w1b, ig_w2b};
    int   lens[NCVT] = {(int)SLOT, (int)SLOT, (int)W768, (int)W768, 512*768, 768*512, 768*384,
                        (int)W768, (int)W768, (int)W768, (int)W768, (int)W768, (int)W768, (int)W768};
    for (int i = 0; i < NCVT; ++i){ cd.s[i] = srcs[i]; cd.d[i] = dsts[i]; cd.n[i] = lens[i]; }
    cvt_k<<<dim3((int)(SLOT / 1024), NCVT), blk, 0, stream>>>(cd);
    extract_k<<<dim3((384 * 768 + 255) / 256), blk, 0, stream>>>(fda_w1, sa_w, w1c, sac);

    // J1: t0 = gelu(text@tl^T) -> SL2 ; im0 = gelu(image@il^T) -> SL3
    { JB b{}; b.add(SL[0], tl_wb, SL[2], NB, DM, DM, DM, DM, tl_b, 1.f, nullptr, nullptr, 1, 0);
              b.add(SL[1], il_wb, SL[3], NB, DM, DM, DM, DM, il_b, 1.f, nullptr, nullptr, 1, 0); launch(b); }
    // J2: wv = t0@wv^T -> SL0 (N=512) ; x1 = conv1(im0) -> SL1 (N=384)
    { JB b{}; b.add(SL[2], sda_wvb, SL[0], NB, 512, DM, DM, DM, sda_bv, 1.f, nullptr, nullptr, 0, 0);
              b.add(SL[3], w1c,     SL[1], NB, 384, DM, DM, DM, fda_b1, bnscale, bn1_g, bn1_b, 1, 0); launch(b); }
    // fused FDA tail (in place on SL1)
    fda_fused_k<<<dim3(NB), dim3(128), 0, stream>>>(SL[1], ca_w1, ca_w2, sac, sa_b, dec_w, dec_b, sigma);
    // J34 (batched): t1 = wv@wo^T -> SL4 (K=512) ; im1 = gelu((x4@wf^T+bf)*bn2) -> SL5 (K=384)
    { JB b{}; b.add(SL[0], sda_wob, SL[4], NB, DM, 512, 512, 512, sda_bo, 1.f, nullptr, nullptr, 0, 0);
              b.add(SL[1], fda_wfb, SL[5], NB, DM, 384, 384, 384, fda_bf, bnscale, bn2_g, bn2_b, 1, 0); launch(b); }

    // J5: QKV both directions (6 jobs)
    { JB b{};
      b.add(SL[4], dmi_wqb, SL[0], NB, DM, DM, DM, DM, dmi_bq, 1.f, nullptr, nullptr, 0, 0);
      b.add(SL[5], dmi_wkb, SL[1], NB, DM, DM, DM, DM, dmi_bk, 1.f, nullptr, nullptr, 0, 0);
      b.add(SL[5], dmi_wvb, SL[2], NB, DM, DM, DM, DM, dmi_bv, 1.f, nullptr, nullptr, 0, 1);
      b.add(SL[5], dmi_wqb, SL[3], NB, DM, DM, DM, DM, dmi_bq, 1.f, nullptr, nullptr, 0, 0);
      b.add(SL[4], dmi_wkb, SL[6], NB, DM, DM, DM, DM, dmi_bk, 1.f, nullptr, nullptr, 0, 0);
      b.add(SL[4], dmi_wvb, SL[7], NB, DM, DM, DM, DM, dmi_bv, 1.f, nullptr, nullptr, 0, 1);
      launch(b); }
    // J6: scores with fused exp + per-block partial row sums (no atomics)
    { JB b{}; b.add(SL[0], SL[1], SC1, NB, NB, DM, DM, DM, nullptr, iscale, nullptr, nullptr, 4, 0, part);
              b.add(SL[3], SL[6], SC2, NB, NB, DM, DM, DM, nullptr, iscale, nullptr, nullptr, 4, 0, part + 32 * NB); launch(b); }
    // reduce partials -> lbuf
    denom_k<<<dim3((2 * NB + 255) / 256), blk, 0, stream>>>(part, lbuf);
    // J7: PV split-K=2 x 2 dirs (4 jobs, 768 blocks) on unnormalized exp-scores
    { JB b{};
      b.add(SC1,        SL[2],        SL[0], NB, DM, 2048, NB, NB, nullptr, 1.f, nullptr, nullptr, 0, 0);
      b.add(SC1 + 2048, SL[2] + 2048, SL[1], NB, DM, 2048, NB, NB, nullptr, 1.f, nullptr, nullptr, 0, 0);
      b.add(SC2,        SL[7],        SL[3], NB, DM, 2048, NB, NB, nullptr, 1.f, nullptr, nullptr, 0, 0);
      b.add(SC2 + 2048, SL[7] + 2048, SL[6], NB, DM, 2048, NB, NB, nullptr, 1.f, nullptr, nullptr, 0, 0);
      launch(b); }
    // a1 = (SL0+SL1)/l1 -> SL4 ; a2 = (SL3+SL6)/l2 -> SL5
    reduce2_k<<<dim3((int)(SLOT / 2048)), blk, 0, stream>>>(SL[0], SL[1], SL[4], lbuf,
                                                           SL[3], SL[6], SL[5], lbuf + NB);
    // J8/J9: gates
    { JB b{}; b.add(SL[4], tg_w1b, SL[0], NB, DM, DM, DM, DM, tg_b1, 1.f, nullptr, nullptr, 3, 0);
              b.add(SL[5], ig_w1b, SL[1], NB, DM, DM, DM, DM, ig_b1, 1.f, nullptr, nullptr, 3, 0); launch(b); }
    { JB b{}; b.add(SL[0], tg_w2b, SL[3], NB, DM, DM, DM, DM, tg_b2, 1.f, nullptr, nullptr, 2, 0);
              b.add(SL[1], ig_w2b, SL[6], NB, DM, DM, DM, DM, ig_b2, 1.f, nullptr, nullptr, 2, 0); launch(b); }
    // fused combine + classifier + softmax
    combine_cls_k<<<dim3(NB), blk, 0, stream>>>(SL[3], SL[4], t_scale, SL[6], SL[5], i_scale,
                                                cls_w, cls_b, out);
}

// Round 6
// 544.506 us; speedup vs baseline: 5.9466x; 1.0082x over previous
//
#include <hip/hip_runtime.h>
#include <hip/hip_bf16.h>
#include <math.h>

typedef __hip_bfloat16 bf16;
typedef __bf16 bf16x8 __attribute__((ext_vector_type(8)));
typedef float f32x4 __attribute__((ext_vector_type(4)));
typedef unsigned short u16;
typedef u16 u16x8 __attribute__((ext_vector_type(8)));

#define NB 4096          // batch rows
#define DM 768           // model dim

__device__ __forceinline__ float cvt(float x){ return x; }
__device__ __forceinline__ float cvt(bf16 x){ return __bfloat162float(x); }
__device__ __forceinline__ void stv(float* p, float v){ *p = v; }
__device__ __forceinline__ void stv(bf16* p, float v){ *p = __float2bfloat16(v); }

__device__ __forceinline__ float gelu_f(float x){
    return 0.5f * x * (1.0f + erff(x * 0.70710678118654752440f));
}
__device__ __forceinline__ float sigmoid_f(float x){
    return 1.0f / (1.0f + __expf(-x));
}

__device__ __forceinline__ void async_copy16(const void* g, void* l){
    __builtin_amdgcn_global_load_lds((const __attribute__((address_space(1))) void*)g,
                                     (__attribute__((address_space(3))) void*)l, 16, 0, 0);
}

// ---------------------------------------------------------------------------
// Flat multi-job MFMA GEMM (R7 K-loop/epilogue structure -- proven optimum).
// R1-R4 post-mortem: the 256x256 8-phase kernel is unreachable with this
// toolchain's register budgeting (512-thr pinned to 128-reg cap; amdgpu_*
// attrs ignored; 256-thr caps at 256 arch VGPRs with no AGPR overflow ->
// spills). Do not re-attempt without disasm access.
// R5 post-mortem (XCD swizzle, T1): aspect-ratio dependent!
//   - Wide/square jobs (J6: nx=32): default round-robin already near-optimal
//     (per-XCD window = 16 A x 4 B panels = 3.9MB, fits 4MB L2 since
//     32%8==0 pins gx mod 8 per XCD). Chunked swizzle gave 4 A x 32 B =
//     7MB -> B-thrash: FETCH 61.8->105.4MB, dur 90.7->96.9us. REGRESSION.
//   - Narrow jobs (nx<=6): linear scatters ~24 A-panels/XCD (4.7MB, thrash);
//     chunked gives 4 A + <=6 B = 2MB (fits). Net total gain came from these.
// => R6: gate the swizzle on nx <= 8.
//
// Per job: C = act((A @ Bm^T + b0) * alpha * gv + b1)
// act: 0 none, 1 gelu, 2 sigmoid, 3 relu, 4 exp (__expf; softmax numerator --
// scores are tiny so no max subtraction needed, softmax is shift-invariant).
// rs != nullptr: block (gx,gy) writes its 128 per-row tile sums to
// rs[gx*M + row] (each slot written exactly once -- no atomics, no memset).
// A: (M,ldA) bf16 cols [0,K). Bm: (N,ldB) bf16 (B^T layout) cols [0,K).
// M%128==0, N%128==0, K%64==0. trans=1: store C^T into (N,M).
// BK=64 (32 MFMA per barrier), XOR-chunk LDS swizzle, LDS-staged coalesced
// epilogue stores (256 B lines).
// ---------------------------------------------------------------------------
#define MAXJ 8
struct Job {
    const bf16* A; const bf16* B; bf16* C;
    const float* b0; const float* gv; const float* b1;
    float* rs;
    int M, N, K, ldA, ldB, act, trans, blk0, nx, nb;
    float alpha;
};
struct Jobs { Job j[MAXJ]; int nj; };

__global__ __launch_bounds__(256) void mgemm_k(Jobs jb)
{
    int z = 0;
    #pragma unroll
    for (int i = 1; i < MAXJ; ++i)
        if (i < jb.nj && (int)blockIdx.x >= jb.j[i].blk0) z = i;
    const Job& J = jb.j[z];
    const bf16* __restrict__ A  = J.A;
    const bf16* __restrict__ Bm = J.B;
    bf16* __restrict__ C        = J.C;
    const int bx0 = (int)blockIdx.x - J.blk0;
    // XCD-aware chunked swizzle -- NARROW JOBS ONLY (nx<=8; see header).
    // Wide jobs (J6 nx=32) keep linear: round-robin is already L2-optimal.
    int bx = bx0;
    if (J.nx <= 8 && (J.nb & 7) == 0){ const int cpx = J.nb >> 3; bx = (bx0 & 7) * cpx + (bx0 >> 3); }
    const int gx = bx % J.nx;
    const int gy = bx / J.nx;
    const int M = J.M, N = J.N, K = J.K, ldA = J.ldA, ldB = J.ldB;

    // staging: A = smem[0 .. 8191] (128x64), B = smem[8192 .. 16383]
    // epilogue: 128x136 bf16 tile = 17408 elems
    __shared__ __align__(16) bf16 smem[17408];
    const int tid  = threadIdx.x;
    const int wave = tid >> 6;
    const int lane = tid & 63;
    const int row0 = gy * 128;
    const int col0 = gx * 128;
    const int wrow = (wave & 1) * 64;
    const int wcol = (wave >> 1) * 64;
    const int fl   = lane & 15;
    const int q    = lane >> 4;

    // staging: per instr a wave stages 8 rows x 64 cols (1 KiB).
    // phys chunk (lane&7) at row r holds logical chunk (lane&7)^(r&7).
    const int sr8 = lane >> 3;
    const int sc8 = (((lane & 7) ^ sr8)) * 8;
    const bf16* pA = A  + (size_t)(row0 + wave * 32 + sr8) * ldA + sc8;
    const bf16* pB = Bm + (size_t)(col0 + wave * 32 + sr8) * ldB + sc8;
    bf16* ldsA = &smem[(wave * 32) * 64];
    bf16* ldsB = &smem[8192 + (wave * 32) * 64];

    f32x4 acc[4][4] = {};
    for (int k0 = 0; k0 < K; k0 += 64){
        #pragma unroll
        for (int i = 0; i < 4; ++i){
            async_copy16(pA + (size_t)(i * 8) * ldA, ldsA + i * 512);
            async_copy16(pB + (size_t)(i * 8) * ldB, ldsB + i * 512);
        }
        pA += 64; pB += 64;
        __syncthreads();
        #pragma unroll
        for (int ks = 0; ks < 2; ++ks){
            bf16x8 af[4], bfv[4];
            #pragma unroll
            for (int i = 0; i < 4; ++i){
                const int ra = wrow + i * 16 + fl;
                const int rb = wcol + i * 16 + fl;
                const int ca = ((ks * 4 + q) ^ (ra & 7)) * 8;
                const int cb = ((ks * 4 + q) ^ (rb & 7)) * 8;
                af[i]  = *(const bf16x8*)&smem[ra * 64 + ca];
                bfv[i] = *(const bf16x8*)&smem[8192 + rb * 64 + cb];
            }
            #pragma unroll
            for (int mi = 0; mi < 4; ++mi)
                #pragma unroll
                for (int ni = 0; ni < 4; ++ni)
                    acc[mi][ni] = __builtin_amdgcn_mfma_f32_16x16x32_bf16(af[mi], bfv[ni], acc[mi][ni], 0, 0, 0);
        }
        __syncthreads();
    }

    // epilogue: C/D layout col = lane&15, row = q*4 + reg (verified R4-R10)
    // stage to LDS (padded ld=136), then block-wide 256 B coalesced stores.
    constexpr int ELD = 136;
    #pragma unroll
    for (int ni = 0; ni < 4; ++ni){
        const int col = col0 + wcol + ni * 16 + fl;
        const float b0 = J.b0 ? J.b0[col] : 0.f;
        const float gm = (J.gv ? J.gv[col] : 1.f) * J.alpha;
        const float b1 = J.b1 ? J.b1[col] : 0.f;
        const int lcol = wcol + ni * 16 + fl;
        #pragma unroll
        for (int mi = 0; mi < 4; ++mi){
            const int lrow = wrow + mi * 16 + q * 4;
            #pragma unroll
            for (int r = 0; r < 4; ++r){
                float v = (acc[mi][ni][r] + b0) * gm + b1;
                if      (J.act == 1) v = gelu_f(v);
                else if (J.act == 2) v = sigmoid_f(v);
                else if (J.act == 3) v = fmaxf(v, 0.f);
                else if (J.act == 4) v = __expf(v);
                if (J.trans) smem[(size_t)lcol * ELD + lrow + r] = __float2bfloat16(v);
                else         smem[(size_t)(lrow + r) * ELD + lcol] = __float2bfloat16(v);
            }
        }
    }
    __syncthreads();
    const int erow = tid >> 4;         // 0..15
    const int ecol = (tid & 15) * 8;   // element offset, 16 B
    #pragma unroll
    for (int p = 0; p < 8; ++p){
        const int row = p * 16 + erow;
        const u16x8 uv = *(const u16x8*)&smem[row * ELD + ecol];
        if (J.trans) *(u16x8*)&C[(size_t)(col0 + row) * M + row0 + ecol] = uv;
        else         *(u16x8*)&C[(size_t)(row0 + row) * N + col0 + ecol] = uv;
        if (J.rs){
            float s = 0.f;
            #pragma unroll
            for (int j = 0; j < 8; ++j) s += __uint_as_float((unsigned)uv[j] << 16);
            s += __shfl_down(s, 8, 16);
            s += __shfl_down(s, 4, 16);
            s += __shfl_down(s, 2, 16);
            s += __shfl_down(s, 1, 16);
            if ((tid & 15) == 0) J.rs[(size_t)gx * M + row0 + row] = s;   // exactly-once, no atomic
        }
    }
}

// Reduce 32 per-chunk partials per row into the softmax denominator.
// part layout: [2 dirs][32 chunks][NB rows]; l: [2][NB].
__global__ __launch_bounds__(256) void denom_k(const float* __restrict__ part, float* __restrict__ l)
{
    const int t = blockIdx.x * 256 + threadIdx.x;     // 0 .. 2*NB-1
    if (t >= 2 * NB) return;
    const int dir = t >> 12, row = t & (NB - 1);
    const float* p = part + (size_t)dir * 32 * NB + row;
    float s = 0.f;
    #pragma unroll
    for (int c = 0; c < 32; ++c) s += p[(size_t)c * NB];
    l[t] = s;
}

// Batched fp32 -> bf16 conversion
#define NCVT 14
struct CvtDesc { const float* s[NCVT]; bf16* d[NCVT]; int n[NCVT]; };
__global__ __launch_bounds__(256) void cvt_k(CvtDesc cd)
{
    const int e = blockIdx.y;
    const int base = (blockIdx.x * 256 + threadIdx.x) * 4;
    if (base >= cd.n[e]) return;
    const float4 v = *(const float4*)(cd.s[e] + base);
    union { bf16 h[4]; unsigned long long u; } o;
    o.h[0] = __float2bfloat16(v.x);
    o.h[1] = __float2bfloat16(v.y);
    o.h[2] = __float2bfloat16(v.z);
    o.h[3] = __float2bfloat16(v.w);
    *(unsigned long long*)(cd.d[e] + base) = o.u;
}

__global__ __launch_bounds__(256) void extract_k(
    const float* __restrict__ w1, const float* __restrict__ saw,
    bf16* __restrict__ w1c, float* __restrict__ sac)
{
    const int idx = blockIdx.x * 256 + threadIdx.x;
    if (idx < 384 * 768){
        const int oc = idx / 768, ic = idx % 768;
        w1c[idx] = __float2bfloat16(w1[(size_t)oc * 6912 + (size_t)ic * 9 + 4]);
    }
    if (idx < 384) sac[idx] = saw[(size_t)idx * 49 + 24];
}

// Fused FDA tail: ca1 -> ca2 -> x2 -> sa -> x3 -> dec -> x4, in place
__global__ __launch_bounds__(128) void fda_fused_k(
    bf16* __restrict__ x, const float* __restrict__ wc1, const float* __restrict__ wc2,
    const float* __restrict__ sac, const float* __restrict__ sab,
    const float* __restrict__ decw, const float* __restrict__ decb,
    const float* __restrict__ sigma)
{
    __shared__ float xs[384];
    __shared__ float ca1s[24];
    __shared__ float red[128];
    const int b = blockIdx.x;
    const int tid = threadIdx.x;
    bf16* xr = x + (size_t)b * 384;
    #pragma unroll
    for (int i = 0; i < 3; ++i) xs[tid + i * 128] = cvt(xr[tid + i * 128]);
    __syncthreads();
    if (tid < 96){
        const int o = tid >> 2, sub = tid & 3;
        const float* w = wc1 + (size_t)o * 384 + sub * 96;
        float p = 0.f;
        #pragma unroll 8
        for (int k = 0; k < 96; ++k) p = fmaf(xs[sub * 96 + k], w[k], p);
        p += __shfl_down(p, 1, 64);
        p += __shfl_down(p, 2, 64);
        if (sub == 0) ca1s[o] = gelu_f(p);
    }
    __syncthreads();
    float x2[3];
    float p = 0.f;
    #pragma unroll
    for (int i = 0; i < 3; ++i){
        const int c = tid + i * 128;
        float s = 0.f;
        const float* w = wc2 + (size_t)c * 24;
        #pragma unroll
        for (int k = 0; k < 24; ++k) s = fmaf(ca1s[k], w[k], s);
        const float v = xs[c] * sigmoid_f(s);
        x2[i] = v;
        p += v * sac[c];
    }
    red[tid] = p; __syncthreads();
    for (int s = 64; s > 0; s >>= 1){ if (tid < s) red[tid] += red[tid + s]; __syncthreads(); }
    const float sa = sigmoid_f(red[0] + sab[0]);
    __syncthreads();
    float qq = 0.f;
    #pragma unroll
    for (int i = 0; i < 3; ++i){
        const int c = tid + i * 128;
        x2[i] *= sa;
        qq += x2[i] * decw[c];
    }
    red[tid] = qq; __syncthreads();
    for (int s = 64; s > 0; s >>= 1){ if (tid < s) red[tid] += red[tid + s]; __syncthreads(); }
    const float xg = gelu_f(red[0] + decb[0]);
    #pragma unroll
    for (int i = 0; i < 3; ++i){
        const int c = tid + i * 128;
        const float sg = sigma[c];
        stv(&xr[c], x2[i] + sg * (x2[i] - xg));
    }
}

// o1 = (a+b)/l1[row] ; o2 = (c+d)/l2[row]  (split-K reduce + softmax denom)
__global__ __launch_bounds__(256) void reduce2_k(
    const bf16* __restrict__ a, const bf16* __restrict__ b, bf16* __restrict__ o1,
    const float* __restrict__ l1,
    const bf16* __restrict__ c, const bf16* __restrict__ d, bf16* __restrict__ o2,
    const float* __restrict__ l2)
{
    const size_t i = ((size_t)blockIdx.x * 256 + threadIdx.x) * 8;
    if (i >= (size_t)NB * DM) return;
    const int row = (int)(i / DM);     // 8-elem chunk never crosses a row (768 % 8 == 0)
    const float inv1 = 1.0f / l1[row];
    const float inv2 = 1.0f / l2[row];
    u16x8 ua = *(const u16x8*)((const u16*)a + i);
    u16x8 ub = *(const u16x8*)((const u16*)b + i);
    u16x8 uc = *(const u16x8*)((const u16*)c + i);
    u16x8 ud = *(const u16x8*)((const u16*)d + i);
    u16x8 r1, r2;
    #pragma unroll
    for (int j = 0; j < 8; ++j){
        const float s1 = (__uint_as_float((unsigned)ua[j] << 16) + __uint_as_float((unsigned)ub[j] << 16)) * inv1;
        const float s2 = (__uint_as_float((unsigned)uc[j] << 16) + __uint_as_float((unsigned)ud[j] << 16)) * inv2;
        r1[j] = __bfloat16_as_ushort(__float2bfloat16(s1));
        r2[j] = __bfloat16_as_ushort(__float2bfloat16(s2));
    }
    *(u16x8*)((u16*)o1 + i) = r1;
    *(u16x8*)((u16*)o2 + i) = r2;
}

// Fused gate-combine + classifier + softmax(3). One block per batch row.
__global__ __launch_bounds__(256) void combine_cls_k(
    const bf16* __restrict__ g1, const bf16* __restrict__ a1, const float* __restrict__ s1,
    const bf16* __restrict__ g2, const bf16* __restrict__ a2, const float* __restrict__ s2,
    const float* __restrict__ w, const float* __restrict__ bias, float* __restrict__ out)
{
    __shared__ float r0[256], r1[256], r2[256];
    const int b = blockIdx.x;
    const int tid = threadIdx.x;
    const size_t off = (size_t)b * DM;
    float p0 = 0.f, p1 = 0.f, p2 = 0.f;
    #pragma unroll
    for (int i = 0; i < 3; ++i){
        const int c = tid + i * 256;
        const float v = sigmoid_f(cvt(g1[off + c])) * cvt(a1[off + c]) * s1[c]
                      + sigmoid_f(cvt(g2[off + c])) * cvt(a2[off + c]) * s2[c];
        p0 = fmaf(v, w[c],         p0);
        p1 = fmaf(v, w[DM + c],    p1);
        p2 = fmaf(v, w[2*DM + c],  p2);
    }
    r0[tid] = p0; r1[tid] = p1; r2[tid] = p2; __syncthreads();
    for (int s = 128; s > 0; s >>= 1){
        if (tid < s){ r0[tid] += r0[tid + s]; r1[tid] += r1[tid + s]; r2[tid] += r2[tid + s]; }
        __syncthreads();
    }
    if (tid == 0){
        const float l0 = r0[0] + bias[0];
        const float l1 = r1[0] + bias[1];
        const float l2 = r2[0] + bias[2];
        const float mx = fmaxf(l0, fmaxf(l1, l2));
        const float e0 = __expf(l0 - mx), e1 = __expf(l1 - mx), e2 = __expf(l2 - mx);
        const float inv = 1.f / (e0 + e1 + e2);
        out[(size_t)b * 3 + 0] = e0 * inv;
        out[(size_t)b * 3 + 1] = e1 * inv;
        out[(size_t)b * 3 + 2] = e2 * inv;
    }
}

extern "C" void kernel_launch(void* const* d_in, const int* in_sizes, int n_in,
                              void* d_out, int out_size, void* d_ws, size_t ws_size,
                              hipStream_t stream)
{
    const float* text   = (const float*)d_in[0];
    const float* image  = (const float*)d_in[1];
    const float* tl_w   = (const float*)d_in[2];
    const float* tl_b   = (const float*)d_in[3];
    const float* il_w   = (const float*)d_in[4];
    const float* il_b   = (const float*)d_in[5];
    const float* sda_wv = (const float*)d_in[10];
    const float* sda_bv = (const float*)d_in[11];
    const float* sda_wo = (const float*)d_in[12];
    const float* sda_bo = (const float*)d_in[13];
    const float* fda_w1 = (const float*)d_in[14];
    const float* fda_b1 = (const float*)d_in[15];
    const float* bn1_g  = (const float*)d_in[16];
    const float* bn1_b  = (const float*)d_in[17];
    const float* ca_w1  = (const float*)d_in[18];
    const float* ca_w2  = (const float*)d_in[19];
    const float* sa_w   = (const float*)d_in[20];
    const float* sa_b   = (const float*)d_in[21];
    const float* dec_w  = (const float*)d_in[22];
    const float* dec_b  = (const float*)d_in[23];
    const float* sigma  = (const float*)d_in[24];
    const float* fda_wf = (const float*)d_in[25];
    const float* fda_bf = (const float*)d_in[26];
    const float* bn2_g  = (const float*)d_in[27];
    const float* bn2_b  = (const float*)d_in[28];
    const float* dmi_wq = (const float*)d_in[29];
    const float* dmi_bq = (const float*)d_in[30];
    const float* dmi_wk = (const float*)d_in[31];
    const float* dmi_bk = (const float*)d_in[32];
    const float* dmi_wv = (const float*)d_in[33];
    const float* dmi_bv = (const float*)d_in[34];
    const float* tg_w1  = (const float*)d_in[35];
    const float* tg_b1  = (const float*)d_in[36];
    const float* tg_w2  = (const float*)d_in[37];
    const float* tg_b2  = (const float*)d_in[38];
    const float* ig_w1  = (const float*)d_in[39];
    const float* ig_b1  = (const float*)d_in[40];
    const float* ig_w2  = (const float*)d_in[41];
    const float* ig_b2  = (const float*)d_in[42];
    const float* t_scale= (const float*)d_in[43];
    const float* i_scale= (const float*)d_in[44];
    const float* cls_w  = (const float*)d_in[45];
    const float* cls_b  = (const float*)d_in[46];
    float* out = (float*)d_out;

    // ---- workspace (~129 MB) ----
    char* base = (char*)d_ws;
    auto alloc = [&](size_t bytes){ void* p = (void*)base; base += (bytes + 255) & ~(size_t)255; return p; };
    const size_t SLOT = (size_t)NB * DM;
    const size_t W768 = (size_t)768 * 768;
    bf16* tl_wb   = (bf16*)alloc(W768 * 2);
    bf16* il_wb   = (bf16*)alloc(W768 * 2);
    bf16* sda_wvb = (bf16*)alloc((size_t)512 * 768 * 2);
    bf16* sda_wob = (bf16*)alloc((size_t)768 * 512 * 2);
    bf16* fda_wfb = (bf16*)alloc((size_t)768 * 384 * 2);
    bf16* dmi_wqb = (bf16*)alloc(W768 * 2);
    bf16* dmi_wkb = (bf16*)alloc(W768 * 2);
    bf16* dmi_wvb = (bf16*)alloc(W768 * 2);
    bf16* tg_w1b  = (bf16*)alloc(W768 * 2);
    bf16* tg_w2b  = (bf16*)alloc(W768 * 2);
    bf16* ig_w1b  = (bf16*)alloc(W768 * 2);
    bf16* ig_w2b  = (bf16*)alloc(W768 * 2);
    bf16* w1c     = (bf16*)alloc((size_t)384 * 768 * 2);
    float* sac    = (float*)alloc(1536 * 4);
    float* lbuf   = (float*)alloc(2 * NB * 4);               // final denominators [2][NB]
    float* part   = (float*)alloc((size_t)2 * 32 * NB * 4);  // per-chunk partials [2][32][NB], 1 MB
    bf16* SL[8];
    for (int i = 0; i < 8; ++i) SL[i] = (bf16*)alloc(SLOT * 2);
    bf16* SC1 = (bf16*)alloc((size_t)NB * NB * 2);
    bf16* SC2 = (bf16*)alloc((size_t)NB * NB * 2);

    const float bnscale = 1.0f / sqrtf(1.0f + 1e-5f);
    const float iscale  = 1.0f / sqrtf(768.0f);
    const dim3 blk(256);

    struct JB {
        Jobs jb; int blocks;
        void add(const bf16* A, const bf16* B, bf16* C, int M, int N, int K, int ldA, int ldB,
                 const float* b0, float al, const float* gv, const float* b1, int act, int trans,
                 float* rs = nullptr){
            Job& j = jb.j[jb.nj++];
            j.A=A; j.B=B; j.C=C; j.b0=b0; j.gv=gv; j.b1=b1; j.rs=rs;
            j.M=M; j.N=N; j.K=K; j.ldA=ldA; j.ldB=ldB; j.act=act; j.trans=trans;
            j.alpha=al; j.blk0=blocks; j.nx=N/128; j.nb=(N/128)*(M/128);
            blocks += (N/128)*(M/128);
        }
    };
    auto launch = [&](JB& b){ mgemm_k<<<dim3(b.blocks), blk, 0, stream>>>(b.jb); };

    // fp32 -> bf16 staging
    CvtDesc cd;
    const float* srcs[NCVT] = {text, image, tl_w, il_w, sda_wv, sda_wo, fda_wf,
                               dmi_wq, dmi_wk, dmi_wv, tg_w1, tg_w2, ig_w1, ig_w2};
    bf16* dsts[NCVT] = {SL[0], SL[1], tl_wb, il_wb, sda_wvb, sda_wob, fda_wfb,
                        dmi_wqb, dmi_wkb, dmi_wvb, tg_w1b, tg_w2b, ig_w1b, ig_w2b};
    int   lens[NCVT] = {(int)SLOT, (int)SLOT, (int)W768, (int)W768, 512*768, 768*512, 768*384,
                        (int)W768, (int)W768, (int)W768, (int)W768, (int)W768, (int)W768, (int)W768};
    for (int i = 0; i < NCVT; ++i){ cd.s[i] = srcs[i]; cd.d[i] = dsts[i]; cd.n[i] = lens[i]; }
    cvt_k<<<dim3((int)(SLOT / 1024), NCVT), blk, 0, stream>>>(cd);
    extract_k<<<dim3((384 * 768 + 255) / 256), blk, 0, stream>>>(fda_w1, sa_w, w1c, sac);

    // J1: t0 = gelu(text@tl^T) -> SL2 ; im0 = gelu(image@il^T) -> SL3
    { JB b{}; b.add(SL[0], tl_wb, SL[2], NB, DM, DM, DM, DM, tl_b, 1.f, nullptr, nullptr, 1, 0);
              b.add(SL[1], il_wb, SL[3], NB, DM, DM, DM, DM, il_b, 1.f, nullptr, nullptr, 1, 0); launch(b); }
    // J2: wv = t0@wv^T -> SL0 (N=512) ; x1 = conv1(im0) -> SL1 (N=384)
    { JB b{}; b.add(SL[2], sda_wvb, SL[0], NB, 512, DM, DM, DM, sda_bv, 1.f, nullptr, nullptr, 0, 0);
              b.add(SL[3], w1c,     SL[1], NB, 384, DM, DM, DM, fda_b1, bnscale, bn1_g, bn1_b, 1, 0); launch(b); }
    // fused FDA tail (in place on SL1)
    fda_fused_k<<<dim3(NB), dim3(128), 0, stream>>>(SL[1], ca_w1, ca_w2, sac, sa_b, dec_w, dec_b, sigma);
    // J34 (batched): t1 = wv@wo^T -> SL4 (K=512) ; im1 = gelu((x4@wf^T+bf)*bn2) -> SL5 (K=384)
    { JB b{}; b.add(SL[0], sda_wob, SL[4], NB, DM, 512, 512, 512, sda_bo, 1.f, nullptr, nullptr, 0, 0);
              b.add(SL[1], fda_wfb, SL[5], NB, DM, 384, 384, 384, fda_bf, bnscale, bn2_g, bn2_b, 1, 0); launch(b); }

    // J5: QKV both directions (6 jobs)
    { JB b{};
      b.add(SL[4], dmi_wqb, SL[0], NB, DM, DM, DM, DM, dmi_bq, 1.f, nullptr, nullptr, 0, 0);
      b.add(SL[5], dmi_wkb, SL[1], NB, DM, DM, DM, DM, dmi_bk, 1.f, nullptr, nullptr, 0, 0);
      b.add(SL[5], dmi_wvb, SL[2], NB, DM, DM, DM, DM, dmi_bv, 1.f, nullptr, nullptr, 0, 1);
      b.add(SL[5], dmi_wqb, SL[3], NB, DM, DM, DM, DM, dmi_bq, 1.f, nullptr, nullptr, 0, 0);
      b.add(SL[4], dmi_wkb, SL[6], NB, DM, DM, DM, DM, dmi_bk, 1.f, nullptr, nullptr, 0, 0);
      b.add(SL[4], dmi_wvb, SL[7], NB, DM, DM, DM, DM, dmi_bv, 1.f, nullptr, nullptr, 0, 1);
      launch(b); }
    // J6: scores with fused exp + per-block partial row sums (no atomics)
    { JB b{}; b.add(SL[0], SL[1], SC1, NB, NB, DM, DM, DM, nullptr, iscale, nullptr, nullptr, 4, 0, part);
              b.add(SL[3], SL[6], SC2, NB, NB, DM, DM, DM, nullptr, iscale, nullptr, nullptr, 4, 0, part + 32 * NB); launch(b); }
    // reduce partials -> lbuf
    denom_k<<<dim3((2 * NB + 255) / 256), blk, 0, stream>>>(part, lbuf);
    // J7: PV split-K=2 x 2 dirs (4 jobs, 768 blocks) on unnormalized exp-scores
    { JB b{};
      b.add(SC1,        SL[2],        SL[0], NB, DM, 2048, NB, NB, nullptr, 1.f, nullptr, nullptr, 0, 0);
      b.add(SC1 + 2048, SL[2] + 2048, SL[1], NB, DM, 2048, NB, NB, nullptr, 1.f, nullptr, nullptr, 0, 0);
      b.add(SC2,        SL[7],        SL[3], NB, DM, 2048, NB, NB, nullptr, 1.f, nullptr, nullptr, 0, 0);
      b.add(SC2 + 2048, SL[7] + 2048, SL[6], NB, DM, 2048, NB, NB, nullptr, 1.f, nullptr, nullptr, 0, 0);
      launch(b); }
    // a1 = (SL0+SL1)/l1 -> SL4 ; a2 = (SL3+SL6)/l2 -> SL5
    reduce2_k<<<dim3((int)(SLOT / 2048)), blk, 0, stream>>>(SL[0], SL[1], SL[4], lbuf,
                                                           SL[3], SL[6], SL[5], lbuf + NB);
    // J8/J9: gates
    { JB b{}; b.add(SL[4], tg_w1b, SL[0], NB, DM, DM, DM, DM, tg_b1, 1.f, nullptr, nullptr, 3, 0);
              b.add(SL[5], ig_w1b, SL[1], NB, DM, DM, DM, DM, ig_b1, 1.f, nullptr, nullptr, 3, 0); launch(b); }
    { JB b{}; b.add(SL[0], tg_w2b, SL[3], NB, DM, DM, DM, DM, tg_b2, 1.f, nullptr, nullptr, 2, 0);
              b.add(SL[1], ig_w2b, SL[6], NB, DM, DM, DM, DM, ig_b2, 1.f, nullptr, nullptr, 2, 0); launch(b); }
    // fused combine + classifier + softmax
    combine_cls_k<<<dim3(NB), blk, 0, stream>>>(SL[3], SL[4], t_scale, SL[6], SL[5], i_scale,
                                                cls_w, cls_b, out);
}

// Round 7
// 535.274 us; speedup vs baseline: 6.0492x; 1.0172x over previous
//
#include <hip/hip_runtime.h>
#include <hip/hip_bf16.h>
#include <math.h>

typedef __hip_bfloat16 bf16;
typedef __bf16 bf16x8 __attribute__((ext_vector_type(8)));
typedef float f32x4 __attribute__((ext_vector_type(4)));
typedef unsigned short u16;
typedef u16 u16x8 __attribute__((ext_vector_type(8)));

#define NB 4096          // batch rows
#define DM 768           // model dim

__device__ __forceinline__ float cvt(float x){ return x; }
__device__ __forceinline__ float cvt(bf16 x){ return __bfloat162float(x); }
__device__ __forceinline__ void stv(float* p, float v){ *p = v; }
__device__ __forceinline__ void stv(bf16* p, float v){ *p = __float2bfloat16(v); }

__device__ __forceinline__ float gelu_f(float x){
    return 0.5f * x * (1.0f + erff(x * 0.70710678118654752440f));
}
__device__ __forceinline__ float sigmoid_f(float x){
    return 1.0f / (1.0f + __expf(-x));
}

__device__ __forceinline__ void async_copy16(const void* g, void* l){
    __builtin_amdgcn_global_load_lds((const __attribute__((address_space(1))) void*)g,
                                     (__attribute__((address_space(3))) void*)l, 16, 0, 0);
}

// ---------------------------------------------------------------------------
// Flat multi-job MFMA GEMM (proven R7-structure; 2-barrier 128x128 tile).
// R1-R4: 256x256 8-phase kernel unreachable (toolchain register budgeting:
//   512-thr pinned to 128-reg cap, amdgpu_* attrs ignored, 256-thr caps at
//   256 arch VGPRs with no AGPR overflow -> spills). Frozen decision.
// R5/R6 (XCD swizzle, T1): aspect-ratio dependent, footprint-arithmetic
//   verified both ways:
//   - chunked per-XCD footprint = (nb/8)/nx A-panels + nx B-panels;
//     fits 4MB L2 for nx<=~16 at K<=768 -> big win on narrow jobs.
//   - nx=32 (J6): chunked = 4A+32B = 7MB thrash (FETCH +70%, REGRESSED);
//     linear round-robin there is already ~L2-optimal (16A+4B=3.9MB).
//   => gate: chunked iff nx <= 16.
// R7: (1) J5 QK-concat into N=1536 jobs (wqb/wkb contiguous by construction;
//     SL0/1 + SL2/3 serve as 4096x1536 buffers); J6 reads Q/K as ld=1536
//     slices. (2) act=5: gate-combine fused into store phase
//     (v = sigmoid(logit)*aux*scale), combine_cls slims to 2 inputs.
//     (3) extract + qk-bias concat merged into cvt dispatch.
//
// Per job: C = act((A @ Bm^T + b0) * alpha * gv + b1)
// act: 0 none, 1 gelu, 2 sigmoid, 3 relu, 4 exp, 5 store-phase
//      sigmoid(x)*aux[row,col]*sv[col] (acc-loop applies affine only).
// rs != nullptr: block (gx,gy) writes its 128 per-row tile sums to
// rs[gx*M + row] (each slot written exactly once -- no atomics, no memset).
// A: (M,ldA) bf16 cols [0,K). Bm: (N,ldB) bf16 (B^T layout) cols [0,K).
// M%128==0, N%128==0, K%64==0. trans=1: store C^T into (N,M).
// ---------------------------------------------------------------------------
#define MAXJ 8
struct Job {
    const bf16* A; const bf16* B; bf16* C;
    const float* b0; const float* gv; const float* b1;
    float* rs;
    const bf16* aux; const float* sv;
    int M, N, K, ldA, ldB, act, trans, blk0, nx, nb;
    float alpha;
};
struct Jobs { Job j[MAXJ]; int nj; };

__global__ __launch_bounds__(256) void mgemm_k(Jobs jb)
{
    int z = 0;
    #pragma unroll
    for (int i = 1; i < MAXJ; ++i)
        if (i < jb.nj && (int)blockIdx.x >= jb.j[i].blk0) z = i;
    const Job& J = jb.j[z];
    const bf16* __restrict__ A  = J.A;
    const bf16* __restrict__ Bm = J.B;
    bf16* __restrict__ C        = J.C;
    const int bx0 = (int)blockIdx.x - J.blk0;
    // XCD-aware chunked swizzle -- narrow jobs only (nx<=16; see header).
    int bx = bx0;
    if (J.nx <= 16 && (J.nb & 7) == 0){ const int cpx = J.nb >> 3; bx = (bx0 & 7) * cpx + (bx0 >> 3); }
    const int gx = bx % J.nx;
    const int gy = bx / J.nx;
    const int M = J.M, N = J.N, K = J.K, ldA = J.ldA, ldB = J.ldB;

    // staging: A = smem[0 .. 8191] (128x64), B = smem[8192 .. 16383]
    // epilogue: 128x136 bf16 tile = 17408 elems
    __shared__ __align__(16) bf16 smem[17408];
    const int tid  = threadIdx.x;
    const int wave = tid >> 6;
    const int lane = tid & 63;
    const int row0 = gy * 128;
    const int col0 = gx * 128;
    const int wrow = (wave & 1) * 64;
    const int wcol = (wave >> 1) * 64;
    const int fl   = lane & 15;
    const int q    = lane >> 4;

    // staging: per instr a wave stages 8 rows x 64 cols (1 KiB).
    // phys chunk (lane&7) at row r holds logical chunk (lane&7)^(r&7).
    const int sr8 = lane >> 3;
    const int sc8 = (((lane & 7) ^ sr8)) * 8;
    const bf16* pA = A  + (size_t)(row0 + wave * 32 + sr8) * ldA + sc8;
    const bf16* pB = Bm + (size_t)(col0 + wave * 32 + sr8) * ldB + sc8;
    bf16* ldsA = &smem[(wave * 32) * 64];
    bf16* ldsB = &smem[8192 + (wave * 32) * 64];

    f32x4 acc[4][4] = {};
    for (int k0 = 0; k0 < K; k0 += 64){
        #pragma unroll
        for (int i = 0; i < 4; ++i){
            async_copy16(pA + (size_t)(i * 8) * ldA, ldsA + i * 512);
            async_copy16(pB + (size_t)(i * 8) * ldB, ldsB + i * 512);
        }
        pA += 64; pB += 64;
        __syncthreads();
        #pragma unroll
        for (int ks = 0; ks < 2; ++ks){
            bf16x8 af[4], bfv[4];
            #pragma unroll
            for (int i = 0; i < 4; ++i){
                const int ra = wrow + i * 16 + fl;
                const int rb = wcol + i * 16 + fl;
                const int ca = ((ks * 4 + q) ^ (ra & 7)) * 8;
                const int cb = ((ks * 4 + q) ^ (rb & 7)) * 8;
                af[i]  = *(const bf16x8*)&smem[ra * 64 + ca];
                bfv[i] = *(const bf16x8*)&smem[8192 + rb * 64 + cb];
            }
            #pragma unroll
            for (int mi = 0; mi < 4; ++mi)
                #pragma unroll
                for (int ni = 0; ni < 4; ++ni)
                    acc[mi][ni] = __builtin_amdgcn_mfma_f32_16x16x32_bf16(af[mi], bfv[ni], acc[mi][ni], 0, 0, 0);
        }
        __syncthreads();
    }

    // epilogue: C/D layout col = lane&15, row = q*4 + reg (verified)
    // stage to LDS (padded ld=136), then block-wide 256 B coalesced stores.
    constexpr int ELD = 136;
    #pragma unroll
    for (int ni = 0; ni < 4; ++ni){
        const int col = col0 + wcol + ni * 16 + fl;
        const float b0 = J.b0 ? J.b0[col] : 0.f;
        const float gm = (J.gv ? J.gv[col] : 1.f) * J.alpha;
        const float b1 = J.b1 ? J.b1[col] : 0.f;
        const int lcol = wcol + ni * 16 + fl;
        #pragma unroll
        for (int mi = 0; mi < 4; ++mi){
            const int lrow = wrow + mi * 16 + q * 4;
            #pragma unroll
            for (int r = 0; r < 4; ++r){
                float v = (acc[mi][ni][r] + b0) * gm + b1;
                if      (J.act == 1) v = gelu_f(v);
                else if (J.act == 2) v = sigmoid_f(v);
                else if (J.act == 3) v = fmaxf(v, 0.f);
                else if (J.act == 4) v = __expf(v);
                // act==5: affine only here; sigmoid*aux*sv applied in store phase
                if (J.trans) smem[(size_t)lcol * ELD + lrow + r] = __float2bfloat16(v);
                else         smem[(size_t)(lrow + r) * ELD + lcol] = __float2bfloat16(v);
            }
        }
    }
    __syncthreads();
    const int erow = tid >> 4;         // 0..15
    const int ecol = (tid & 15) * 8;   // element offset, 16 B
    #pragma unroll
    for (int p = 0; p < 8; ++p){
        const int row = p * 16 + erow;
        u16x8 uv = *(const u16x8*)&smem[row * ELD + ecol];
        if (J.act == 5){
            // gate-combine fusion: v = sigmoid(logit) * aux[row,col] * sv[col]
            // (coalesced u16x8 aux load mirrors the C-store pattern; logit was
            //  bf16-staged exactly as the old standalone-gate path was.)
            const u16x8 av = *(const u16x8*)((const u16*)J.aux + (size_t)(row0 + row) * N + col0 + ecol);
            #pragma unroll
            for (int j = 0; j < 8; ++j){
                const float g = __uint_as_float((unsigned)uv[j] << 16);
                const float a = __uint_as_float((unsigned)av[j] << 16);
                const float v = sigmoid_f(g) * a * J.sv[col0 + ecol + j];
                uv[j] = __bfloat16_as_ushort(__float2bfloat16(v));
            }
        }
        if (J.trans) *(u16x8*)&C[(size_t)(col0 + row) * M + row0 + ecol] = uv;
        else         *(u16x8*)&C[(size_t)(row0 + row) * N + col0 + ecol] = uv;
        if (J.rs){
            float s = 0.f;
            #pragma unroll
            for (int j = 0; j < 8; ++j) s += __uint_as_float((unsigned)uv[j] << 16);
            s += __shfl_down(s, 8, 16);
            s += __shfl_down(s, 4, 16);
            s += __shfl_down(s, 2, 16);
            s += __shfl_down(s, 1, 16);
            if ((tid & 15) == 0) J.rs[(size_t)gx * M + row0 + row] = s;   // exactly-once, no atomic
        }
    }
}

// Reduce 32 per-chunk partials per row into the softmax denominator.
// part layout: [2 dirs][32 chunks][NB rows]; l: [2][NB].
__global__ __launch_bounds__(256) void denom_k(const float* __restrict__ part, float* __restrict__ l)
{
    const int t = blockIdx.x * 256 + threadIdx.x;     // 0 .. 2*NB-1
    if (t >= 2 * NB) return;
    const int dir = t >> 12, row = t & (NB - 1);
    const float* p = part + (size_t)dir * 32 * NB + row;
    float s = 0.f;
    #pragma unroll
    for (int c = 0; c < 32; ++c) s += p[(size_t)c * NB];
    l[t] = s;
}

// Batched fp32 -> bf16 conversion + (merged) conv-weight extract + QK bias concat
#define NCVT 14
struct CvtDesc { const float* s[NCVT]; bf16* d[NCVT]; int n[NCVT]; };
__global__ __launch_bounds__(256) void cvt_k(CvtDesc cd,
    const float* __restrict__ w1, const float* __restrict__ saw,
    bf16* __restrict__ w1c, float* __restrict__ sac,
    const float* __restrict__ bq, const float* __restrict__ bk,
    float* __restrict__ qkb)
{
    const int e = blockIdx.y;
    if (e == NCVT){
        const int idx = blockIdx.x * 256 + threadIdx.x;
        if (idx < 384 * 768){
            const int oc = idx / 768, ic = idx % 768;
            w1c[idx] = __float2bfloat16(w1[(size_t)oc * 6912 + (size_t)ic * 9 + 4]);
        }
        if (idx < 384) sac[idx] = saw[(size_t)idx * 49 + 24];
        if (idx < 768)                   qkb[idx] = bq[idx];
        else if (idx < 1536)             qkb[idx] = bk[idx - 768];
        return;
    }
    const int base = (blockIdx.x * 256 + threadIdx.x) * 4;
    if (base >= cd.n[e]) return;
    const float4 v = *(const float4*)(cd.s[e] + base);
    union { bf16 h[4]; unsigned long long u; } o;
    o.h[0] = __float2bfloat16(v.x);
    o.h[1] = __float2bfloat16(v.y);
    o.h[2] = __float2bfloat16(v.z);
    o.h[3] = __float2bfloat16(v.w);
    *(unsigned long long*)(cd.d[e] + base) = o.u;
}

// Fused FDA tail: ca1 -> ca2 -> x2 -> sa -> x3 -> dec -> x4, in place
__global__ __launch_bounds__(128) void fda_fused_k(
    bf16* __restrict__ x, const float* __restrict__ wc1, const float* __restrict__ wc2,
    const float* __restrict__ sac, const float* __restrict__ sab,
    const float* __restrict__ decw, const float* __restrict__ decb,
    const float* __restrict__ sigma)
{
    __shared__ float xs[384];
    __shared__ float ca1s[24];
    __shared__ float red[128];
    const int b = blockIdx.x;
    const int tid = threadIdx.x;
    bf16* xr = x + (size_t)b * 384;
    #pragma unroll
    for (int i = 0; i < 3; ++i) xs[tid + i * 128] = cvt(xr[tid + i * 128]);
    __syncthreads();
    if (tid < 96){
        const int o = tid >> 2, sub = tid & 3;
        const float* w = wc1 + (size_t)o * 384 + sub * 96;
        float p = 0.f;
        #pragma unroll 8
        for (int k = 0; k < 96; ++k) p = fmaf(xs[sub * 96 + k], w[k], p);
        p += __shfl_down(p, 1, 64);
        p += __shfl_down(p, 2, 64);
        if (sub == 0) ca1s[o] = gelu_f(p);
    }
    __syncthreads();
    float x2[3];
    float p = 0.f;
    #pragma unroll
    for (int i = 0; i < 3; ++i){
        const int c = tid + i * 128;
        float s = 0.f;
        const float* w = wc2 + (size_t)c * 24;
        #pragma unroll
        for (int k = 0; k < 24; ++k) s = fmaf(ca1s[k], w[k], s);
        const float v = xs[c] * sigmoid_f(s);
        x2[i] = v;
        p += v * sac[c];
    }
    red[tid] = p; __syncthreads();
    for (int s = 64; s > 0; s >>= 1){ if (tid < s) red[tid] += red[tid + s]; __syncthreads(); }
    const float sa = sigmoid_f(red[0] + sab[0]);
    __syncthreads();
    float qq = 0.f;
    #pragma unroll
    for (int i = 0; i < 3; ++i){
        const int c = tid + i * 128;
        x2[i] *= sa;
        qq += x2[i] * decw[c];
    }
    red[tid] = qq; __syncthreads();
    for (int s = 64; s > 0; s >>= 1){ if (tid < s) red[tid] += red[tid + s]; __syncthreads(); }
    const float xg = gelu_f(red[0] + decb[0]);
    #pragma unroll
    for (int i = 0; i < 3; ++i){
        const int c = tid + i * 128;
        const float sg = sigma[c];
        stv(&xr[c], x2[i] + sg * (x2[i] - xg));
    }
}

// o1 = (a+b)/l1[row] ; o2 = (c+d)/l2[row]  (split-K reduce + softmax denom)
__global__ __launch_bounds__(256) void reduce2_k(
    const bf16* __restrict__ a, const bf16* __restrict__ b, bf16* __restrict__ o1,
    const float* __restrict__ l1,
    const bf16* __restrict__ c, const bf16* __restrict__ d, bf16* __restrict__ o2,
    const float* __restrict__ l2)
{
    const size_t i = ((size_t)blockIdx.x * 256 + threadIdx.x) * 8;
    if (i >= (size_t)NB * DM) return;
    const int row = (int)(i / DM);     // 8-elem chunk never crosses a row (768 % 8 == 0)
    const float inv1 = 1.0f / l1[row];
    const float inv2 = 1.0f / l2[row];
    u16x8 ua = *(const u16x8*)((const u16*)a + i);
    u16x8 ub = *(const u16x8*)((const u16*)b + i);
    u16x8 uc = *(const u16x8*)((const u16*)c + i);
    u16x8 ud = *(const u16x8*)((const u16*)d + i);
    u16x8 r1, r2;
    #pragma unroll
    for (int j = 0; j < 8; ++j){
        const float s1 = (__uint_as_float((unsigned)ua[j] << 16) + __uint_as_float((unsigned)ub[j] << 16)) * inv1;
        const float s2 = (__uint_as_float((unsigned)uc[j] << 16) + __uint_as_float((unsigned)ud[j] << 16)) * inv2;
        r1[j] = __bfloat16_as_ushort(__float2bfloat16(s1));
        r2[j] = __bfloat16_as_ushort(__float2bfloat16(s2));
    }
    *(u16x8*)((u16*)o1 + i) = r1;
    *(u16x8*)((u16*)o2 + i) = r2;
}

// Slim classifier: logits = (v1+v2) @ w^T + bias; softmax(3).
// (gate-combine v = sigmoid(g)*a*s now computed in mgemm act=5 store phase.)
__global__ __launch_bounds__(256) void combine_cls_k(
    const bf16* __restrict__ v1, const bf16* __restrict__ v2,
    const float* __restrict__ w, const float* __restrict__ bias, float* __restrict__ out)
{
    __shared__ float r0[256], r1[256], r2[256];
    const int b = blockIdx.x;
    const int tid = threadIdx.x;
    const size_t off = (size_t)b * DM;
    float p0 = 0.f, p1 = 0.f, p2 = 0.f;
    #pragma unroll
    for (int i = 0; i < 3; ++i){
        const int c = tid + i * 256;
        const float v = cvt(v1[off + c]) + cvt(v2[off + c]);
        p0 = fmaf(v, w[c],         p0);
        p1 = fmaf(v, w[DM + c],    p1);
        p2 = fmaf(v, w[2*DM + c],  p2);
    }
    r0[tid] = p0; r1[tid] = p1; r2[tid] = p2; __syncthreads();
    for (int s = 128; s > 0; s >>= 1){
        if (tid < s){ r0[tid] += r0[tid + s]; r1[tid] += r1[tid + s]; r2[tid] += r2[tid + s]; }
        __syncthreads();
    }
    if (tid == 0){
        const float l0 = r0[0] + bias[0];
        const float l1 = r1[0] + bias[1];
        const float l2 = r2[0] + bias[2];
        const float mx = fmaxf(l0, fmaxf(l1, l2));
        const float e0 = __expf(l0 - mx), e1 = __expf(l1 - mx), e2 = __expf(l2 - mx);
        const float inv = 1.f / (e0 + e1 + e2);
        out[(size_t)b * 3 + 0] = e0 * inv;
        out[(size_t)b * 3 + 1] = e1 * inv;
        out[(size_t)b * 3 + 2] = e2 * inv;
    }
}

extern "C" void kernel_launch(void* const* d_in, const int* in_sizes, int n_in,
                              void* d_out, int out_size, void* d_ws, size_t ws_size,
                              hipStream_t stream)
{
    const float* text   = (const float*)d_in[0];
    const float* image  = (const float*)d_in[1];
    const float* tl_w   = (const float*)d_in[2];
    const float* tl_b   = (const float*)d_in[3];
    const float* il_w   = (const float*)d_in[4];
    const float* il_b   = (const float*)d_in[5];
    const float* sda_wv = (const float*)d_in[10];
    const float* sda_bv = (const float*)d_in[11];
    const float* sda_wo = (const float*)d_in[12];
    const float* sda_bo = (const float*)d_in[13];
    const float* fda_w1 = (const float*)d_in[14];
    const float* fda_b1 = (const float*)d_in[15];
    const float* bn1_g  = (const float*)d_in[16];
    const float* bn1_b  = (const float*)d_in[17];
    const float* ca_w1  = (const float*)d_in[18];
    const float* ca_w2  = (const float*)d_in[19];
    const float* sa_w   = (const float*)d_in[20];
    const float* sa_b   = (const float*)d_in[21];
    const float* dec_w  = (const float*)d_in[22];
    const float* dec_b  = (const float*)d_in[23];
    const float* sigma  = (const float*)d_in[24];
    const float* fda_wf = (const float*)d_in[25];
    const float* fda_bf = (const float*)d_in[26];
    const float* bn2_g  = (const float*)d_in[27];
    const float* bn2_b  = (const float*)d_in[28];
    const float* dmi_wq = (const float*)d_in[29];
    const float* dmi_bq = (const float*)d_in[30];
    const float* dmi_wk = (const float*)d_in[31];
    const float* dmi_bk = (const float*)d_in[32];
    const float* dmi_wv = (const float*)d_in[33];
    const float* dmi_bv = (const float*)d_in[34];
    const float* tg_w1  = (const float*)d_in[35];
    const float* tg_b1  = (const float*)d_in[36];
    const float* tg_w2  = (const float*)d_in[37];
    const float* tg_b2  = (const float*)d_in[38];
    const float* ig_w1  = (const float*)d_in[39];
    const float* ig_b1  = (const float*)d_in[40];
    const float* ig_w2  = (const float*)d_in[41];
    const float* ig_b2  = (const float*)d_in[42];
    const float* t_scale= (const float*)d_in[43];
    const float* i_scale= (const float*)d_in[44];
    const float* cls_w  = (const float*)d_in[45];
    const float* cls_b  = (const float*)d_in[46];
    float* out = (float*)d_out;

    // ---- workspace (~129 MB) ----
    char* base = (char*)d_ws;
    auto alloc = [&](size_t bytes){ void* p = (void*)base; base += (bytes + 255) & ~(size_t)255; return p; };
    const size_t SLOT = (size_t)NB * DM;
    const size_t W768 = (size_t)768 * 768;
    bf16* tl_wb   = (bf16*)alloc(W768 * 2);
    bf16* il_wb   = (bf16*)alloc(W768 * 2);
    bf16* sda_wvb = (bf16*)alloc((size_t)512 * 768 * 2);
    bf16* sda_wob = (bf16*)alloc((size_t)768 * 512 * 2);
    bf16* fda_wfb = (bf16*)alloc((size_t)768 * 384 * 2);
    // dmi_wqb and dmi_wkb MUST stay adjacent: together they form Wqk (1536x768)
    // for the merged J5 jobs. (All preceding alloc sizes are 256-multiples, so
    // alloc introduces no padding between them.)
    bf16* dmi_wqb = (bf16*)alloc(W768 * 2);
    bf16* dmi_wkb = (bf16*)alloc(W768 * 2);
    bf16* dmi_wvb = (bf16*)alloc(W768 * 2);
    bf16* tg_w1b  = (bf16*)alloc(W768 * 2);
    bf16* tg_w2b  = (bf16*)alloc(W768 * 2);
    bf16* ig_w1b  = (bf16*)alloc(W768 * 2);
    bf16* ig_w2b  = (bf16*)alloc(W768 * 2);
    bf16* w1c     = (bf16*)alloc((size_t)384 * 768 * 2);
    float* sac    = (float*)alloc(1536 * 4);
    float* qkb    = (float*)alloc(1536 * 4);                 // [bq; bk] concat
    float* lbuf   = (float*)alloc(2 * NB * 4);               // final denominators [2][NB]
    float* part   = (float*)alloc((size_t)2 * 32 * NB * 4);  // per-chunk partials [2][32][NB], 1 MB
    bf16* SL[8];
    for (int i = 0; i < 8; ++i) SL[i] = (bf16*)alloc(SLOT * 2);  // contiguous: SL[i]+SLOT == SL[i+1]
    bf16* SC1 = (bf16*)alloc((size_t)NB * NB * 2);
    bf16* SC2 = (bf16*)alloc((size_t)NB * NB * 2);

    const float bnscale = 1.0f / sqrtf(1.0f + 1e-5f);
    const float iscale  = 1.0f / sqrtf(768.0f);
    const dim3 blk(256);

    struct JB {
        Jobs jb; int blocks;
        void add(const bf16* A, const bf16* B, bf16* C, int M, int N, int K, int ldA, int ldB,
                 const float* b0, float al, const float* gv, const float* b1, int act, int trans,
                 float* rs = nullptr, const bf16* aux = nullptr, const float* sv = nullptr){
            Job& j = jb.j[jb.nj++];
            j.A=A; j.B=B; j.C=C; j.b0=b0; j.gv=gv; j.b1=b1; j.rs=rs; j.aux=aux; j.sv=sv;
            j.M=M; j.N=N; j.K=K; j.ldA=ldA; j.ldB=ldB; j.act=act; j.trans=trans;
            j.alpha=al; j.blk0=blocks; j.nx=N/128; j.nb=(N/128)*(M/128);
            blocks += (N/128)*(M/128);
        }
    };
    auto launch = [&](JB& b){ mgemm_k<<<dim3(b.blocks), blk, 0, stream>>>(b.jb); };

    // fp32 -> bf16 staging (+ merged conv-weight extract + QK-bias concat)
    CvtDesc cd;
    const float* srcs[NCVT] = {text, image, tl_w, il_w, sda_wv, sda_wo, fda_wf,
                               dmi_wq, dmi_wk, dmi_wv, tg_w1, tg_w2, ig_w1, ig_w2};
    bf16* dsts[NCVT] = {SL[0], SL[1], tl_wb, il_wb, sda_wvb, sda_wob, fda_wfb,
                        dmi_wqb, dmi_wkb, dmi_wvb, tg_w1b, tg_w2b, ig_w1b, ig_w2b};
    int   lens[NCVT] = {(int)SLOT, (int)SLOT, (int)W768, (int)W768, 512*768, 768*512, 768*384,
                        (int)W768, (int)W768, (int)W768, (int)W768, (int)W768, (int)W768, (int)W768};
    for (int i = 0; i < NCVT; ++i){ cd.s[i] = srcs[i]; cd.d[i] = dsts[i]; cd.n[i] = lens[i]; }
    cvt_k<<<dim3((int)(SLOT / 1024), NCVT + 1), blk, 0, stream>>>(cd, fda_w1, sa_w, w1c, sac,
                                                                  dmi_bq, dmi_bk, qkb);

    // J1: t0 = gelu(text@tl^T) -> SL2 ; im0 = gelu(image@il^T) -> SL3
    { JB b{}; b.add(SL[0], tl_wb, SL[2], NB, DM, DM, DM, DM, tl_b, 1.f, nullptr, nullptr, 1, 0);
              b.add(SL[1], il_wb, SL[3], NB, DM, DM, DM, DM, il_b, 1.f, nullptr, nullptr, 1, 0); launch(b); }
    // J2: wv = t0@wv^T -> SL0 (N=512) ; x1 = conv1(im0) -> SL1 (N=384)
    { JB b{}; b.add(SL[2], sda_wvb, SL[0], NB, 512, DM, DM, DM, sda_bv, 1.f, nullptr, nullptr, 0, 0);
              b.add(SL[3], w1c,     SL[1], NB, 384, DM, DM, DM, fda_b1, bnscale, bn1_g, bn1_b, 1, 0); launch(b); }
    // fused FDA tail (in place on SL1)
    fda_fused_k<<<dim3(NB), dim3(128), 0, stream>>>(SL[1], ca_w1, ca_w2, sac, sa_b, dec_w, dec_b, sigma);
    // J34 (batched): t1 = wv@wo^T -> SL4 (K=512) ; im1 = gelu((x4@wf^T+bf)*bn2) -> SL5 (K=384)
    { JB b{}; b.add(SL[0], sda_wob, SL[4], NB, DM, 512, 512, 512, sda_bo, 1.f, nullptr, nullptr, 0, 0);
              b.add(SL[1], fda_wfb, SL[5], NB, DM, 384, 384, 384, fda_bf, bnscale, bn2_g, bn2_b, 1, 0); launch(b); }

    // J5: merged QK (N=1536, Wqk = [wq;wk]) both directions + V^T jobs.
    //   bufT = SL0..SL1 (4096x1536): cols 0-767 = Q_t, 768-1535 = K_t
    //   bufI = SL2..SL3 (4096x1536): cols 0-767 = Q_im, 768-1535 = K_im
    { JB b{};
      b.add(SL[4], dmi_wqb, SL[0], NB, 1536, DM, DM, DM, qkb,    1.f, nullptr, nullptr, 0, 0);
      b.add(SL[5], dmi_wqb, SL[2], NB, 1536, DM, DM, DM, qkb,    1.f, nullptr, nullptr, 0, 0);
      b.add(SL[5], dmi_wvb, SL[6], NB, DM,   DM, DM, DM, dmi_bv, 1.f, nullptr, nullptr, 0, 1);   // V_im^T
      b.add(SL[4], dmi_wvb, SL[7], NB, DM,   DM, DM, DM, dmi_bv, 1.f, nullptr, nullptr, 0, 1);   // V_t^T
      launch(b); }
    // J6: scores (strided Q/K slices, ld=1536) with fused exp + per-block partial row sums
    { JB b{}; b.add(SL[0],       SL[2] + 768, SC1, NB, NB, DM, 1536, 1536, nullptr, iscale, nullptr, nullptr, 4, 0, part);
              b.add(SL[2],       SL[0] + 768, SC2, NB, NB, DM, 1536, 1536, nullptr, iscale, nullptr, nullptr, 4, 0, part + 32 * NB); launch(b); }
    // reduce partials -> lbuf
    denom_k<<<dim3((2 * NB + 255) / 256), blk, 0, stream>>>(part, lbuf);
    // J7: PV split-K=2 x 2 dirs (4 jobs, 768 blocks) on unnormalized exp-scores
    { JB b{};
      b.add(SC1,        SL[6],        SL[0], NB, DM, 2048, NB, NB, nullptr, 1.f, nullptr, nullptr, 0, 0);
      b.add(SC1 + 2048, SL[6] + 2048, SL[1], NB, DM, 2048, NB, NB, nullptr, 1.f, nullptr, nullptr, 0, 0);
      b.add(SC2,        SL[7],        SL[2], NB, DM, 2048, NB, NB, nullptr, 1.f, nullptr, nullptr, 0, 0);
      b.add(SC2 + 2048, SL[7] + 2048, SL[3], NB, DM, 2048, NB, NB, nullptr, 1.f, nullptr, nullptr, 0, 0);
      launch(b); }
    // a1 = (SL0+SL1)/l1 -> SL4 ; a2 = (SL2+SL3)/l2 -> SL5
    reduce2_k<<<dim3((int)(SLOT / 2048)), blk, 0, stream>>>(SL[0], SL[1], SL[4], lbuf,
                                                           SL[2], SL[3], SL[5], lbuf + NB);
    // J8: gate hidden (relu)
    { JB b{}; b.add(SL[4], tg_w1b, SL[0], NB, DM, DM, DM, DM, tg_b1, 1.f, nullptr, nullptr, 3, 0);
              b.add(SL[5], ig_w1b, SL[1], NB, DM, DM, DM, DM, ig_b1, 1.f, nullptr, nullptr, 3, 0); launch(b); }
    // J9: gate out + fused combine (act=5): v = sigmoid(logit)*a*scale
    { JB b{}; b.add(SL[0], tg_w2b, SL[3], NB, DM, DM, DM, DM, tg_b2, 1.f, nullptr, nullptr, 5, 0, nullptr, SL[4], t_scale);
              b.add(SL[1], ig_w2b, SL[6], NB, DM, DM, DM, DM, ig_b2, 1.f, nullptr, nullptr, 5, 0, nullptr, SL[5], i_scale); launch(b); }
    // slim classifier + softmax
    combine_cls_k<<<dim3(NB), blk, 0, stream>>>(SL[3], SL[6], cls_w, cls_b, out);
}